// Round 7
// baseline (2846.981 us; speedup 1.0000x reference)
//
#include <hip/hip_runtime.h>
#include <math.h>

// SPDNet forward. Round 14 resubmit (r6 bench was an infra failure, no data).
// r13 LDS-diet + r11 1-wave blocks.
// r13 (4-wave blocks, natural VGPR=128) lost occupancy two ways: VGPR capped
// 4 waves/SIMD, and 4-wave block granularity held LDS until the slowest wave
// (doeig stragglers) retired -> 23% effective. Fix: back to 64-thread blocks
// (independent wave retirement, the r11 structure that measured 44%) while
// keeping the r13 slice of 1696 floats (6784 B) -> 24 blocks/CU possible
// (6784 x 24 = 162.8 KB <= 160 KiB pool... actually 163840 B, fits).
// __launch_bounds__(64, 6) caps VGPR at 85 (6 waves/SIMD) -- above the
// hot-loop live set (~60-70), far from r12's spill cliff at 40.
// All math byte-identical to r13 (passed, absmax 0.0625):
//  - x/w1/w2 from global (weights L1-resident; x symmetric -> coalesced)
//  - L and X1 half-rows in registers; L[kk][kc] on the fly via pair shfl
//  - partial-spectrum ReEig: register GJ inertia (PB broadcast), 2-pass
//    shift-invert, f64 GS + Rayleigh-Ritz, rank-4 correction in M2 space;
//    jac32 fallback. Stage 2: f64 chol16 certificate + jac16 fallback.
//    Stage 3: serial 4x4 Jacobi + LogEig + fc + log_softmax.
//  - wave-private LDS, CFENCE only (no __syncthreads).

#define MAXSW32 8
#define MAXSW16 8
#define MAXSW4  8
#define JTOL2   1e-12f
#define EPS_REC 1e-4f
#define SHIFT1  4e-4f
#define BRKTOL  1e-7f
#define DELTA2  2e-4

#define SLICE   1696
#define OFF_PB  1152
#define OFF_NRM 1188
#define OFF_W3  1220
#define OFF_VT  1300
#define OFF_M2  1364

// Compiler-only memory fence (wave-private LDS: HW-ordered per wave).
#define CFENCE() asm volatile("" ::: "memory")

// Static component access into the a0..a3 half-row (r must be compile-time).
#define XRC(r) ( (r)<8 ? ((r)<4 ? ((r)==0?a0.x:(r)==1?a0.y:(r)==2?a0.z:a0.w) \
                                : ((r)==4?a1.x:(r)==5?a1.y:(r)==6?a1.z:a1.w)) \
                       : ((r)<12 ? ((r)==8?a2.x:(r)==9?a2.y:(r)==10?a2.z:a2.w) \
                                 : ((r)==12?a3.x:(r)==13?a3.y:(r)==14?a3.z:a3.w)) )

#define ACC16(part, av, w2r) do { \
  float4 _w0 = (w2r)[0], _w1 = (w2r)[1], _w2 = (w2r)[2], _w3 = (w2r)[3]; \
  float _a = (av); \
  part[0]+=_a*_w0.x; part[1]+=_a*_w0.y; part[2]+=_a*_w0.z; part[3]+=_a*_w0.w; \
  part[4]+=_a*_w1.x; part[5]+=_a*_w1.y; part[6]+=_a*_w1.z; part[7]+=_a*_w1.w; \
  part[8]+=_a*_w2.x; part[9]+=_a*_w2.y; part[10]+=_a*_w2.z; part[11]+=_a*_w2.w; \
  part[12]+=_a*_w3.x; part[13]+=_a*_w3.y; part[14]+=_a*_w3.z; part[15]+=_a*_w3.w; \
} while (0)

__device__ __forceinline__ float shfl_xor_f(float v, int m) { return __shfl_xor(v, m, 64); }
__device__ __forceinline__ float dot4(float4 a, float4 b) {
  return a.x * b.x + a.y * b.y + a.z * b.z + a.w * b.w;
}
__device__ __forceinline__ void axpy4(float4& a, float xv, float4 w) {
  a.x += xv * w.x; a.y += xv * w.y; a.z += xv * w.z; a.w += xv * w.w;
}

__device__ __forceinline__ float dpp_add_xor1(float d) {
  return d + __int_as_float(__builtin_amdgcn_mov_dpp(__float_as_int(d), 0xB1, 0xF, 0xF, true));
}
__device__ __forceinline__ float dpp_add_xor2(float d) {
  return d + __int_as_float(__builtin_amdgcn_mov_dpp(__float_as_int(d), 0x4E, 0xF, 0xF, true));
}
__device__ __forceinline__ float dpp_add_halfmirror(float d) {
  return d + __int_as_float(__builtin_amdgcn_mov_dpp(__float_as_int(d), 0x141, 0xF, 0xF, true));
}

__device__ __forceinline__ double dsum64(double v) {
  #pragma unroll
  for (int m = 1; m <= 32; m <<= 1) v += __shfl_xor(v, m, 64);
  return v;
}
__device__ __forceinline__ float wmax64(float v) {
  #pragma unroll
  for (int m = 1; m <= 32; m <<= 1) v = fmaxf(v, __shfl_xor(v, m, 64));
  return v;
}

__device__ __forceinline__ void rot_cs(float d, float dpp, float dqq,
                                       float& c, float& s) {
  float tau = 0.5f * (dqq - dpp);
  float r   = __builtin_amdgcn_sqrtf(fmaf(tau, tau, d * d));
  float den = fabsf(tau) + r;
  float tnum = __uint_as_float(__float_as_uint(d) ^
                               (__float_as_uint(tau) & 0x80000000u));
  float t = tnum * __builtin_amdgcn_rcpf(den);
  c = __builtin_amdgcn_rsqf(fmaf(t, t, 1.f));
  s = t * c;
}

// Register-resident Gauss-Jordan of A = X1 - SHIFT1*I, 4 RHS in regs.
__device__ __forceinline__ void gj_reg(float4 x0, float4 x1, float4 x2, float4 x3,
                                       float* __restrict__ PB,
                                       int kc, int h, int hb, float maxd,
                                       float4& y, float& down,
                                       int& mneg, bool& brk) {
  float4 r0 = x0, r1 = x1, r2 = x2, r3 = x3;
  const int dc = kc - hb;
  r0.x -= (dc == 0)  ? SHIFT1 : 0.f;
  r0.y -= (dc == 1)  ? SHIFT1 : 0.f;
  r0.z -= (dc == 2)  ? SHIFT1 : 0.f;
  r0.w -= (dc == 3)  ? SHIFT1 : 0.f;
  r1.x -= (dc == 4)  ? SHIFT1 : 0.f;
  r1.y -= (dc == 5)  ? SHIFT1 : 0.f;
  r1.z -= (dc == 6)  ? SHIFT1 : 0.f;
  r1.w -= (dc == 7)  ? SHIFT1 : 0.f;
  r2.x -= (dc == 8)  ? SHIFT1 : 0.f;
  r2.y -= (dc == 9)  ? SHIFT1 : 0.f;
  r2.z -= (dc == 10) ? SHIFT1 : 0.f;
  r2.w -= (dc == 11) ? SHIFT1 : 0.f;
  r3.x -= (dc == 12) ? SHIFT1 : 0.f;
  r3.y -= (dc == 13) ? SHIFT1 : 0.f;
  r3.z -= (dc == 14) ? SHIFT1 : 0.f;
  r3.w -= (dc == 15) ? SHIFT1 : 0.f;

  mneg = 0; brk = false; down = 1.f;
  #pragma unroll
  for (int k = 0; k < 32; ++k) {
    if (kc == k) {
      *(float4*)(PB + hb)      = r0;
      *(float4*)(PB + hb + 4)  = r1;
      *(float4*)(PB + hb + 8)  = r2;
      *(float4*)(PB + hb + 12) = r3;
      if (h == 0) *(float4*)(PB + 32) = y;
    }
    CFENCE();
    const float  d  = PB[k];
    const float4 p0 = *(const float4*)(PB + hb);
    const float4 p1 = *(const float4*)(PB + hb + 4);
    const float4 p2 = *(const float4*)(PB + hb + 8);
    const float4 p3 = *(const float4*)(PB + hb + 12);
    const float4 py = *(const float4*)(PB + 32);
    CFENCE();
    mneg += (d <= 0.f) ? 1 : 0;
    brk = brk || !(fabsf(d) >= BRKTOL * maxd);
    float elt;
    {
      const int q = (k >> 2) & 3;
      const float4 rq = (q == 0) ? r0 : (q == 1) ? r1 : (q == 2) ? r2 : r3;
      const int m = k & 3;
      elt = (m == 0) ? rq.x : (m == 1) ? rq.y : (m == 2) ? rq.z : rq.w;
    }
    const bool ownhalf = (k >= 16) ? (h == 1) : (h == 0);
    float tm = ownhalf ? elt : 0.f;
    float f  = dpp_add_xor1(tm);
    float fr = f * __builtin_amdgcn_rcpf(d);
    fr   = (brk || (kc == k)) ? 0.f : fr;
    down = (kc == k) ? d : down;
    axpy4(r0, -fr, p0);
    axpy4(r1, -fr, p1);
    axpy4(r2, -fr, p2);
    axpy4(r3, -fr, p3);
    axpy4(y,  -fr, py);
  }
}

// One-sided Jacobi, n=32, column stride 36. 16 pairs x 4 lanes.
__device__ __forceinline__ void jac32(float* __restrict__ G, float* __restrict__ nrm,
                                      int lane) {
  const int kq  = lane >> 2, sub = lane & 3;
  const int k = (kq & 8) | ((kq & 1) << 2) | (kq & 2) | ((kq & 4) >> 2);
  const int o0 = 4 * sub, o1 = 4 * sub + 16;
  int pp = (k == 0) ? 31 : k;
  int qq = (k == 0) ? 0 : (31 - k);
  for (int sw = 0; sw < MAXSW32; ++sw) {
    bool anyact = false;
    for (int r = 0; r < 31; ++r) {
      CFENCE();
      const int p = pp, q = qq;
      if (k != 0) { pp += 16; if (pp >= 31) pp -= 31; }
      qq += 16; if (qq >= 31) qq -= 31;
      const int pb = p * 36, qb = q * 36;
      float dpp = nrm[p], dqq = nrm[q];
      float4 gp0 = *(const float4*)(G + pb + o0);
      float4 gp1 = *(const float4*)(G + pb + o1);
      float4 gq0 = *(const float4*)(G + qb + o0);
      float4 gq1 = *(const float4*)(G + qb + o1);
      float d = dot4(gp0, gq0) + dot4(gp1, gq1);
      d = dpp_add_xor1(d);
      d = dpp_add_xor2(d);
      bool active = (d * d > JTOL2 * dpp * dqq);
      if (__ballot(active) == 0ull) continue;
      anyact = true;
      if (active) {
        float c, s;
        rot_cs(d, dpp, dqq, c, s);
        float4 np0, np1, nq0, nq1;
        np0.x = c * gp0.x - s * gq0.x; nq0.x = s * gp0.x + c * gq0.x;
        np0.y = c * gp0.y - s * gq0.y; nq0.y = s * gp0.y + c * gq0.y;
        np0.z = c * gp0.z - s * gq0.z; nq0.z = s * gp0.z + c * gq0.z;
        np0.w = c * gp0.w - s * gq0.w; nq0.w = s * gp0.w + c * gq0.w;
        np1.x = c * gp1.x - s * gq1.x; nq1.x = s * gp1.x + c * gq1.x;
        np1.y = c * gp1.y - s * gq1.y; nq1.y = s * gp1.y + c * gq1.y;
        np1.z = c * gp1.z - s * gq1.z; nq1.z = s * gp1.z + c * gq1.z;
        np1.w = c * gp1.w - s * gq1.w; nq1.w = s * gp1.w + c * gq1.w;
        *(float4*)(G + pb + o0) = np0;
        *(float4*)(G + pb + o1) = np1;
        *(float4*)(G + qb + o0) = nq0;
        *(float4*)(G + qb + o1) = nq1;
        if (sub == 0) {
          float cs2 = 2.f * c * s * d, cc = c * c, ss = s * s;
          nrm[p] = cc * dpp - cs2 + ss * dqq;
          nrm[q] = ss * dpp + cs2 + cc * dqq;
        }
      }
    }
    if (!anyact) break;
  }
  CFENCE();
}

// One-sided Jacobi, n=16, column stride 20. 8 pairs x 8 lanes.
__device__ __forceinline__ void jac16(float* __restrict__ G, float* __restrict__ nrm,
                                      int lane) {
  const int kq = lane >> 3, sub = lane & 7;
  const int k = (kq >> 1) | ((kq & 1) << 2);
  const int o = 2 * sub;
  int pp = (k == 0) ? 15 : k;
  int qq = (k == 0) ? 0 : (15 - k);
  for (int sw = 0; sw < MAXSW16; ++sw) {
    bool anyact = false;
    for (int r = 0; r < 15; ++r) {
      CFENCE();
      const int p = pp, q = qq;
      if (k != 0) { pp += 8; if (pp >= 15) pp -= 15; }
      qq += 8; if (qq >= 15) qq -= 15;
      const int pb = p * 20 + o, qb = q * 20 + o;
      float dpp = nrm[p], dqq = nrm[q];
      float2 gp = *(const float2*)(G + pb);
      float2 gq = *(const float2*)(G + qb);
      float d = gp.x * gq.x + gp.y * gq.y;
      d = dpp_add_xor1(d);
      d = dpp_add_xor2(d);
      d = dpp_add_halfmirror(d);
      bool active = (d * d > JTOL2 * dpp * dqq);
      if (__ballot(active) == 0ull) continue;
      anyact = true;
      if (active) {
        float c, s;
        rot_cs(d, dpp, dqq, c, s);
        float2 np, nq;
        np.x = c * gp.x - s * gq.x; nq.x = s * gp.x + c * gq.x;
        np.y = c * gp.y - s * gq.y; nq.y = s * gp.y + c * gq.y;
        *(float2*)(G + pb) = np;
        *(float2*)(G + qb) = nq;
        if (sub == 0) {
          float cs2 = 2.f * c * s * d, cc = c * c, ss = s * s;
          nrm[p] = cc * dpp - cs2 + ss * dqq;
          nrm[q] = ss * dpp + cs2 + cc * dqq;
        }
      }
    }
    if (!anyact) break;
  }
  CFENCE();
}

__launch_bounds__(64, 6)
__global__ void spdnet_kernel(const float* __restrict__ x,
                              const float* __restrict__ w1,
                              const float* __restrict__ w2,
                              const float* __restrict__ w3,
                              const float* __restrict__ fcw,
                              float* __restrict__ out,
                              int B) {
  const int lane = threadIdx.x;
  const int b    = blockIdx.x;

  __shared__ __align__(16) float SH[SLICE];
  float* const A   = SH;             // G/Z (doeig) | E + Q (common) | chol f64 | Y/X3
  float* const PB  = SH + OFF_PB;    // 36: GJ pivot broadcast
  float* const NRM = SH + OFF_NRM;   // 32
  float* const W3S = SH + OFF_W3;    // 80: w3 col-major stride 20
  float* const VT  = SH + OFF_VT;    // 64: TQ then V
  float* const M2R = SH + OFF_M2;    // 320: M2 stride 20

  const float* xb = x + (size_t)b * 1024;
  const int kc = lane >> 1, h = lane & 1, hb = h * 16;

  float w3r = w3[lane];

  // ---- L = x*w1 half-columns in regs (a[r] = L[hb+r][kc]) ----
  float4 a0 = {0.f, 0.f, 0.f, 0.f}, a1 = a0, a2 = a0, a3 = a0;
  #pragma unroll
  for (int j = 0; j < 32; ++j) {
    float wv = w1[j * 32 + kc];
    const float4* xr = (const float4*)(xb + j * 32 + hb);
    axpy4(a0, wv, xr[0]);
    axpy4(a1, wv, xr[1]);
    axpy4(a2, wv, xr[2]);
    axpy4(a3, wv, xr[3]);
  }
  // ---- X1 half-row (b regs), L[kk][kc] fetched on the fly via pair shfl ----
  {
    float4 b0 = {0.f, 0.f, 0.f, 0.f}, b1 = b0, b2 = b0, b3 = b0;
    #pragma unroll
    for (int kk = 0; kk < 32; ++kk) {
      float own = XRC(kk & 15);
      float par = shfl_xor_f(own, 1);
      float lv  = ((kk >> 4) == h) ? own : par;
      const float4* wr = (const float4*)(w1 + kk * 32 + hb);
      axpy4(b0, lv, wr[0]);
      axpy4(b1, lv, wr[1]);
      axpy4(b2, lv, wr[2]);
      axpy4(b3, lv, wr[3]);
    }
    a0 = b0; a1 = b1; a2 = b2; a3 = b3;
  }
  float nv = dot4(a0, a0) + dot4(a1, a1) + dot4(a2, a2) + dot4(a3, a3);
  nv += shfl_xor_f(nv, 1);
  if (h == 0) NRM[kc] = nv;
  CFENCE();

  // ---- maxd = max diag (own diag elt via static select chain) ----
  float maxd;
  {
    const int dc = kc & 15;
    float dvv = XRC(0);
    #pragma unroll
    for (int t = 1; t < 16; ++t) dvv = (dc == t) ? XRC(t) : dvv;
    dvv = ((kc >> 4) == h) ? dvv : 0.f;
    maxd = wmax64(dvv);
  }

  // ---- inertia + shift-invert pass 1 ----
  float4 yv;
  {
    unsigned s = kc * 0x9E3779B9u + 0x7F4A7C15u;
    s = s * 1664525u + 1013904223u; yv.x = (float)(int)(s >> 16) - 32768.f;
    s = s * 1664525u + 1013904223u; yv.y = (float)(int)(s >> 16) - 32768.f;
    s = s * 1664525u + 1013904223u; yv.z = (float)(int)(s >> 16) - 32768.f;
    s = s * 1664525u + 1013904223u; yv.w = (float)(int)(s >> 16) - 32768.f;
  }
  int mneg; bool brk; float down;
  gj_reg(a0, a1, a2, a3, PB, kc, h, hb, maxd, yv, down, mneg, brk);
  const bool doeig  = brk || (mneg > 4);
  const bool docorr = !doeig && (mneg >= 1);

  if (docorr) {
    // ---- pass 2 (refine) + f64 GS + Rayleigh-Ritz ----
    float rd1 = __builtin_amdgcn_rcpf(down);
    float4 y1 = make_float4(yv.x * rd1, yv.y * rd1, yv.z * rd1, yv.w * rd1);
    int mn2; bool b2; float down2;
    gj_reg(a0, a1, a2, a3, PB, kc, h, hb, maxd, y1, down2, mn2, b2);
    (void)mn2; (void)b2;
    float rd2 = __builtin_amdgcn_rcpf(down2);
    double v0 = (double)(y1.x * rd2), v1 = (double)(y1.y * rd2);
    double v2 = (double)(y1.z * rd2), v3 = (double)(y1.w * rd2);
    double n, pr, q0, q1, q2, q3;
    n = 0.5 * dsum64(v0 * v0); q0 = v0 * (1.0 / sqrt(n + 1e-280));
    pr = 0.5 * dsum64(q0 * v1); v1 -= pr * q0;
    n = 0.5 * dsum64(v1 * v1); q1 = v1 * (1.0 / sqrt(n + 1e-280));
    pr = 0.5 * dsum64(q0 * v2); v2 -= pr * q0;
    pr = 0.5 * dsum64(q1 * v2); v2 -= pr * q1;
    n = 0.5 * dsum64(v2 * v2); q2 = v2 * (1.0 / sqrt(n + 1e-280));
    pr = 0.5 * dsum64(q0 * v3); v3 -= pr * q0;
    pr = 0.5 * dsum64(q1 * v3); v3 -= pr * q1;
    pr = 0.5 * dsum64(q2 * v3); v3 -= pr * q2;
    n = 0.5 * dsum64(v3 * v3); q3 = v3 * (1.0 / sqrt(n + 1e-280));
    if (h == 0)
      *(float4*)(A + 640 + 4 * kc) =
          make_float4((float)q0, (float)q1, (float)q2, (float)q3);
    CFENCE();
    // T partials over own half: T[q] += X1[kc][i] * Q[i][q]
    double T0 = 0, T1 = 0, T2 = 0, T3 = 0;
    #pragma unroll
    for (int r = 0; r < 16; ++r) {
      float4 qv = *(const float4*)(A + 640 + 4 * (hb + r));
      double xv = (double)XRC(r);
      T0 += xv * qv.x; T1 += xv * qv.y; T2 += xv * qv.z; T3 += xv * qv.w;
    }
    double S00 = dsum64(q0 * T0), S10 = dsum64(q1 * T0);
    double S20 = dsum64(q2 * T0), S30 = dsum64(q3 * T0);
    double S11 = dsum64(q1 * T1), S21 = dsum64(q2 * T1), S31 = dsum64(q3 * T1);
    double S22 = dsum64(q2 * T2), S32 = dsum64(q3 * T2);
    double S33 = dsum64(q3 * T3);
    if (lane == 0) {
      double Ad[4][4] = {{S00, S10, S20, S30}, {S10, S11, S21, S31},
                         {S20, S21, S22, S32}, {S30, S31, S32, S33}};
      float Wd[4][4] = {{1.f, 0.f, 0.f, 0.f}, {0.f, 1.f, 0.f, 0.f},
                        {0.f, 0.f, 1.f, 0.f}, {0.f, 0.f, 0.f, 1.f}};
      for (int sw = 0; sw < 5; ++sw) {
        #pragma unroll
        for (int p = 0; p < 3; ++p) {
          #pragma unroll
          for (int q = p + 1; q < 4; ++q) {
            double apq = Ad[p][q];
            if (fabs(apq) > 1e-14 * (fabs(Ad[p][p]) + fabs(Ad[q][q])) + 1e-300) {
              double tau = 0.5 * (Ad[q][q] - Ad[p][p]);
              double rr = sqrt(tau * tau + apq * apq);
              double t = ((tau >= 0.0) ? apq : -apq) / (fabs(tau) + rr);
              double c = 1.0 / sqrt(t * t + 1.0), sv = t * c;
              #pragma unroll
              for (int jj = 0; jj < 4; ++jj) {
                double ap = Ad[p][jj], aq = Ad[q][jj];
                Ad[p][jj] = c * ap - sv * aq;
                Ad[q][jj] = sv * ap + c * aq;
              }
              #pragma unroll
              for (int ii = 0; ii < 4; ++ii) {
                double ap = Ad[ii][p], aq = Ad[ii][q];
                Ad[ii][p] = c * ap - sv * aq;
                Ad[ii][q] = sv * ap + c * aq;
                float wp = Wd[ii][p], wq = Wd[ii][q];
                Wd[ii][p] = (float)(c * wp - sv * wq);
                Wd[ii][q] = (float)(sv * wp + c * wq);
              }
            }
          }
        }
      }
      #pragma unroll
      for (int qi = 0; qi < 4; ++qi) {
        NRM[16 + qi] = (float)Ad[qi][qi];
        #pragma unroll
        for (int ai = 0; ai < 4; ++ai) NRM[ai * 4 + qi] = Wd[ai][qi];
      }
    }
    CFENCE();
  }

  if (doeig) {
    // ---- fallback: dump X1 to LDS + full one-sided Jacobi ----
    *(float4*)(A + kc * 36 + hb)      = a0;
    *(float4*)(A + kc * 36 + hb + 4)  = a1;
    *(float4*)(A + kc * 36 + hb + 8)  = a2;
    *(float4*)(A + kc * 36 + hb + 12) = a3;
    CFENCE();
    jac32(A, NRM, lane);
  }

  if (!doeig) {
    // ---- E[a][kc] = w2_a . x1_kc  -> A stride 20 (rec1 base = X1) ----
    {
      float part[16];
      #pragma unroll
      for (int a = 0; a < 16; ++a) part[a] = 0.f;
      #pragma unroll
      for (int r = 0; r < 16; ++r) {
        const float4* w2r = (const float4*)(w2 + (hb + r) * 16);
        ACC16(part, XRC(r), w2r);
      }
      #pragma unroll
      for (int a = 0; a < 16; ++a) part[a] = dpp_add_xor1(part[a]);
      if (h == 0) {
        *(float4*)(A + kc * 20 + 0)  = make_float4(part[0],  part[1],  part[2],  part[3]);
        *(float4*)(A + kc * 20 + 4)  = make_float4(part[4],  part[5],  part[6],  part[7]);
        *(float4*)(A + kc * 20 + 8)  = make_float4(part[8],  part[9],  part[10], part[11]);
        *(float4*)(A + kc * 20 + 12) = make_float4(part[12], part[13], part[14], part[15]);
      }
      CFENCE();
    }
    if (docorr) {
      // ---- TQ = w2^T Q ----
      const int aq = lane >> 4, a16 = lane & 15;
      float tq = 0.f;
      #pragma unroll 4
      for (int j = 0; j < 32; ++j)
        tq += w2[j * 16 + a16] * A[640 + 4 * j + aq];
      VT[aq * 16 + a16] = tq;
      CFENCE();
      if (lane < 16) {
        float t0 = VT[lane], t1 = VT[16 + lane];
        float t2 = VT[32 + lane], t3 = VT[48 + lane];
        float4 vv;
        {
          float cs = __builtin_amdgcn_sqrtf(fmaxf(EPS_REC - NRM[16], 0.f));
          vv.x = cs * (t0 * NRM[0] + t1 * NRM[4] + t2 * NRM[8] + t3 * NRM[12]);
        }
        {
          float cs = __builtin_amdgcn_sqrtf(fmaxf(EPS_REC - NRM[17], 0.f));
          vv.y = cs * (t0 * NRM[1] + t1 * NRM[5] + t2 * NRM[9] + t3 * NRM[13]);
        }
        {
          float cs = __builtin_amdgcn_sqrtf(fmaxf(EPS_REC - NRM[18], 0.f));
          vv.z = cs * (t0 * NRM[2] + t1 * NRM[6] + t2 * NRM[10] + t3 * NRM[14]);
        }
        {
          float cs = __builtin_amdgcn_sqrtf(fmaxf(EPS_REC - NRM[19], 0.f));
          vv.w = cs * (t0 * NRM[3] + t1 * NRM[7] + t2 * NRM[11] + t3 * NRM[15]);
        }
        CFENCE();
        *(float4*)(VT + lane * 4) = vv;
      }
      CFENCE();
    }
  } else {
    // ---- slow Z in place over G columns (stride 36) ----
    float g[16];
    #pragma unroll
    for (int c = 0; c < 4; ++c) {
      float4 v = *(const float4*)(A + kc * 36 + hb + 4 * c);
      g[4 * c] = v.x; g[4 * c + 1] = v.y; g[4 * c + 2] = v.z; g[4 * c + 3] = v.w;
    }
    float dpp = 0.f;
    #pragma unroll
    for (int i = 0; i < 16; ++i) dpp += g[i] * g[i];
    dpp += shfl_xor_f(dpp, 1);
    float lam = __builtin_amdgcn_sqrtf(dpp);
    float mu  = fmaxf(lam, 1e-4f);
    float sc  = __builtin_amdgcn_sqrtf(mu) * __builtin_amdgcn_rcpf(fmaxf(lam, 1e-30f));
    float part[16];
    #pragma unroll
    for (int a = 0; a < 16; ++a) part[a] = 0.f;
    #pragma unroll
    for (int r = 0; r < 16; ++r) {
      const float4* w2r = (const float4*)(w2 + (hb + r) * 16);
      ACC16(part, g[r], w2r);
    }
    #pragma unroll
    for (int a = 0; a < 16; ++a) part[a] = dpp_add_xor1(part[a]) * sc;
    CFENCE();
    if (h == 0) {
      *(float4*)(A + kc * 36 + 0)  = make_float4(part[0],  part[1],  part[2],  part[3]);
      *(float4*)(A + kc * 36 + 4)  = make_float4(part[4],  part[5],  part[6],  part[7]);
      *(float4*)(A + kc * 36 + 8)  = make_float4(part[8],  part[9],  part[10], part[11]);
      *(float4*)(A + kc * 36 + 12) = make_float4(part[12], part[13], part[14], part[15]);
    }
    CFENCE();
  }

  // ---- M2 (16x16) into M2R stride 20 (+rank-4 corr); stage w3 ----
  {
    const int a = lane & 15, b0i = (lane >> 4) * 4;
    float m0 = 0.f, m1 = 0.f, m2 = 0.f, m3 = 0.f;
    if (!doeig) {
      #pragma unroll
      for (int kk = 0; kk < 32; ++kk) {
        float za = A[kk * 20 + a];                           // E[a][kk]
        float4 zb = *(const float4*)(w2 + kk * 16 + b0i);    // w2[kk][b..]
        m0 += za * zb.x; m1 += za * zb.y; m2 += za * zb.z; m3 += za * zb.w;
      }
    } else {
      #pragma unroll
      for (int kk = 0; kk < 32; ++kk) {
        float za = A[kk * 36 + a];                           // Z[a][kk]
        float4 zb = *(const float4*)(A + kk * 36 + b0i);     // Z[b..][kk]
        m0 += za * zb.x; m1 += za * zb.y; m2 += za * zb.z; m3 += za * zb.w;
      }
    }
    if (docorr) {
      float4 va = *(const float4*)(VT + a * 4);
      float4 v0 = *(const float4*)(VT + (b0i + 0) * 4);
      float4 v1 = *(const float4*)(VT + (b0i + 1) * 4);
      float4 v2 = *(const float4*)(VT + (b0i + 2) * 4);
      float4 v3 = *(const float4*)(VT + (b0i + 3) * 4);
      m0 += dot4(va, v0); m1 += dot4(va, v1);
      m2 += dot4(va, v2); m3 += dot4(va, v3);
    }
    M2R[(b0i + 0) * 20 + a] = m0;
    M2R[(b0i + 1) * 20 + a] = m1;
    M2R[(b0i + 2) * 20 + a] = m2;
    M2R[(b0i + 3) * 20 + a] = m3;
    W3S[(lane & 3) * 20 + (lane >> 2)] = w3r;   // w3 col-major
  }
  CFENCE();

  // ---- norms of M2 columns ----
  if (lane < 32) {
    int cc = lane >> 1;
    float4 v0 = *(const float4*)(M2R + cc * 20 + 8 * h);
    float4 v1 = *(const float4*)(M2R + cc * 20 + 8 * h + 4);
    float n2 = dot4(v0, v0) + dot4(v1, v1);
    n2 += shfl_xor_f(n2, 1);
    if (h == 0) NRM[cc] = n2;
  }
  CFENCE();

  // ---- chol16 PD certificate on M2, f64 (Cd over A[0,640)) ----
  bool fast2 = true;
  {
    double* Cd = (double*)A;
    const int c16 = lane >> 2, s4 = (lane & 3) * 4;
    #pragma unroll
    for (int r = 0; r < 4; ++r)
      Cd[c16 * 20 + s4 + r] = (double)M2R[c16 * 20 + s4 + r];
    CFENCE();
    if (lane < 16) Cd[lane * 20 + lane] -= DELTA2;
    for (int k = 0; k < 16; ++k) {
      CFENCE();
      double d = Cd[k * 20 + k];
      if (!(d > 0.0)) { fast2 = false; break; }
      double rd = 1.0 / d;
      if (c16 > k) {
        double f = Cd[c16 * 20 + k] * rd;
        #pragma unroll
        for (int r = 0; r < 4; ++r)
          Cd[c16 * 20 + s4 + r] -= f * Cd[k * 20 + s4 + r];
      }
    }
  }
  CFENCE();

  if (fast2) {
    // ---- FAST stage 2: rec2 = M2 ----
    const int k3 = (lane >> 2) & 15, a3 = lane & 3;
    float dotv = 0.f;
    #pragma unroll
    for (int c = 0; c < 4; ++c) {
      float4 gv = *(const float4*)(M2R + k3 * 20 + 4 * c);
      float4 wv = *(const float4*)(W3S + a3 * 20 + 4 * c);
      dotv += dot4(gv, wv);
    }
    CFENCE();
    A[k3 * 4 + a3] = dotv;                 // Y (Cd dead)
    CFENCE();
    if (lane < 16) {
      int a = lane >> 2, b2 = lane & 3;
      float s = 0.f;
      #pragma unroll
      for (int kk = 0; kk < 16; ++kk)
        s += A[kk * 4 + a] * W3S[b2 * 20 + kk];
      A[64 + lane] = s;                    // X3
    }
    CFENCE();
  } else {
    // ---- SLOW stage 2: eig #2 + Y + X3 ----
    jac16(M2R, NRM, lane);
    {
      const int k3 = (lane >> 2) & 15, a3 = lane & 3;
      float dpp2 = 0.f, dotv = 0.f;
      #pragma unroll
      for (int c = 0; c < 4; ++c) {
        float4 gv = *(const float4*)(M2R + k3 * 20 + 4 * c);
        float4 wv = *(const float4*)(W3S + a3 * 20 + 4 * c);
        dpp2 += dot4(gv, gv);
        dotv += dot4(gv, wv);
      }
      float lam2 = __builtin_amdgcn_sqrtf(dpp2);
      float mu2  = fmaxf(lam2, 1e-4f);
      float sc2  = __builtin_amdgcn_sqrtf(mu2) * __builtin_amdgcn_rcpf(fmaxf(lam2, 1e-30f));
      CFENCE();
      A[k3 * 4 + a3] = dotv * sc2;         // Y
    }
    CFENCE();
    if (lane < 16) {
      int a = lane >> 2, b2 = lane & 3;
      float s = 0.f;
      #pragma unroll
      for (int kk = 0; kk < 16; ++kk)
        s += A[kk * 4 + a] * A[kk * 4 + b2];
      A[64 + lane] = s;                    // X3
    }
    CFENCE();
  }

  // ---- stage 3: serial 4x4 two-sided Jacobi + LogEig + fc + log_softmax ----
  if (lane == 0) {
    float Am[4][4], V[4][4];
    float maxdg = 0.f;
    #pragma unroll
    for (int i = 0; i < 4; ++i) {
      #pragma unroll
      for (int j = 0; j < 4; ++j) {
        Am[i][j] = A[64 + i * 4 + j];
        V[i][j] = (i == j) ? 1.f : 0.f;
      }
      maxdg = fmaxf(maxdg, fabsf(Am[i][i]));
    }
    float tol3 = 1e-7f * maxdg;
    for (int sw = 0; sw < MAXSW4; ++sw) {
      bool any = false;
      #pragma unroll
      for (int p = 0; p < 3; ++p) {
        #pragma unroll
        for (int q = p + 1; q < 4; ++q) {
          float apq = Am[p][q];
          if (fabsf(apq) > tol3) {
            any = true;
            float c, sv;
            rot_cs(apq, Am[p][p], Am[q][q], c, sv);
            #pragma unroll
            for (int j = 0; j < 4; ++j) {
              float ap = Am[p][j], aq = Am[q][j];
              Am[p][j] = c * ap - sv * aq;
              Am[q][j] = sv * ap + c * aq;
            }
            #pragma unroll
            for (int i = 0; i < 4; ++i) {
              float ap = Am[i][p], aq = Am[i][q];
              Am[i][p] = c * ap - sv * aq;
              Am[i][q] = sv * ap + c * aq;
              float up = V[i][p], uq = V[i][q];
              V[i][p] = c * up - sv * uq;
              V[i][q] = sv * up + c * uq;
            }
          }
        }
      }
      if (!any) break;
    }
    float lm[4];
    #pragma unroll
    for (int i = 0; i < 4; ++i) lm[i] = logf(fmaxf(Am[i][i], 1e-10f));
    float feat[16];
    #pragma unroll
    for (int i = 0; i < 4; ++i)
      #pragma unroll
      for (int j = 0; j < 4; ++j) {
        float acc2 = 0.f;
        #pragma unroll
        for (int kk = 0; kk < 4; ++kk) acc2 += V[i][kk] * lm[kk] * V[j][kk];
        feat[i * 4 + j] = acc2;
      }
    float z0 = 0.f, z1 = 0.f;
    #pragma unroll
    for (int f = 0; f < 16; ++f) {
      z0 += feat[f] * fcw[f * 2 + 0];
      z1 += feat[f] * fcw[f * 2 + 1];
    }
    float mx = fmaxf(z0, z1);
    float lse = mx + logf(expf(z0 - mx) + expf(z1 - mx));
    out[b * 2 + 0] = z0 - lse;
    out[b * 2 + 1] = z1 - lse;
    float* fo = out + (size_t)2 * B + (size_t)b * 16;
    #pragma unroll
    for (int f = 0; f < 16; ++f) fo[f] = feat[f];
  }
}

extern "C" void kernel_launch(void* const* d_in, const int* in_sizes, int n_in,
                              void* d_out, int out_size, void* d_ws, size_t ws_size,
                              hipStream_t stream) {
  (void)n_in; (void)d_ws; (void)ws_size; (void)out_size;
  const float* x   = (const float*)d_in[0];
  const float* w1  = (const float*)d_in[1];
  const float* w2  = (const float*)d_in[2];
  const float* w3  = (const float*)d_in[3];
  const float* fcw = (const float*)d_in[4];
  float* out = (float*)d_out;
  int B = in_sizes[0] / 1024;
  spdnet_kernel<<<B, 64, 0, stream>>>(x, w1, w2, w3, fcw, out, B);
}

// Round 8
// 1389.425 us; speedup vs baseline: 2.0490x; 2.0490x over previous
//
#include <hip/hip_runtime.h>
#include <math.h>

// SPDNet forward. Round 15: VGPR<=64 via X1-in-LDS + small slice.
// Calibrated launch-bounds law (r12/r13/r14): VGPR cap = 256/min_waves_per_EU
// (granule 8). Occupancy steps at VGPR {64,128,256} -> the only gain past 16
// waves/CU is VGPR<=64 (8 waves/SIMD). r11 hit VGPR=60 with X1 in LDS; r14's
// X1-in-registers pushed natural use to ~128. This round:
//  - X1 dumped to LDS (A, stride 36) right after the matmul; gj_reg loads its
//    rows from LDS at entry (2 loads/pass, NOT per-iteration -> no r10-style
//    conflict tax); T-loop/E/Z read X1 from LDS.
//  - E written IN PLACE over X1 at stride 36 (own-column read-then-write,
//    same pattern as r14's doeig-Z), unifying fast/slow M2 layouts.
//  - Q in a dedicated 128-float region (X1 live through the T-loop).
//  - slice = 1812 floats (7248 B) -> 22 blocks/CU; __launch_bounds__(64,4)
//    -> cap 64. x/w1/w2 still read straight from global.
// Classification math (L, X1, GJ pivots) bitwise-identical to r13/r14
// (passed, absmax 0.0625). E fast-path multiplies by literal 1.0f (exact).
//
// Pipeline (unchanged): partial-spectrum ReEig = register GJ inertia (PB
// broadcast), 2-pass shift-invert, f64 GS + Rayleigh-Ritz, rank-4 correction
// in M2 space; jac32 fallback. Stage 2: f64 chol16 certificate + jac16
// fallback. Stage 3: serial 4x4 Jacobi + LogEig + fc + log_softmax.
// Wave-private LDS, CFENCE only.

#define MAXSW32 8
#define MAXSW16 8
#define MAXSW4  8
#define JTOL2   1e-12f
#define EPS_REC 1e-4f
#define SHIFT1  4e-4f
#define BRKTOL  1e-7f
#define DELTA2  2e-4

#define SLICE   1812
#define OFF_PB  1152
#define OFF_NRM 1188
#define OFF_W3  1220
#define OFF_VT  1300
#define OFF_M2  1364
#define OFF_Q   1684

// Compiler-only memory fence (wave-private LDS: HW-ordered per wave).
#define CFENCE() asm volatile("" ::: "memory")

#define ACC16(part, av, w2r) do { \
  float4 _w0 = (w2r)[0], _w1 = (w2r)[1], _w2 = (w2r)[2], _w3 = (w2r)[3]; \
  float _a = (av); \
  part[0]+=_a*_w0.x; part[1]+=_a*_w0.y; part[2]+=_a*_w0.z; part[3]+=_a*_w0.w; \
  part[4]+=_a*_w1.x; part[5]+=_a*_w1.y; part[6]+=_a*_w1.z; part[7]+=_a*_w1.w; \
  part[8]+=_a*_w2.x; part[9]+=_a*_w2.y; part[10]+=_a*_w2.z; part[11]+=_a*_w2.w; \
  part[12]+=_a*_w3.x; part[13]+=_a*_w3.y; part[14]+=_a*_w3.z; part[15]+=_a*_w3.w; \
} while (0)

// Static component access into a float4 quad set (r compile-time).
#define Q4C(r, v0, v1, v2, v3) \
  ( (r)<8 ? ((r)<4 ? ((r)==0?(v0).x:(r)==1?(v0).y:(r)==2?(v0).z:(v0).w) \
                   : ((r)==4?(v1).x:(r)==5?(v1).y:(r)==6?(v1).z:(v1).w)) \
          : ((r)<12 ? ((r)==8?(v2).x:(r)==9?(v2).y:(r)==10?(v2).z:(v2).w) \
                    : ((r)==12?(v3).x:(r)==13?(v3).y:(r)==14?(v3).z:(v3).w)) )

__device__ __forceinline__ float shfl_xor_f(float v, int m) { return __shfl_xor(v, m, 64); }
__device__ __forceinline__ float dot4(float4 a, float4 b) {
  return a.x * b.x + a.y * b.y + a.z * b.z + a.w * b.w;
}
__device__ __forceinline__ void axpy4(float4& a, float xv, float4 w) {
  a.x += xv * w.x; a.y += xv * w.y; a.z += xv * w.z; a.w += xv * w.w;
}

__device__ __forceinline__ float dpp_add_xor1(float d) {
  return d + __int_as_float(__builtin_amdgcn_mov_dpp(__float_as_int(d), 0xB1, 0xF, 0xF, true));
}
__device__ __forceinline__ float dpp_add_xor2(float d) {
  return d + __int_as_float(__builtin_amdgcn_mov_dpp(__float_as_int(d), 0x4E, 0xF, 0xF, true));
}
__device__ __forceinline__ float dpp_add_halfmirror(float d) {
  return d + __int_as_float(__builtin_amdgcn_mov_dpp(__float_as_int(d), 0x141, 0xF, 0xF, true));
}

__device__ __forceinline__ double dsum64(double v) {
  #pragma unroll
  for (int m = 1; m <= 32; m <<= 1) v += __shfl_xor(v, m, 64);
  return v;
}
__device__ __forceinline__ float wmax64(float v) {
  #pragma unroll
  for (int m = 1; m <= 32; m <<= 1) v = fmaxf(v, __shfl_xor(v, m, 64));
  return v;
}

__device__ __forceinline__ void rot_cs(float d, float dpp, float dqq,
                                       float& c, float& s) {
  float tau = 0.5f * (dqq - dpp);
  float r   = __builtin_amdgcn_sqrtf(fmaf(tau, tau, d * d));
  float den = fabsf(tau) + r;
  float tnum = __uint_as_float(__float_as_uint(d) ^
                               (__float_as_uint(tau) & 0x80000000u));
  float t = tnum * __builtin_amdgcn_rcpf(den);
  c = __builtin_amdgcn_rsqf(fmaf(t, t, 1.f));
  s = t * c;
}

// Register-resident Gauss-Jordan of A = X1 - SHIFT1*I, 4 RHS in regs.
// Rows loaded from X1 in LDS at entry (keeps X1 out of the long-lived set).
__device__ __forceinline__ void gj_reg(const float* __restrict__ X1,
                                       float* __restrict__ PB,
                                       int kc, int h, int hb, float maxd,
                                       float4& y, float& down,
                                       int& mneg, bool& brk) {
  float4 r0 = *(const float4*)(X1 + kc * 36 + hb);
  float4 r1 = *(const float4*)(X1 + kc * 36 + hb + 4);
  float4 r2 = *(const float4*)(X1 + kc * 36 + hb + 8);
  float4 r3 = *(const float4*)(X1 + kc * 36 + hb + 12);
  const int dc = kc - hb;
  r0.x -= (dc == 0)  ? SHIFT1 : 0.f;
  r0.y -= (dc == 1)  ? SHIFT1 : 0.f;
  r0.z -= (dc == 2)  ? SHIFT1 : 0.f;
  r0.w -= (dc == 3)  ? SHIFT1 : 0.f;
  r1.x -= (dc == 4)  ? SHIFT1 : 0.f;
  r1.y -= (dc == 5)  ? SHIFT1 : 0.f;
  r1.z -= (dc == 6)  ? SHIFT1 : 0.f;
  r1.w -= (dc == 7)  ? SHIFT1 : 0.f;
  r2.x -= (dc == 8)  ? SHIFT1 : 0.f;
  r2.y -= (dc == 9)  ? SHIFT1 : 0.f;
  r2.z -= (dc == 10) ? SHIFT1 : 0.f;
  r2.w -= (dc == 11) ? SHIFT1 : 0.f;
  r3.x -= (dc == 12) ? SHIFT1 : 0.f;
  r3.y -= (dc == 13) ? SHIFT1 : 0.f;
  r3.z -= (dc == 14) ? SHIFT1 : 0.f;
  r3.w -= (dc == 15) ? SHIFT1 : 0.f;

  mneg = 0; brk = false; down = 1.f;
  #pragma unroll
  for (int k = 0; k < 32; ++k) {
    if (kc == k) {
      *(float4*)(PB + hb)      = r0;
      *(float4*)(PB + hb + 4)  = r1;
      *(float4*)(PB + hb + 8)  = r2;
      *(float4*)(PB + hb + 12) = r3;
      if (h == 0) *(float4*)(PB + 32) = y;
    }
    CFENCE();
    const float  d  = PB[k];
    const float4 p0 = *(const float4*)(PB + hb);
    const float4 p1 = *(const float4*)(PB + hb + 4);
    const float4 p2 = *(const float4*)(PB + hb + 8);
    const float4 p3 = *(const float4*)(PB + hb + 12);
    const float4 py = *(const float4*)(PB + 32);
    CFENCE();
    mneg += (d <= 0.f) ? 1 : 0;
    brk = brk || !(fabsf(d) >= BRKTOL * maxd);
    float elt;
    {
      const int q = (k >> 2) & 3;
      const float4 rq = (q == 0) ? r0 : (q == 1) ? r1 : (q == 2) ? r2 : r3;
      const int m = k & 3;
      elt = (m == 0) ? rq.x : (m == 1) ? rq.y : (m == 2) ? rq.z : rq.w;
    }
    const bool ownhalf = (k >= 16) ? (h == 1) : (h == 0);
    float tm = ownhalf ? elt : 0.f;
    float f  = dpp_add_xor1(tm);
    float fr = f * __builtin_amdgcn_rcpf(d);
    fr   = (brk || (kc == k)) ? 0.f : fr;
    down = (kc == k) ? d : down;
    axpy4(r0, -fr, p0);
    axpy4(r1, -fr, p1);
    axpy4(r2, -fr, p2);
    axpy4(r3, -fr, p3);
    axpy4(y,  -fr, py);
  }
}

// One-sided Jacobi, n=32, column stride 36. 16 pairs x 4 lanes.
__device__ __forceinline__ void jac32(float* __restrict__ G, float* __restrict__ nrm,
                                      int lane) {
  const int kq  = lane >> 2, sub = lane & 3;
  const int k = (kq & 8) | ((kq & 1) << 2) | (kq & 2) | ((kq & 4) >> 2);
  const int o0 = 4 * sub, o1 = 4 * sub + 16;
  int pp = (k == 0) ? 31 : k;
  int qq = (k == 0) ? 0 : (31 - k);
  for (int sw = 0; sw < MAXSW32; ++sw) {
    bool anyact = false;
    for (int r = 0; r < 31; ++r) {
      CFENCE();
      const int p = pp, q = qq;
      if (k != 0) { pp += 16; if (pp >= 31) pp -= 31; }
      qq += 16; if (qq >= 31) qq -= 31;
      const int pb = p * 36, qb = q * 36;
      float dpp = nrm[p], dqq = nrm[q];
      float4 gp0 = *(const float4*)(G + pb + o0);
      float4 gp1 = *(const float4*)(G + pb + o1);
      float4 gq0 = *(const float4*)(G + qb + o0);
      float4 gq1 = *(const float4*)(G + qb + o1);
      float d = dot4(gp0, gq0) + dot4(gp1, gq1);
      d = dpp_add_xor1(d);
      d = dpp_add_xor2(d);
      bool active = (d * d > JTOL2 * dpp * dqq);
      if (__ballot(active) == 0ull) continue;
      anyact = true;
      if (active) {
        float c, s;
        rot_cs(d, dpp, dqq, c, s);
        float4 np0, np1, nq0, nq1;
        np0.x = c * gp0.x - s * gq0.x; nq0.x = s * gp0.x + c * gq0.x;
        np0.y = c * gp0.y - s * gq0.y; nq0.y = s * gp0.y + c * gq0.y;
        np0.z = c * gp0.z - s * gq0.z; nq0.z = s * gp0.z + c * gq0.z;
        np0.w = c * gp0.w - s * gq0.w; nq0.w = s * gp0.w + c * gq0.w;
        np1.x = c * gp1.x - s * gq1.x; nq1.x = s * gp1.x + c * gq1.x;
        np1.y = c * gp1.y - s * gq1.y; nq1.y = s * gp1.y + c * gq1.y;
        np1.z = c * gp1.z - s * gq1.z; nq1.z = s * gp1.z + c * gq1.z;
        np1.w = c * gp1.w - s * gq1.w; nq1.w = s * gp1.w + c * gq1.w;
        *(float4*)(G + pb + o0) = np0;
        *(float4*)(G + pb + o1) = np1;
        *(float4*)(G + qb + o0) = nq0;
        *(float4*)(G + qb + o1) = nq1;
        if (sub == 0) {
          float cs2 = 2.f * c * s * d, cc = c * c, ss = s * s;
          nrm[p] = cc * dpp - cs2 + ss * dqq;
          nrm[q] = ss * dpp + cs2 + cc * dqq;
        }
      }
    }
    if (!anyact) break;
  }
  CFENCE();
}

// One-sided Jacobi, n=16, column stride 20. 8 pairs x 8 lanes.
__device__ __forceinline__ void jac16(float* __restrict__ G, float* __restrict__ nrm,
                                      int lane) {
  const int kq = lane >> 3, sub = lane & 7;
  const int k = (kq >> 1) | ((kq & 1) << 2);
  const int o = 2 * sub;
  int pp = (k == 0) ? 15 : k;
  int qq = (k == 0) ? 0 : (15 - k);
  for (int sw = 0; sw < MAXSW16; ++sw) {
    bool anyact = false;
    for (int r = 0; r < 15; ++r) {
      CFENCE();
      const int p = pp, q = qq;
      if (k != 0) { pp += 8; if (pp >= 15) pp -= 15; }
      qq += 8; if (qq >= 15) qq -= 15;
      const int pb = p * 20 + o, qb = q * 20 + o;
      float dpp = nrm[p], dqq = nrm[q];
      float2 gp = *(const float2*)(G + pb);
      float2 gq = *(const float2*)(G + qb);
      float d = gp.x * gq.x + gp.y * gq.y;
      d = dpp_add_xor1(d);
      d = dpp_add_xor2(d);
      d = dpp_add_halfmirror(d);
      bool active = (d * d > JTOL2 * dpp * dqq);
      if (__ballot(active) == 0ull) continue;
      anyact = true;
      if (active) {
        float c, s;
        rot_cs(d, dpp, dqq, c, s);
        float2 np, nq;
        np.x = c * gp.x - s * gq.x; nq.x = s * gp.x + c * gq.x;
        np.y = c * gp.y - s * gq.y; nq.y = s * gp.y + c * gq.y;
        *(float2*)(G + pb) = np;
        *(float2*)(G + qb) = nq;
        if (sub == 0) {
          float cs2 = 2.f * c * s * d, cc = c * c, ss = s * s;
          nrm[p] = cc * dpp - cs2 + ss * dqq;
          nrm[q] = ss * dpp + cs2 + cc * dqq;
        }
      }
    }
    if (!anyact) break;
  }
  CFENCE();
}

__launch_bounds__(64, 4)
__global__ void spdnet_kernel(const float* __restrict__ x,
                              const float* __restrict__ w1,
                              const float* __restrict__ w2,
                              const float* __restrict__ w3,
                              const float* __restrict__ fcw,
                              float* __restrict__ out,
                              int B) {
  const int lane = threadIdx.x;
  const int b    = blockIdx.x;

  __shared__ __align__(16) float SH[SLICE];
  float* const A   = SH;             // X1 -> E/Z in place (stride 36) | Cd f64 | Y/X3
  float* const PB  = SH + OFF_PB;    // 36: GJ pivot broadcast
  float* const NRM = SH + OFF_NRM;   // 32
  float* const W3S = SH + OFF_W3;    // 80: w3 col-major stride 20
  float* const VT  = SH + OFF_VT;    // 64: TQ then V
  float* const M2R = SH + OFF_M2;    // 320: M2 stride 20
  float* const QS  = SH + OFF_Q;     // 128: Q rows (4 per row)

  const float* xb = x + (size_t)b * 1024;
  const int kc = lane >> 1, h = lane & 1, hb = h * 16;

  float w3r = w3[lane];

  // ---- L = x*w1 half-columns in regs (a[r] = L[hb+r][kc]) ----
  float4 a0 = {0.f, 0.f, 0.f, 0.f}, a1 = a0, a2 = a0, a3 = a0;
  #pragma unroll
  for (int j = 0; j < 32; ++j) {
    float wv = w1[j * 32 + kc];
    const float4* xr = (const float4*)(xb + j * 32 + hb);
    axpy4(a0, wv, xr[0]);
    axpy4(a1, wv, xr[1]);
    axpy4(a2, wv, xr[2]);
    axpy4(a3, wv, xr[3]);
  }
  // ---- X1 half-row; L[kk][kc] on the fly via pair shfl ----
  {
    float4 b0 = {0.f, 0.f, 0.f, 0.f}, b1 = b0, b2 = b0, b3 = b0;
    #pragma unroll
    for (int kk = 0; kk < 32; ++kk) {
      float own = Q4C(kk & 15, a0, a1, a2, a3);
      float par = shfl_xor_f(own, 1);
      float lv  = ((kk >> 4) == h) ? own : par;
      const float4* wr = (const float4*)(w1 + kk * 32 + hb);
      axpy4(b0, lv, wr[0]);
      axpy4(b1, lv, wr[1]);
      axpy4(b2, lv, wr[2]);
      axpy4(b3, lv, wr[3]);
    }
    float nv = dot4(b0, b0) + dot4(b1, b1) + dot4(b2, b2) + dot4(b3, b3);
    nv += shfl_xor_f(nv, 1);
    // dump X1 to LDS (stride 36); registers b/a die here
    *(float4*)(A + kc * 36 + hb)      = b0;
    *(float4*)(A + kc * 36 + hb + 4)  = b1;
    *(float4*)(A + kc * 36 + hb + 8)  = b2;
    *(float4*)(A + kc * 36 + hb + 12) = b3;
    if (h == 0) NRM[kc] = nv;
  }
  CFENCE();

  // ---- maxd = max diag (uniform pair read) ----
  float maxd = wmax64(A[kc * 36 + kc]);

  // ---- inertia + shift-invert pass 1 ----
  float4 yv;
  {
    unsigned s = kc * 0x9E3779B9u + 0x7F4A7C15u;
    s = s * 1664525u + 1013904223u; yv.x = (float)(int)(s >> 16) - 32768.f;
    s = s * 1664525u + 1013904223u; yv.y = (float)(int)(s >> 16) - 32768.f;
    s = s * 1664525u + 1013904223u; yv.z = (float)(int)(s >> 16) - 32768.f;
    s = s * 1664525u + 1013904223u; yv.w = (float)(int)(s >> 16) - 32768.f;
  }
  int mneg; bool brk; float down;
  gj_reg(A, PB, kc, h, hb, maxd, yv, down, mneg, brk);
  const bool doeig  = brk || (mneg > 4);
  const bool docorr = !doeig && (mneg >= 1);

  if (docorr) {
    // ---- pass 2 (refine) + f64 GS + Rayleigh-Ritz ----
    float rd1 = __builtin_amdgcn_rcpf(down);
    float4 y1 = make_float4(yv.x * rd1, yv.y * rd1, yv.z * rd1, yv.w * rd1);
    int mn2; bool b2; float down2;
    gj_reg(A, PB, kc, h, hb, maxd, y1, down2, mn2, b2);
    (void)mn2; (void)b2;
    float rd2 = __builtin_amdgcn_rcpf(down2);
    double v0 = (double)(y1.x * rd2), v1 = (double)(y1.y * rd2);
    double v2 = (double)(y1.z * rd2), v3 = (double)(y1.w * rd2);
    double n, pr, q0, q1, q2, q3;
    n = 0.5 * dsum64(v0 * v0); q0 = v0 * (1.0 / sqrt(n + 1e-280));
    pr = 0.5 * dsum64(q0 * v1); v1 -= pr * q0;
    n = 0.5 * dsum64(v1 * v1); q1 = v1 * (1.0 / sqrt(n + 1e-280));
    pr = 0.5 * dsum64(q0 * v2); v2 -= pr * q0;
    pr = 0.5 * dsum64(q1 * v2); v2 -= pr * q1;
    n = 0.5 * dsum64(v2 * v2); q2 = v2 * (1.0 / sqrt(n + 1e-280));
    pr = 0.5 * dsum64(q0 * v3); v3 -= pr * q0;
    pr = 0.5 * dsum64(q1 * v3); v3 -= pr * q1;
    pr = 0.5 * dsum64(q2 * v3); v3 -= pr * q2;
    n = 0.5 * dsum64(v3 * v3); q3 = v3 * (1.0 / sqrt(n + 1e-280));
    if (h == 0)
      *(float4*)(QS + 4 * kc) =
          make_float4((float)q0, (float)q1, (float)q2, (float)q3);
    CFENCE();
    // T partials over own half: T[q] += X1[kc][hb+r] * Q[hb+r][q]
    double T0 = 0, T1 = 0, T2 = 0, T3 = 0;
    #pragma unroll
    for (int r = 0; r < 16; ++r) {
      float4 qv = *(const float4*)(QS + 4 * (hb + r));
      double xv = (double)A[kc * 36 + hb + r];
      T0 += xv * qv.x; T1 += xv * qv.y; T2 += xv * qv.z; T3 += xv * qv.w;
    }
    double S00 = dsum64(q0 * T0), S10 = dsum64(q1 * T0);
    double S20 = dsum64(q2 * T0), S30 = dsum64(q3 * T0);
    double S11 = dsum64(q1 * T1), S21 = dsum64(q2 * T1), S31 = dsum64(q3 * T1);
    double S22 = dsum64(q2 * T2), S32 = dsum64(q3 * T2);
    double S33 = dsum64(q3 * T3);
    if (lane == 0) {
      double Ad[4][4] = {{S00, S10, S20, S30}, {S10, S11, S21, S31},
                         {S20, S21, S22, S32}, {S30, S31, S32, S33}};
      float Wd[4][4] = {{1.f, 0.f, 0.f, 0.f}, {0.f, 1.f, 0.f, 0.f},
                        {0.f, 0.f, 1.f, 0.f}, {0.f, 0.f, 0.f, 1.f}};
      for (int sw = 0; sw < 5; ++sw) {
        #pragma unroll
        for (int p = 0; p < 3; ++p) {
          #pragma unroll
          for (int q = p + 1; q < 4; ++q) {
            double apq = Ad[p][q];
            if (fabs(apq) > 1e-14 * (fabs(Ad[p][p]) + fabs(Ad[q][q])) + 1e-300) {
              double tau = 0.5 * (Ad[q][q] - Ad[p][p]);
              double rr = sqrt(tau * tau + apq * apq);
              double t = ((tau >= 0.0) ? apq : -apq) / (fabs(tau) + rr);
              double c = 1.0 / sqrt(t * t + 1.0), sv = t * c;
              #pragma unroll
              for (int jj = 0; jj < 4; ++jj) {
                double ap = Ad[p][jj], aq = Ad[q][jj];
                Ad[p][jj] = c * ap - sv * aq;
                Ad[q][jj] = sv * ap + c * aq;
              }
              #pragma unroll
              for (int ii = 0; ii < 4; ++ii) {
                double ap = Ad[ii][p], aq = Ad[ii][q];
                Ad[ii][p] = c * ap - sv * aq;
                Ad[ii][q] = sv * ap + c * aq;
                float wp = Wd[ii][p], wq = Wd[ii][q];
                Wd[ii][p] = (float)(c * wp - sv * wq);
                Wd[ii][q] = (float)(sv * wp + c * wq);
              }
            }
          }
        }
      }
      #pragma unroll
      for (int qi = 0; qi < 4; ++qi) {
        NRM[16 + qi] = (float)Ad[qi][qi];
        #pragma unroll
        for (int ai = 0; ai < 4; ++ai) NRM[ai * 4 + qi] = Wd[ai][qi];
      }
    }
    CFENCE();
  }

  if (doeig) {
    // ---- fallback: full one-sided Jacobi on X1 (already in LDS) ----
    jac32(A, NRM, lane);
  }

  // ---- E (fast: scz=1) / Z (slow: scz=sqrt(mu)/lam) in place over A cols ----
  {
    float g[16];
    #pragma unroll
    for (int c = 0; c < 4; ++c) {
      float4 v = *(const float4*)(A + kc * 36 + hb + 4 * c);
      g[4 * c] = v.x; g[4 * c + 1] = v.y; g[4 * c + 2] = v.z; g[4 * c + 3] = v.w;
    }
    float scz = 1.f;
    if (doeig) {
      float dpp = 0.f;
      #pragma unroll
      for (int i = 0; i < 16; ++i) dpp += g[i] * g[i];
      dpp += shfl_xor_f(dpp, 1);
      float lam = __builtin_amdgcn_sqrtf(dpp);
      float mu  = fmaxf(lam, 1e-4f);
      scz = __builtin_amdgcn_sqrtf(mu) * __builtin_amdgcn_rcpf(fmaxf(lam, 1e-30f));
    }
    float part[16];
    #pragma unroll
    for (int a = 0; a < 16; ++a) part[a] = 0.f;
    #pragma unroll
    for (int r = 0; r < 16; ++r) {
      const float4* w2r = (const float4*)(w2 + (hb + r) * 16);
      ACC16(part, g[r], w2r);
    }
    #pragma unroll
    for (int a = 0; a < 16; ++a) part[a] = dpp_add_xor1(part[a]) * scz;
    CFENCE();
    if (h == 0) {
      *(float4*)(A + kc * 36 + 0)  = make_float4(part[0],  part[1],  part[2],  part[3]);
      *(float4*)(A + kc * 36 + 4)  = make_float4(part[4],  part[5],  part[6],  part[7]);
      *(float4*)(A + kc * 36 + 8)  = make_float4(part[8],  part[9],  part[10], part[11]);
      *(float4*)(A + kc * 36 + 12) = make_float4(part[12], part[13], part[14], part[15]);
    }
    CFENCE();
  }

  if (docorr) {
    // ---- TQ = w2^T Q ----
    const int aq = lane >> 4, a16 = lane & 15;
    float tq = 0.f;
    #pragma unroll 4
    for (int j = 0; j < 32; ++j)
      tq += w2[j * 16 + a16] * QS[4 * j + aq];
    VT[aq * 16 + a16] = tq;
    CFENCE();
    if (lane < 16) {
      float t0 = VT[lane], t1 = VT[16 + lane];
      float t2 = VT[32 + lane], t3 = VT[48 + lane];
      float4 vv;
      {
        float cs = __builtin_amdgcn_sqrtf(fmaxf(EPS_REC - NRM[16], 0.f));
        vv.x = cs * (t0 * NRM[0] + t1 * NRM[4] + t2 * NRM[8] + t3 * NRM[12]);
      }
      {
        float cs = __builtin_amdgcn_sqrtf(fmaxf(EPS_REC - NRM[17], 0.f));
        vv.y = cs * (t0 * NRM[1] + t1 * NRM[5] + t2 * NRM[9] + t3 * NRM[13]);
      }
      {
        float cs = __builtin_amdgcn_sqrtf(fmaxf(EPS_REC - NRM[18], 0.f));
        vv.z = cs * (t0 * NRM[2] + t1 * NRM[6] + t2 * NRM[10] + t3 * NRM[14]);
      }
      {
        float cs = __builtin_amdgcn_sqrtf(fmaxf(EPS_REC - NRM[19], 0.f));
        vv.w = cs * (t0 * NRM[3] + t1 * NRM[7] + t2 * NRM[11] + t3 * NRM[15]);
      }
      CFENCE();
      *(float4*)(VT + lane * 4) = vv;
    }
    CFENCE();
  }

  // ---- M2 (16x16) into M2R stride 20 (+rank-4 corr); stage w3 ----
  {
    const int a = lane & 15, b0i = (lane >> 4) * 4;
    float m0 = 0.f, m1 = 0.f, m2 = 0.f, m3 = 0.f;
    if (!doeig) {
      #pragma unroll
      for (int kk = 0; kk < 32; ++kk) {
        float za = A[kk * 36 + a];                           // E[a][kk]
        float4 zb = *(const float4*)(w2 + kk * 16 + b0i);    // w2[kk][b..]
        m0 += za * zb.x; m1 += za * zb.y; m2 += za * zb.z; m3 += za * zb.w;
      }
    } else {
      #pragma unroll
      for (int kk = 0; kk < 32; ++kk) {
        float za = A[kk * 36 + a];                           // Z[a][kk]
        float4 zb = *(const float4*)(A + kk * 36 + b0i);     // Z[b..][kk]
        m0 += za * zb.x; m1 += za * zb.y; m2 += za * zb.z; m3 += za * zb.w;
      }
    }
    if (docorr) {
      float4 va = *(const float4*)(VT + a * 4);
      float4 v0 = *(const float4*)(VT + (b0i + 0) * 4);
      float4 v1 = *(const float4*)(VT + (b0i + 1) * 4);
      float4 v2 = *(const float4*)(VT + (b0i + 2) * 4);
      float4 v3 = *(const float4*)(VT + (b0i + 3) * 4);
      m0 += dot4(va, v0); m1 += dot4(va, v1);
      m2 += dot4(va, v2); m3 += dot4(va, v3);
    }
    M2R[(b0i + 0) * 20 + a] = m0;
    M2R[(b0i + 1) * 20 + a] = m1;
    M2R[(b0i + 2) * 20 + a] = m2;
    M2R[(b0i + 3) * 20 + a] = m3;
    W3S[(lane & 3) * 20 + (lane >> 2)] = w3r;   // w3 col-major
  }
  CFENCE();

  // ---- norms of M2 columns ----
  if (lane < 32) {
    int cc = lane >> 1;
    float4 v0 = *(const float4*)(M2R + cc * 20 + 8 * h);
    float4 v1 = *(const float4*)(M2R + cc * 20 + 8 * h + 4);
    float n2 = dot4(v0, v0) + dot4(v1, v1);
    n2 += shfl_xor_f(n2, 1);
    if (h == 0) NRM[cc] = n2;
  }
  CFENCE();

  // ---- chol16 PD certificate on M2, f64 (Cd over A[0,640)) ----
  bool fast2 = true;
  {
    double* Cd = (double*)A;
    const int c16 = lane >> 2, s4 = (lane & 3) * 4;
    #pragma unroll
    for (int r = 0; r < 4; ++r)
      Cd[c16 * 20 + s4 + r] = (double)M2R[c16 * 20 + s4 + r];
    CFENCE();
    if (lane < 16) Cd[lane * 20 + lane] -= DELTA2;
    for (int k = 0; k < 16; ++k) {
      CFENCE();
      double d = Cd[k * 20 + k];
      if (!(d > 0.0)) { fast2 = false; break; }
      double rd = 1.0 / d;
      if (c16 > k) {
        double f = Cd[c16 * 20 + k] * rd;
        #pragma unroll
        for (int r = 0; r < 4; ++r)
          Cd[c16 * 20 + s4 + r] -= f * Cd[k * 20 + s4 + r];
      }
    }
  }
  CFENCE();

  if (fast2) {
    // ---- FAST stage 2: rec2 = M2 ----
    const int k3 = (lane >> 2) & 15, a3 = lane & 3;
    float dotv = 0.f;
    #pragma unroll
    for (int c = 0; c < 4; ++c) {
      float4 gv = *(const float4*)(M2R + k3 * 20 + 4 * c);
      float4 wv = *(const float4*)(W3S + a3 * 20 + 4 * c);
      dotv += dot4(gv, wv);
    }
    CFENCE();
    A[k3 * 4 + a3] = dotv;                 // Y (Cd dead)
    CFENCE();
    if (lane < 16) {
      int a = lane >> 2, b2 = lane & 3;
      float s = 0.f;
      #pragma unroll
      for (int kk = 0; kk < 16; ++kk)
        s += A[kk * 4 + a] * W3S[b2 * 20 + kk];
      A[64 + lane] = s;                    // X3
    }
    CFENCE();
  } else {
    // ---- SLOW stage 2: eig #2 + Y + X3 ----
    jac16(M2R, NRM, lane);
    {
      const int k3 = (lane >> 2) & 15, a3 = lane & 3;
      float dpp2 = 0.f, dotv = 0.f;
      #pragma unroll
      for (int c = 0; c < 4; ++c) {
        float4 gv = *(const float4*)(M2R + k3 * 20 + 4 * c);
        float4 wv = *(const float4*)(W3S + a3 * 20 + 4 * c);
        dpp2 += dot4(gv, gv);
        dotv += dot4(gv, wv);
      }
      float lam2 = __builtin_amdgcn_sqrtf(dpp2);
      float mu2  = fmaxf(lam2, 1e-4f);
      float sc2  = __builtin_amdgcn_sqrtf(mu2) * __builtin_amdgcn_rcpf(fmaxf(lam2, 1e-30f));
      CFENCE();
      A[k3 * 4 + a3] = dotv * sc2;         // Y
    }
    CFENCE();
    if (lane < 16) {
      int a = lane >> 2, b2 = lane & 3;
      float s = 0.f;
      #pragma unroll
      for (int kk = 0; kk < 16; ++kk)
        s += A[kk * 4 + a] * A[kk * 4 + b2];
      A[64 + lane] = s;                    // X3
    }
    CFENCE();
  }

  // ---- stage 3: serial 4x4 two-sided Jacobi + LogEig + fc + log_softmax ----
  if (lane == 0) {
    float Am[4][4], V[4][4];
    float maxdg = 0.f;
    #pragma unroll
    for (int i = 0; i < 4; ++i) {
      #pragma unroll
      for (int j = 0; j < 4; ++j) {
        Am[i][j] = A[64 + i * 4 + j];
        V[i][j] = (i == j) ? 1.f : 0.f;
      }
      maxdg = fmaxf(maxdg, fabsf(Am[i][i]));
    }
    float tol3 = 1e-7f * maxdg;
    for (int sw = 0; sw < MAXSW4; ++sw) {
      bool any = false;
      #pragma unroll
      for (int p = 0; p < 3; ++p) {
        #pragma unroll
        for (int q = p + 1; q < 4; ++q) {
          float apq = Am[p][q];
          if (fabsf(apq) > tol3) {
            any = true;
            float c, sv;
            rot_cs(apq, Am[p][p], Am[q][q], c, sv);
            #pragma unroll
            for (int j = 0; j < 4; ++j) {
              float ap = Am[p][j], aq = Am[q][j];
              Am[p][j] = c * ap - sv * aq;
              Am[q][j] = sv * ap + c * aq;
            }
            #pragma unroll
            for (int i = 0; i < 4; ++i) {
              float ap = Am[i][p], aq = Am[i][q];
              Am[i][p] = c * ap - sv * aq;
              Am[i][q] = sv * ap + c * aq;
              float up = V[i][p], uq = V[i][q];
              V[i][p] = c * up - sv * uq;
              V[i][q] = sv * up + c * uq;
            }
          }
        }
      }
      if (!any) break;
    }
    float lm[4];
    #pragma unroll
    for (int i = 0; i < 4; ++i) lm[i] = logf(fmaxf(Am[i][i], 1e-10f));
    float feat[16];
    #pragma unroll
    for (int i = 0; i < 4; ++i)
      #pragma unroll
      for (int j = 0; j < 4; ++j) {
        float acc2 = 0.f;
        #pragma unroll
        for (int kk = 0; kk < 4; ++kk) acc2 += V[i][kk] * lm[kk] * V[j][kk];
        feat[i * 4 + j] = acc2;
      }
    float z0 = 0.f, z1 = 0.f;
    #pragma unroll
    for (int f = 0; f < 16; ++f) {
      z0 += feat[f] * fcw[f * 2 + 0];
      z1 += feat[f] * fcw[f * 2 + 1];
    }
    float mx = fmaxf(z0, z1);
    float lse = mx + logf(expf(z0 - mx) + expf(z1 - mx));
    out[b * 2 + 0] = z0 - lse;
    out[b * 2 + 1] = z1 - lse;
    float* fo = out + (size_t)2 * B + (size_t)b * 16;
    #pragma unroll
    for (int f = 0; f < 16; ++f) fo[f] = feat[f];
  }
}

extern "C" void kernel_launch(void* const* d_in, const int* in_sizes, int n_in,
                              void* d_out, int out_size, void* d_ws, size_t ws_size,
                              hipStream_t stream) {
  (void)n_in; (void)d_ws; (void)ws_size; (void)out_size;
  const float* x   = (const float*)d_in[0];
  const float* w1  = (const float*)d_in[1];
  const float* w2  = (const float*)d_in[2];
  const float* w3  = (const float*)d_in[3];
  const float* fcw = (const float*)d_in[4];
  float* out = (float*)d_out;
  int B = in_sizes[0] / 1024;
  spdnet_kernel<<<B, 64, 0, stream>>>(x, w1, w2, w3, fcw, out, B);
}

// Round 9
// 822.464 us; speedup vs baseline: 3.4615x; 1.6893x over previous
//
#include <hip/hip_runtime.h>
#include <math.h>

// SPDNet forward. Round 16: natural VGPR<=64 + 8KB slice.
// Calibrated: __launch_bounds__ 2nd arg forces cap = 256/w -> any forced cap
// below natural demand (~128 for global-operand matmuls) spills catastrophically
// (r15: 4GB scratch). r11's natural 60 VGPR came from LDS-operand matmuls.
// This round reproduces that register profile inside a 2004-float slice:
//  - x staged in A (stride 32); L-loop: x from LDS + w1 scalar-broadcast
//    global (1 scalar/iter in flight, unroll 8).
//  - L parked over dead x (stride 32); a-regs die; X1-loop: lv from LDS +
//    w1 rows global (unroll 4). Same FMA order -> classification bitwise
//    identical to r13/r15 (passed, absmax 0.0625).
//  - w2 staged in W2S (512) -> E/Z/TQ/M2 read it from LDS.
//  - Overlays: X1/E/Z stride 36 over A; M2 in place over dead E at A[0,320)
//    (all-reads-before-stores, wave lockstep); Cd f64 at A+320; Y@A+320,
//    X3@A+384 (Cd dead). No M2R region. Slice 2004 fl = 8016B -> ~19
//    blocks/CU at 1 wave each; VGPR<=64 natural -> up to 8 waves/SIMD.
// __launch_bounds__(64) plain: natural allocation, no forced spill.
//
// Pipeline (unchanged): partial-spectrum ReEig = register GJ inertia (PB
// broadcast), 2-pass shift-invert, f64 GS + Rayleigh-Ritz, rank-4 correction
// in M2 space; jac32 fallback. Stage 2: f64 chol16 certificate + jac16
// fallback. Stage 3: serial 4x4 Jacobi + LogEig + fc + log_softmax.
// Wave-private LDS, CFENCE only.

#define MAXSW32 8
#define MAXSW16 8
#define MAXSW4  8
#define JTOL2   1e-12f
#define EPS_REC 1e-4f
#define SHIFT1  4e-4f
#define BRKTOL  1e-7f
#define DELTA2  2e-4

#define SLICE   2004
#define OFF_PB  1152
#define OFF_NRM 1188
#define OFF_W3  1220
#define OFF_VT  1300
#define OFF_Q   1364
#define OFF_W2  1492

// Compiler-only memory fence (wave-private LDS: HW-ordered per wave).
#define CFENCE() asm volatile("" ::: "memory")

#define ACC16(part, av, w2r) do { \
  float4 _w0 = (w2r)[0], _w1 = (w2r)[1], _w2 = (w2r)[2], _w3 = (w2r)[3]; \
  float _a = (av); \
  part[0]+=_a*_w0.x; part[1]+=_a*_w0.y; part[2]+=_a*_w0.z; part[3]+=_a*_w0.w; \
  part[4]+=_a*_w1.x; part[5]+=_a*_w1.y; part[6]+=_a*_w1.z; part[7]+=_a*_w1.w; \
  part[8]+=_a*_w2.x; part[9]+=_a*_w2.y; part[10]+=_a*_w2.z; part[11]+=_a*_w2.w; \
  part[12]+=_a*_w3.x; part[13]+=_a*_w3.y; part[14]+=_a*_w3.z; part[15]+=_a*_w3.w; \
} while (0)

__device__ __forceinline__ float shfl_xor_f(float v, int m) { return __shfl_xor(v, m, 64); }
__device__ __forceinline__ float dot4(float4 a, float4 b) {
  return a.x * b.x + a.y * b.y + a.z * b.z + a.w * b.w;
}
__device__ __forceinline__ void axpy4(float4& a, float xv, float4 w) {
  a.x += xv * w.x; a.y += xv * w.y; a.z += xv * w.z; a.w += xv * w.w;
}

__device__ __forceinline__ float dpp_add_xor1(float d) {
  return d + __int_as_float(__builtin_amdgcn_mov_dpp(__float_as_int(d), 0xB1, 0xF, 0xF, true));
}
__device__ __forceinline__ float dpp_add_xor2(float d) {
  return d + __int_as_float(__builtin_amdgcn_mov_dpp(__float_as_int(d), 0x4E, 0xF, 0xF, true));
}
__device__ __forceinline__ float dpp_add_halfmirror(float d) {
  return d + __int_as_float(__builtin_amdgcn_mov_dpp(__float_as_int(d), 0x141, 0xF, 0xF, true));
}

__device__ __forceinline__ double dsum64(double v) {
  #pragma unroll
  for (int m = 1; m <= 32; m <<= 1) v += __shfl_xor(v, m, 64);
  return v;
}
__device__ __forceinline__ float wmax64(float v) {
  #pragma unroll
  for (int m = 1; m <= 32; m <<= 1) v = fmaxf(v, __shfl_xor(v, m, 64));
  return v;
}

__device__ __forceinline__ void rot_cs(float d, float dpp, float dqq,
                                       float& c, float& s) {
  float tau = 0.5f * (dqq - dpp);
  float r   = __builtin_amdgcn_sqrtf(fmaf(tau, tau, d * d));
  float den = fabsf(tau) + r;
  float tnum = __uint_as_float(__float_as_uint(d) ^
                               (__float_as_uint(tau) & 0x80000000u));
  float t = tnum * __builtin_amdgcn_rcpf(den);
  c = __builtin_amdgcn_rsqf(fmaf(t, t, 1.f));
  s = t * c;
}

// Register-resident Gauss-Jordan of A = X1 - SHIFT1*I, 4 RHS in regs.
// Rows loaded from X1 in LDS (stride 36) at entry.
__device__ __forceinline__ void gj_reg(const float* __restrict__ X1,
                                       float* __restrict__ PB,
                                       int kc, int h, int hb, float maxd,
                                       float4& y, float& down,
                                       int& mneg, bool& brk) {
  float4 r0 = *(const float4*)(X1 + kc * 36 + hb);
  float4 r1 = *(const float4*)(X1 + kc * 36 + hb + 4);
  float4 r2 = *(const float4*)(X1 + kc * 36 + hb + 8);
  float4 r3 = *(const float4*)(X1 + kc * 36 + hb + 12);
  const int dc = kc - hb;
  r0.x -= (dc == 0)  ? SHIFT1 : 0.f;
  r0.y -= (dc == 1)  ? SHIFT1 : 0.f;
  r0.z -= (dc == 2)  ? SHIFT1 : 0.f;
  r0.w -= (dc == 3)  ? SHIFT1 : 0.f;
  r1.x -= (dc == 4)  ? SHIFT1 : 0.f;
  r1.y -= (dc == 5)  ? SHIFT1 : 0.f;
  r1.z -= (dc == 6)  ? SHIFT1 : 0.f;
  r1.w -= (dc == 7)  ? SHIFT1 : 0.f;
  r2.x -= (dc == 8)  ? SHIFT1 : 0.f;
  r2.y -= (dc == 9)  ? SHIFT1 : 0.f;
  r2.z -= (dc == 10) ? SHIFT1 : 0.f;
  r2.w -= (dc == 11) ? SHIFT1 : 0.f;
  r3.x -= (dc == 12) ? SHIFT1 : 0.f;
  r3.y -= (dc == 13) ? SHIFT1 : 0.f;
  r3.z -= (dc == 14) ? SHIFT1 : 0.f;
  r3.w -= (dc == 15) ? SHIFT1 : 0.f;

  mneg = 0; brk = false; down = 1.f;
  #pragma unroll
  for (int k = 0; k < 32; ++k) {
    if (kc == k) {
      *(float4*)(PB + hb)      = r0;
      *(float4*)(PB + hb + 4)  = r1;
      *(float4*)(PB + hb + 8)  = r2;
      *(float4*)(PB + hb + 12) = r3;
      if (h == 0) *(float4*)(PB + 32) = y;
    }
    CFENCE();
    const float  d  = PB[k];
    const float4 p0 = *(const float4*)(PB + hb);
    const float4 p1 = *(const float4*)(PB + hb + 4);
    const float4 p2 = *(const float4*)(PB + hb + 8);
    const float4 p3 = *(const float4*)(PB + hb + 12);
    const float4 py = *(const float4*)(PB + 32);
    CFENCE();
    mneg += (d <= 0.f) ? 1 : 0;
    brk = brk || !(fabsf(d) >= BRKTOL * maxd);
    float elt;
    {
      const int q = (k >> 2) & 3;
      const float4 rq = (q == 0) ? r0 : (q == 1) ? r1 : (q == 2) ? r2 : r3;
      const int m = k & 3;
      elt = (m == 0) ? rq.x : (m == 1) ? rq.y : (m == 2) ? rq.z : rq.w;
    }
    const bool ownhalf = (k >= 16) ? (h == 1) : (h == 0);
    float tm = ownhalf ? elt : 0.f;
    float f  = dpp_add_xor1(tm);
    float fr = f * __builtin_amdgcn_rcpf(d);
    fr   = (brk || (kc == k)) ? 0.f : fr;
    down = (kc == k) ? d : down;
    axpy4(r0, -fr, p0);
    axpy4(r1, -fr, p1);
    axpy4(r2, -fr, p2);
    axpy4(r3, -fr, p3);
    axpy4(y,  -fr, py);
  }
}

// One-sided Jacobi, n=32, column stride 36. 16 pairs x 4 lanes.
__device__ __forceinline__ void jac32(float* __restrict__ G, float* __restrict__ nrm,
                                      int lane) {
  const int kq  = lane >> 2, sub = lane & 3;
  const int k = (kq & 8) | ((kq & 1) << 2) | (kq & 2) | ((kq & 4) >> 2);
  const int o0 = 4 * sub, o1 = 4 * sub + 16;
  int pp = (k == 0) ? 31 : k;
  int qq = (k == 0) ? 0 : (31 - k);
  for (int sw = 0; sw < MAXSW32; ++sw) {
    bool anyact = false;
    for (int r = 0; r < 31; ++r) {
      CFENCE();
      const int p = pp, q = qq;
      if (k != 0) { pp += 16; if (pp >= 31) pp -= 31; }
      qq += 16; if (qq >= 31) qq -= 31;
      const int pb = p * 36, qb = q * 36;
      float dpp = nrm[p], dqq = nrm[q];
      float4 gp0 = *(const float4*)(G + pb + o0);
      float4 gp1 = *(const float4*)(G + pb + o1);
      float4 gq0 = *(const float4*)(G + qb + o0);
      float4 gq1 = *(const float4*)(G + qb + o1);
      float d = dot4(gp0, gq0) + dot4(gp1, gq1);
      d = dpp_add_xor1(d);
      d = dpp_add_xor2(d);
      bool active = (d * d > JTOL2 * dpp * dqq);
      if (__ballot(active) == 0ull) continue;
      anyact = true;
      if (active) {
        float c, s;
        rot_cs(d, dpp, dqq, c, s);
        float4 np0, np1, nq0, nq1;
        np0.x = c * gp0.x - s * gq0.x; nq0.x = s * gp0.x + c * gq0.x;
        np0.y = c * gp0.y - s * gq0.y; nq0.y = s * gp0.y + c * gq0.y;
        np0.z = c * gp0.z - s * gq0.z; nq0.z = s * gp0.z + c * gq0.z;
        np0.w = c * gp0.w - s * gq0.w; nq0.w = s * gp0.w + c * gq0.w;
        np1.x = c * gp1.x - s * gq1.x; nq1.x = s * gp1.x + c * gq1.x;
        np1.y = c * gp1.y - s * gq1.y; nq1.y = s * gp1.y + c * gq1.y;
        np1.z = c * gp1.z - s * gq1.z; nq1.z = s * gp1.z + c * gq1.z;
        np1.w = c * gp1.w - s * gq1.w; nq1.w = s * gp1.w + c * gq1.w;
        *(float4*)(G + pb + o0) = np0;
        *(float4*)(G + pb + o1) = np1;
        *(float4*)(G + qb + o0) = nq0;
        *(float4*)(G + qb + o1) = nq1;
        if (sub == 0) {
          float cs2 = 2.f * c * s * d, cc = c * c, ss = s * s;
          nrm[p] = cc * dpp - cs2 + ss * dqq;
          nrm[q] = ss * dpp + cs2 + cc * dqq;
        }
      }
    }
    if (!anyact) break;
  }
  CFENCE();
}

// One-sided Jacobi, n=16, column stride 20. 8 pairs x 8 lanes.
__device__ __forceinline__ void jac16(float* __restrict__ G, float* __restrict__ nrm,
                                      int lane) {
  const int kq = lane >> 3, sub = lane & 7;
  const int k = (kq >> 1) | ((kq & 1) << 2);
  const int o = 2 * sub;
  int pp = (k == 0) ? 15 : k;
  int qq = (k == 0) ? 0 : (15 - k);
  for (int sw = 0; sw < MAXSW16; ++sw) {
    bool anyact = false;
    for (int r = 0; r < 15; ++r) {
      CFENCE();
      const int p = pp, q = qq;
      if (k != 0) { pp += 8; if (pp >= 15) pp -= 15; }
      qq += 8; if (qq >= 15) qq -= 15;
      const int pb = p * 20 + o, qb = q * 20 + o;
      float dpp = nrm[p], dqq = nrm[q];
      float2 gp = *(const float2*)(G + pb);
      float2 gq = *(const float2*)(G + qb);
      float d = gp.x * gq.x + gp.y * gq.y;
      d = dpp_add_xor1(d);
      d = dpp_add_xor2(d);
      d = dpp_add_halfmirror(d);
      bool active = (d * d > JTOL2 * dpp * dqq);
      if (__ballot(active) == 0ull) continue;
      anyact = true;
      if (active) {
        float c, s;
        rot_cs(d, dpp, dqq, c, s);
        float2 np, nq;
        np.x = c * gp.x - s * gq.x; nq.x = s * gp.x + c * gq.x;
        np.y = c * gp.y - s * gq.y; nq.y = s * gp.y + c * gq.y;
        *(float2*)(G + pb) = np;
        *(float2*)(G + qb) = nq;
        if (sub == 0) {
          float cs2 = 2.f * c * s * d, cc = c * c, ss = s * s;
          nrm[p] = cc * dpp - cs2 + ss * dqq;
          nrm[q] = ss * dpp + cs2 + cc * dqq;
        }
      }
    }
    if (!anyact) break;
  }
  CFENCE();
}

__launch_bounds__(64)
__global__ void spdnet_kernel(const float* __restrict__ x,
                              const float* __restrict__ w1,
                              const float* __restrict__ w2,
                              const float* __restrict__ w3,
                              const float* __restrict__ fcw,
                              float* __restrict__ out,
                              int B) {
  const int lane = threadIdx.x;
  const int b    = blockIdx.x;

  __shared__ __align__(16) float SH[SLICE];
  float* const A   = SH;             // x(s32) -> L(s32) -> X1/E/Z(s36) -> M2(s20,[0,320)) | Cd f64 @320 | Y@320 X3@384
  float* const PB  = SH + OFF_PB;    // 36: GJ pivot broadcast
  float* const NRM = SH + OFF_NRM;   // 32
  float* const W3S = SH + OFF_W3;    // 80: w3 col-major stride 20
  float* const VT  = SH + OFF_VT;    // 64: TQ then V
  float* const QS  = SH + OFF_Q;     // 128: Q rows (4 per row)
  float* const W2S = SH + OFF_W2;    // 512: w2 row-major

  const float* xb = x + (size_t)b * 1024;
  const int kc = lane >> 1, h = lane & 1, hb = h * 16;

  float w3r = w3[lane];

  // ---- stage x -> A[0,1024) (stride 32) and w2 -> W2S ----
  #pragma unroll
  for (int t = 0; t < 4; ++t)
    ((float4*)A)[lane + 64 * t] = ((const float4*)xb)[lane + 64 * t];
  #pragma unroll
  for (int t = 0; t < 2; ++t)
    ((float4*)W2S)[lane + 64 * t] = ((const float4*)w2)[lane + 64 * t];
  CFENCE();

  // ---- L = x*w1 half-columns in regs (a[r] = L[hb+r][kc]); x from LDS ----
  float4 a0 = {0.f, 0.f, 0.f, 0.f}, a1 = a0, a2 = a0, a3 = a0;
  #pragma unroll 8
  for (int j = 0; j < 32; ++j) {
    float wv = w1[j * 32 + kc];              // 128B broadcast segment, L1
    const float4* xr = (const float4*)(A + j * 32 + hb);
    axpy4(a0, wv, xr[0]);
    axpy4(a1, wv, xr[1]);
    axpy4(a2, wv, xr[2]);
    axpy4(a3, wv, xr[3]);
  }
  CFENCE();                                  // all x reads done
  // ---- park L over dead x: A[j*32 + kc] = L[j][kc] ----
  A[(hb + 0)  * 32 + kc] = a0.x; A[(hb + 1)  * 32 + kc] = a0.y;
  A[(hb + 2)  * 32 + kc] = a0.z; A[(hb + 3)  * 32 + kc] = a0.w;
  A[(hb + 4)  * 32 + kc] = a1.x; A[(hb + 5)  * 32 + kc] = a1.y;
  A[(hb + 6)  * 32 + kc] = a1.z; A[(hb + 7)  * 32 + kc] = a1.w;
  A[(hb + 8)  * 32 + kc] = a2.x; A[(hb + 9)  * 32 + kc] = a2.y;
  A[(hb + 10) * 32 + kc] = a2.z; A[(hb + 11) * 32 + kc] = a2.w;
  A[(hb + 12) * 32 + kc] = a3.x; A[(hb + 13) * 32 + kc] = a3.y;
  A[(hb + 14) * 32 + kc] = a3.z; A[(hb + 15) * 32 + kc] = a3.w;
  CFENCE();

  // ---- X1 half-row (b regs); lv = L[kk][kc] from LDS ----
  {
    float4 b0 = {0.f, 0.f, 0.f, 0.f}, b1 = b0, b2 = b0, b3 = b0;
    #pragma unroll 4
    for (int kk = 0; kk < 32; ++kk) {
      float lv = A[kk * 32 + kc];            // pair-broadcast LDS read
      const float4* wr = (const float4*)(w1 + kk * 32 + hb);
      axpy4(b0, lv, wr[0]);
      axpy4(b1, lv, wr[1]);
      axpy4(b2, lv, wr[2]);
      axpy4(b3, lv, wr[3]);
    }
    float nv = dot4(b0, b0) + dot4(b1, b1) + dot4(b2, b2) + dot4(b3, b3);
    nv += shfl_xor_f(nv, 1);
    CFENCE();                                // all L reads done
    // dump X1 over L (stride 36)
    *(float4*)(A + kc * 36 + hb)      = b0;
    *(float4*)(A + kc * 36 + hb + 4)  = b1;
    *(float4*)(A + kc * 36 + hb + 8)  = b2;
    *(float4*)(A + kc * 36 + hb + 12) = b3;
    if (h == 0) NRM[kc] = nv;
  }
  CFENCE();

  // ---- maxd = max diag (uniform pair read) ----
  float maxd = wmax64(A[kc * 36 + kc]);

  // ---- inertia + shift-invert pass 1 ----
  float4 yv;
  {
    unsigned s = kc * 0x9E3779B9u + 0x7F4A7C15u;
    s = s * 1664525u + 1013904223u; yv.x = (float)(int)(s >> 16) - 32768.f;
    s = s * 1664525u + 1013904223u; yv.y = (float)(int)(s >> 16) - 32768.f;
    s = s * 1664525u + 1013904223u; yv.z = (float)(int)(s >> 16) - 32768.f;
    s = s * 1664525u + 1013904223u; yv.w = (float)(int)(s >> 16) - 32768.f;
  }
  int mneg; bool brk; float down;
  gj_reg(A, PB, kc, h, hb, maxd, yv, down, mneg, brk);
  const bool doeig  = brk || (mneg > 4);
  const bool docorr = !doeig && (mneg >= 1);

  if (docorr) {
    // ---- pass 2 (refine) + f64 GS + Rayleigh-Ritz ----
    float rd1 = __builtin_amdgcn_rcpf(down);
    float4 y1 = make_float4(yv.x * rd1, yv.y * rd1, yv.z * rd1, yv.w * rd1);
    int mn2; bool b2; float down2;
    gj_reg(A, PB, kc, h, hb, maxd, y1, down2, mn2, b2);
    (void)mn2; (void)b2;
    float rd2 = __builtin_amdgcn_rcpf(down2);
    double v0 = (double)(y1.x * rd2), v1 = (double)(y1.y * rd2);
    double v2 = (double)(y1.z * rd2), v3 = (double)(y1.w * rd2);
    double n, pr, q0, q1, q2, q3;
    n = 0.5 * dsum64(v0 * v0); q0 = v0 * (1.0 / sqrt(n + 1e-280));
    pr = 0.5 * dsum64(q0 * v1); v1 -= pr * q0;
    n = 0.5 * dsum64(v1 * v1); q1 = v1 * (1.0 / sqrt(n + 1e-280));
    pr = 0.5 * dsum64(q0 * v2); v2 -= pr * q0;
    pr = 0.5 * dsum64(q1 * v2); v2 -= pr * q1;
    n = 0.5 * dsum64(v2 * v2); q2 = v2 * (1.0 / sqrt(n + 1e-280));
    pr = 0.5 * dsum64(q0 * v3); v3 -= pr * q0;
    pr = 0.5 * dsum64(q1 * v3); v3 -= pr * q1;
    pr = 0.5 * dsum64(q2 * v3); v3 -= pr * q2;
    n = 0.5 * dsum64(v3 * v3); q3 = v3 * (1.0 / sqrt(n + 1e-280));
    if (h == 0)
      *(float4*)(QS + 4 * kc) =
          make_float4((float)q0, (float)q1, (float)q2, (float)q3);
    CFENCE();
    // T partials over own half: T[q] += X1[kc][hb+r] * Q[hb+r][q]
    double T0 = 0, T1 = 0, T2 = 0, T3 = 0;
    #pragma unroll
    for (int r = 0; r < 16; ++r) {
      float4 qv = *(const float4*)(QS + 4 * (hb + r));
      double xv = (double)A[kc * 36 + hb + r];
      T0 += xv * qv.x; T1 += xv * qv.y; T2 += xv * qv.z; T3 += xv * qv.w;
    }
    double S00 = dsum64(q0 * T0), S10 = dsum64(q1 * T0);
    double S20 = dsum64(q2 * T0), S30 = dsum64(q3 * T0);
    double S11 = dsum64(q1 * T1), S21 = dsum64(q2 * T1), S31 = dsum64(q3 * T1);
    double S22 = dsum64(q2 * T2), S32 = dsum64(q3 * T2);
    double S33 = dsum64(q3 * T3);
    if (lane == 0) {
      double Ad[4][4] = {{S00, S10, S20, S30}, {S10, S11, S21, S31},
                         {S20, S21, S22, S32}, {S30, S31, S32, S33}};
      float Wd[4][4] = {{1.f, 0.f, 0.f, 0.f}, {0.f, 1.f, 0.f, 0.f},
                        {0.f, 0.f, 1.f, 0.f}, {0.f, 0.f, 0.f, 1.f}};
      for (int sw = 0; sw < 5; ++sw) {
        #pragma unroll
        for (int p = 0; p < 3; ++p) {
          #pragma unroll
          for (int q = p + 1; q < 4; ++q) {
            double apq = Ad[p][q];
            if (fabs(apq) > 1e-14 * (fabs(Ad[p][p]) + fabs(Ad[q][q])) + 1e-300) {
              double tau = 0.5 * (Ad[q][q] - Ad[p][p]);
              double rr = sqrt(tau * tau + apq * apq);
              double t = ((tau >= 0.0) ? apq : -apq) / (fabs(tau) + rr);
              double c = 1.0 / sqrt(t * t + 1.0), sv = t * c;
              #pragma unroll
              for (int jj = 0; jj < 4; ++jj) {
                double ap = Ad[p][jj], aq = Ad[q][jj];
                Ad[p][jj] = c * ap - sv * aq;
                Ad[q][jj] = sv * ap + c * aq;
              }
              #pragma unroll
              for (int ii = 0; ii < 4; ++ii) {
                double ap = Ad[ii][p], aq = Ad[ii][q];
                Ad[ii][p] = c * ap - sv * aq;
                Ad[ii][q] = sv * ap + c * aq;
                float wp = Wd[ii][p], wq = Wd[ii][q];
                Wd[ii][p] = (float)(c * wp - sv * wq);
                Wd[ii][q] = (float)(sv * wp + c * wq);
              }
            }
          }
        }
      }
      #pragma unroll
      for (int qi = 0; qi < 4; ++qi) {
        NRM[16 + qi] = (float)Ad[qi][qi];
        #pragma unroll
        for (int ai = 0; ai < 4; ++ai) NRM[ai * 4 + qi] = Wd[ai][qi];
      }
    }
    CFENCE();
  }

  if (doeig) {
    // ---- fallback: full one-sided Jacobi on X1 (already in LDS) ----
    jac32(A, NRM, lane);
  }

  // ---- E (fast: scz=1) / Z (slow: scz=sqrt(mu)/lam) in place over A cols ----
  {
    float g[16];
    #pragma unroll
    for (int c = 0; c < 4; ++c) {
      float4 v = *(const float4*)(A + kc * 36 + hb + 4 * c);
      g[4 * c] = v.x; g[4 * c + 1] = v.y; g[4 * c + 2] = v.z; g[4 * c + 3] = v.w;
    }
    float scz = 1.f;
    if (doeig) {
      float dpp = 0.f;
      #pragma unroll
      for (int i = 0; i < 16; ++i) dpp += g[i] * g[i];
      dpp += shfl_xor_f(dpp, 1);
      float lam = __builtin_amdgcn_sqrtf(dpp);
      float mu  = fmaxf(lam, 1e-4f);
      scz = __builtin_amdgcn_sqrtf(mu) * __builtin_amdgcn_rcpf(fmaxf(lam, 1e-30f));
    }
    float part[16];
    #pragma unroll
    for (int a = 0; a < 16; ++a) part[a] = 0.f;
    #pragma unroll
    for (int r = 0; r < 16; ++r) {
      const float4* w2r = (const float4*)(W2S + (hb + r) * 16);
      ACC16(part, g[r], w2r);
    }
    #pragma unroll
    for (int a = 0; a < 16; ++a) part[a] = dpp_add_xor1(part[a]) * scz;
    CFENCE();
    if (h == 0) {
      *(float4*)(A + kc * 36 + 0)  = make_float4(part[0],  part[1],  part[2],  part[3]);
      *(float4*)(A + kc * 36 + 4)  = make_float4(part[4],  part[5],  part[6],  part[7]);
      *(float4*)(A + kc * 36 + 8)  = make_float4(part[8],  part[9],  part[10], part[11]);
      *(float4*)(A + kc * 36 + 12) = make_float4(part[12], part[13], part[14], part[15]);
    }
    CFENCE();
  }

  if (docorr) {
    // ---- TQ = w2^T Q (w2 from LDS) ----
    const int aq = lane >> 4, a16 = lane & 15;
    float tq = 0.f;
    #pragma unroll 4
    for (int j = 0; j < 32; ++j)
      tq += W2S[j * 16 + a16] * QS[4 * j + aq];
    VT[aq * 16 + a16] = tq;
    CFENCE();
    if (lane < 16) {
      float t0 = VT[lane], t1 = VT[16 + lane];
      float t2 = VT[32 + lane], t3 = VT[48 + lane];
      float4 vv;
      {
        float cs = __builtin_amdgcn_sqrtf(fmaxf(EPS_REC - NRM[16], 0.f));
        vv.x = cs * (t0 * NRM[0] + t1 * NRM[4] + t2 * NRM[8] + t3 * NRM[12]);
      }
      {
        float cs = __builtin_amdgcn_sqrtf(fmaxf(EPS_REC - NRM[17], 0.f));
        vv.y = cs * (t0 * NRM[1] + t1 * NRM[5] + t2 * NRM[9] + t3 * NRM[13]);
      }
      {
        float cs = __builtin_amdgcn_sqrtf(fmaxf(EPS_REC - NRM[18], 0.f));
        vv.z = cs * (t0 * NRM[2] + t1 * NRM[6] + t2 * NRM[10] + t3 * NRM[14]);
      }
      {
        float cs = __builtin_amdgcn_sqrtf(fmaxf(EPS_REC - NRM[19], 0.f));
        vv.w = cs * (t0 * NRM[3] + t1 * NRM[7] + t2 * NRM[11] + t3 * NRM[15]);
      }
      CFENCE();
      *(float4*)(VT + lane * 4) = vv;
    }
    CFENCE();
  }

  // ---- M2 (16x16) in place over A[0,320) stride 20 (+rank-4 corr) ----
  {
    const int a = lane & 15, b0i = (lane >> 4) * 4;
    float m0 = 0.f, m1 = 0.f, m2 = 0.f, m3 = 0.f;
    if (!doeig) {
      #pragma unroll
      for (int kk = 0; kk < 32; ++kk) {
        float za = A[kk * 36 + a];                           // E[a][kk]
        float4 zb = *(const float4*)(W2S + kk * 16 + b0i);   // w2[kk][b..]
        m0 += za * zb.x; m1 += za * zb.y; m2 += za * zb.z; m3 += za * zb.w;
      }
    } else {
      #pragma unroll
      for (int kk = 0; kk < 32; ++kk) {
        float za = A[kk * 36 + a];                           // Z[a][kk]
        float4 zb = *(const float4*)(A + kk * 36 + b0i);     // Z[b..][kk]
        m0 += za * zb.x; m1 += za * zb.y; m2 += za * zb.z; m3 += za * zb.w;
      }
    }
    if (docorr) {
      float4 va = *(const float4*)(VT + a * 4);
      float4 v0 = *(const float4*)(VT + (b0i + 0) * 4);
      float4 v1 = *(const float4*)(VT + (b0i + 1) * 4);
      float4 v2 = *(const float4*)(VT + (b0i + 2) * 4);
      float4 v3 = *(const float4*)(VT + (b0i + 3) * 4);
      m0 += dot4(va, v0); m1 += dot4(va, v1);
      m2 += dot4(va, v2); m3 += dot4(va, v3);
    }
    CFENCE();                      // all E/Z reads issued before M2 stores
    A[(b0i + 0) * 20 + a] = m0;
    A[(b0i + 1) * 20 + a] = m1;
    A[(b0i + 2) * 20 + a] = m2;
    A[(b0i + 3) * 20 + a] = m3;
    W3S[(lane & 3) * 20 + (lane >> 2)] = w3r;   // w3 col-major
  }
  CFENCE();

  // ---- norms of M2 columns ----
  if (lane < 32) {
    int cc = lane >> 1;
    float4 v0 = *(const float4*)(A + cc * 20 + 8 * h);
    float4 v1 = *(const float4*)(A + cc * 20 + 8 * h + 4);
    float n2 = dot4(v0, v0) + dot4(v1, v1);
    n2 += shfl_xor_f(n2, 1);
    if (h == 0) NRM[cc] = n2;
  }
  CFENCE();

  // ---- chol16 PD certificate on M2, f64 (Cd @ A+320, disjoint from M2) ----
  bool fast2 = true;
  {
    double* Cd = (double*)(A + 320);
    const int c16 = lane >> 2, s4 = (lane & 3) * 4;
    #pragma unroll
    for (int r = 0; r < 4; ++r)
      Cd[c16 * 20 + s4 + r] = (double)A[c16 * 20 + s4 + r];
    CFENCE();
    if (lane < 16) Cd[lane * 20 + lane] -= DELTA2;
    for (int k = 0; k < 16; ++k) {
      CFENCE();
      double d = Cd[k * 20 + k];
      if (!(d > 0.0)) { fast2 = false; break; }
      double rd = 1.0 / d;
      if (c16 > k) {
        double f = Cd[c16 * 20 + k] * rd;
        #pragma unroll
        for (int r = 0; r < 4; ++r)
          Cd[c16 * 20 + s4 + r] -= f * Cd[k * 20 + s4 + r];
      }
    }
  }
  CFENCE();

  if (fast2) {
    // ---- FAST stage 2: rec2 = M2. Y @ A+320 (Cd dead), X3 @ A+384 ----
    const int k3 = (lane >> 2) & 15, a3 = lane & 3;
    float dotv = 0.f;
    #pragma unroll
    for (int c = 0; c < 4; ++c) {
      float4 gv = *(const float4*)(A + k3 * 20 + 4 * c);
      float4 wv = *(const float4*)(W3S + a3 * 20 + 4 * c);
      dotv += dot4(gv, wv);
    }
    CFENCE();
    A[320 + k3 * 4 + a3] = dotv;           // Y
    CFENCE();
    if (lane < 16) {
      int a = lane >> 2, b2 = lane & 3;
      float s = 0.f;
      #pragma unroll
      for (int kk = 0; kk < 16; ++kk)
        s += A[320 + kk * 4 + a] * W3S[b2 * 20 + kk];
      A[384 + lane] = s;                   // X3
    }
    CFENCE();
  } else {
    // ---- SLOW stage 2: eig #2 + Y + X3 ----
    jac16(A, NRM, lane);
    {
      const int k3 = (lane >> 2) & 15, a3 = lane & 3;
      float dpp2 = 0.f, dotv = 0.f;
      #pragma unroll
      for (int c = 0; c < 4; ++c) {
        float4 gv = *(const float4*)(A + k3 * 20 + 4 * c);
        float4 wv = *(const float4*)(W3S + a3 * 20 + 4 * c);
        dpp2 += dot4(gv, gv);
        dotv += dot4(gv, wv);
      }
      float lam2 = __builtin_amdgcn_sqrtf(dpp2);
      float mu2  = fmaxf(lam2, 1e-4f);
      float sc2  = __builtin_amdgcn_sqrtf(mu2) * __builtin_amdgcn_rcpf(fmaxf(lam2, 1e-30f));
      CFENCE();
      A[320 + k3 * 4 + a3] = dotv * sc2;   // Y
    }
    CFENCE();
    if (lane < 16) {
      int a = lane >> 2, b2 = lane & 3;
      float s = 0.f;
      #pragma unroll
      for (int kk = 0; kk < 16; ++kk)
        s += A[320 + kk * 4 + a] * A[320 + kk * 4 + b2];
      A[384 + lane] = s;                   // X3
    }
    CFENCE();
  }

  // ---- stage 3: serial 4x4 two-sided Jacobi + LogEig + fc + log_softmax ----
  if (lane == 0) {
    float Am[4][4], V[4][4];
    float maxdg = 0.f;
    #pragma unroll
    for (int i = 0; i < 4; ++i) {
      #pragma unroll
      for (int j = 0; j < 4; ++j) {
        Am[i][j] = A[384 + i * 4 + j];
        V[i][j] = (i == j) ? 1.f : 0.f;
      }
      maxdg = fmaxf(maxdg, fabsf(Am[i][i]));
    }
    float tol3 = 1e-7f * maxdg;
    for (int sw = 0; sw < MAXSW4; ++sw) {
      bool any = false;
      #pragma unroll
      for (int p = 0; p < 3; ++p) {
        #pragma unroll
        for (int q = p + 1; q < 4; ++q) {
          float apq = Am[p][q];
          if (fabsf(apq) > tol3) {
            any = true;
            float c, sv;
            rot_cs(apq, Am[p][p], Am[q][q], c, sv);
            #pragma unroll
            for (int j = 0; j < 4; ++j) {
              float ap = Am[p][j], aq = Am[q][j];
              Am[p][j] = c * ap - sv * aq;
              Am[q][j] = sv * ap + c * aq;
            }
            #pragma unroll
            for (int i = 0; i < 4; ++i) {
              float ap = Am[i][p], aq = Am[i][q];
              Am[i][p] = c * ap - sv * aq;
              Am[i][q] = sv * ap + c * aq;
              float up = V[i][p], uq = V[i][q];
              V[i][p] = c * up - sv * uq;
              V[i][q] = sv * up + c * uq;
            }
          }
        }
      }
      if (!any) break;
    }
    float lm[4];
    #pragma unroll
    for (int i = 0; i < 4; ++i) lm[i] = logf(fmaxf(Am[i][i], 1e-10f));
    float feat[16];
    #pragma unroll
    for (int i = 0; i < 4; ++i)
      #pragma unroll
      for (int j = 0; j < 4; ++j) {
        float acc2 = 0.f;
        #pragma unroll
        for (int kk = 0; kk < 4; ++kk) acc2 += V[i][kk] * lm[kk] * V[j][kk];
        feat[i * 4 + j] = acc2;
      }
    float z0 = 0.f, z1 = 0.f;
    #pragma unroll
    for (int f = 0; f < 16; ++f) {
      z0 += feat[f] * fcw[f * 2 + 0];
      z1 += feat[f] * fcw[f * 2 + 1];
    }
    float mx = fmaxf(z0, z1);
    float lse = mx + logf(expf(z0 - mx) + expf(z1 - mx));
    out[b * 2 + 0] = z0 - lse;
    out[b * 2 + 1] = z1 - lse;
    float* fo = out + (size_t)2 * B + (size_t)b * 16;
    #pragma unroll
    for (int f = 0; f < 16; ++f) fo[f] = feat[f];
  }
}

extern "C" void kernel_launch(void* const* d_in, const int* in_sizes, int n_in,
                              void* d_out, int out_size, void* d_ws, size_t ws_size,
                              hipStream_t stream) {
  (void)n_in; (void)d_ws; (void)ws_size; (void)out_size;
  const float* x   = (const float*)d_in[0];
  const float* w1  = (const float*)d_in[1];
  const float* w2  = (const float*)d_in[2];
  const float* w3  = (const float*)d_in[3];
  const float* fcw = (const float*)d_in[4];
  float* out = (float*)d_out;
  int B = in_sizes[0] / 1024;
  spdnet_kernel<<<B, 64, 0, stream>>>(x, w1, w2, w3, fcw, out, B);
}

// Round 10
// 798.632 us; speedup vs baseline: 3.5648x; 1.0298x over previous
//
#include <hip/hip_runtime.h>
#include <math.h>

// SPDNet forward. Round 17: r16 + forced VGPR=64.
// r16 measured natural VGPR=72 -- 8 above the 64-boundary where HW halves
// waves/SIMD (m69) -> only 4 waves/SIMD, occupancy 33%. Per-wave latency is
// 61.7us (vs r11's 77.6): the LDS-operand matmul structure is the fastest
// per-wave yet; it just needs more resident waves. __launch_bounds__(64,4)
// caps VGPR at exactly 256/4 = 64 (calibrated law, r12-r15). The 8-register
// deficit lands in the once-per-wave f64 RR / lane-0 stage-3 blocks (cheap
// scratch), NOT the hot loops (GJ ~50 live, E ~55). w3 load moved to its use
// site (frees one long-lived reg). All math byte-identical to r16 (passed).
//
// Structure (r16): x staged in A (s32); L-loop x-from-LDS + w1 scalar global;
// L parked over dead x; X1-loop lv-from-LDS + w1 rows global; X1/E/Z s36 over
// A; M2 in place over dead E at A[0,320); Cd f64 @A+320; Y@320 X3@384; w2 in
// W2S; slice 2004 fl = 8016B -> 20 blocks/CU. Wave-private LDS, CFENCE only.
// Pipeline: partial-spectrum ReEig (register GJ inertia + 2-pass shift-invert
// + f64 GS/RR + rank-4 correction in M2 space; jac32 fallback); f64 chol16
// certificate + jac16 fallback; serial 4x4 Jacobi + LogEig + fc + softmax.

#define MAXSW32 8
#define MAXSW16 8
#define MAXSW4  8
#define JTOL2   1e-12f
#define EPS_REC 1e-4f
#define SHIFT1  4e-4f
#define BRKTOL  1e-7f
#define DELTA2  2e-4

#define SLICE   2004
#define OFF_PB  1152
#define OFF_NRM 1188
#define OFF_W3  1220
#define OFF_VT  1300
#define OFF_Q   1364
#define OFF_W2  1492

// Compiler-only memory fence (wave-private LDS: HW-ordered per wave).
#define CFENCE() asm volatile("" ::: "memory")

#define ACC16(part, av, w2r) do { \
  float4 _w0 = (w2r)[0], _w1 = (w2r)[1], _w2 = (w2r)[2], _w3 = (w2r)[3]; \
  float _a = (av); \
  part[0]+=_a*_w0.x; part[1]+=_a*_w0.y; part[2]+=_a*_w0.z; part[3]+=_a*_w0.w; \
  part[4]+=_a*_w1.x; part[5]+=_a*_w1.y; part[6]+=_a*_w1.z; part[7]+=_a*_w1.w; \
  part[8]+=_a*_w2.x; part[9]+=_a*_w2.y; part[10]+=_a*_w2.z; part[11]+=_a*_w2.w; \
  part[12]+=_a*_w3.x; part[13]+=_a*_w3.y; part[14]+=_a*_w3.z; part[15]+=_a*_w3.w; \
} while (0)

__device__ __forceinline__ float shfl_xor_f(float v, int m) { return __shfl_xor(v, m, 64); }
__device__ __forceinline__ float dot4(float4 a, float4 b) {
  return a.x * b.x + a.y * b.y + a.z * b.z + a.w * b.w;
}
__device__ __forceinline__ void axpy4(float4& a, float xv, float4 w) {
  a.x += xv * w.x; a.y += xv * w.y; a.z += xv * w.z; a.w += xv * w.w;
}

__device__ __forceinline__ float dpp_add_xor1(float d) {
  return d + __int_as_float(__builtin_amdgcn_mov_dpp(__float_as_int(d), 0xB1, 0xF, 0xF, true));
}
__device__ __forceinline__ float dpp_add_xor2(float d) {
  return d + __int_as_float(__builtin_amdgcn_mov_dpp(__float_as_int(d), 0x4E, 0xF, 0xF, true));
}
__device__ __forceinline__ float dpp_add_halfmirror(float d) {
  return d + __int_as_float(__builtin_amdgcn_mov_dpp(__float_as_int(d), 0x141, 0xF, 0xF, true));
}

__device__ __forceinline__ double dsum64(double v) {
  #pragma unroll
  for (int m = 1; m <= 32; m <<= 1) v += __shfl_xor(v, m, 64);
  return v;
}
__device__ __forceinline__ float wmax64(float v) {
  #pragma unroll
  for (int m = 1; m <= 32; m <<= 1) v = fmaxf(v, __shfl_xor(v, m, 64));
  return v;
}

__device__ __forceinline__ void rot_cs(float d, float dpp, float dqq,
                                       float& c, float& s) {
  float tau = 0.5f * (dqq - dpp);
  float r   = __builtin_amdgcn_sqrtf(fmaf(tau, tau, d * d));
  float den = fabsf(tau) + r;
  float tnum = __uint_as_float(__float_as_uint(d) ^
                               (__float_as_uint(tau) & 0x80000000u));
  float t = tnum * __builtin_amdgcn_rcpf(den);
  c = __builtin_amdgcn_rsqf(fmaf(t, t, 1.f));
  s = t * c;
}

// Register-resident Gauss-Jordan of A = X1 - SHIFT1*I, 4 RHS in regs.
// Rows loaded from X1 in LDS (stride 36) at entry.
__device__ __forceinline__ void gj_reg(const float* __restrict__ X1,
                                       float* __restrict__ PB,
                                       int kc, int h, int hb, float maxd,
                                       float4& y, float& down,
                                       int& mneg, bool& brk) {
  float4 r0 = *(const float4*)(X1 + kc * 36 + hb);
  float4 r1 = *(const float4*)(X1 + kc * 36 + hb + 4);
  float4 r2 = *(const float4*)(X1 + kc * 36 + hb + 8);
  float4 r3 = *(const float4*)(X1 + kc * 36 + hb + 12);
  const int dc = kc - hb;
  r0.x -= (dc == 0)  ? SHIFT1 : 0.f;
  r0.y -= (dc == 1)  ? SHIFT1 : 0.f;
  r0.z -= (dc == 2)  ? SHIFT1 : 0.f;
  r0.w -= (dc == 3)  ? SHIFT1 : 0.f;
  r1.x -= (dc == 4)  ? SHIFT1 : 0.f;
  r1.y -= (dc == 5)  ? SHIFT1 : 0.f;
  r1.z -= (dc == 6)  ? SHIFT1 : 0.f;
  r1.w -= (dc == 7)  ? SHIFT1 : 0.f;
  r2.x -= (dc == 8)  ? SHIFT1 : 0.f;
  r2.y -= (dc == 9)  ? SHIFT1 : 0.f;
  r2.z -= (dc == 10) ? SHIFT1 : 0.f;
  r2.w -= (dc == 11) ? SHIFT1 : 0.f;
  r3.x -= (dc == 12) ? SHIFT1 : 0.f;
  r3.y -= (dc == 13) ? SHIFT1 : 0.f;
  r3.z -= (dc == 14) ? SHIFT1 : 0.f;
  r3.w -= (dc == 15) ? SHIFT1 : 0.f;

  mneg = 0; brk = false; down = 1.f;
  #pragma unroll
  for (int k = 0; k < 32; ++k) {
    if (kc == k) {
      *(float4*)(PB + hb)      = r0;
      *(float4*)(PB + hb + 4)  = r1;
      *(float4*)(PB + hb + 8)  = r2;
      *(float4*)(PB + hb + 12) = r3;
      if (h == 0) *(float4*)(PB + 32) = y;
    }
    CFENCE();
    const float  d  = PB[k];
    const float4 p0 = *(const float4*)(PB + hb);
    const float4 p1 = *(const float4*)(PB + hb + 4);
    const float4 p2 = *(const float4*)(PB + hb + 8);
    const float4 p3 = *(const float4*)(PB + hb + 12);
    const float4 py = *(const float4*)(PB + 32);
    CFENCE();
    mneg += (d <= 0.f) ? 1 : 0;
    brk = brk || !(fabsf(d) >= BRKTOL * maxd);
    float elt;
    {
      const int q = (k >> 2) & 3;
      const float4 rq = (q == 0) ? r0 : (q == 1) ? r1 : (q == 2) ? r2 : r3;
      const int m = k & 3;
      elt = (m == 0) ? rq.x : (m == 1) ? rq.y : (m == 2) ? rq.z : rq.w;
    }
    const bool ownhalf = (k >= 16) ? (h == 1) : (h == 0);
    float tm = ownhalf ? elt : 0.f;
    float f  = dpp_add_xor1(tm);
    float fr = f * __builtin_amdgcn_rcpf(d);
    fr   = (brk || (kc == k)) ? 0.f : fr;
    down = (kc == k) ? d : down;
    axpy4(r0, -fr, p0);
    axpy4(r1, -fr, p1);
    axpy4(r2, -fr, p2);
    axpy4(r3, -fr, p3);
    axpy4(y,  -fr, py);
  }
}

// One-sided Jacobi, n=32, column stride 36. 16 pairs x 4 lanes.
__device__ __forceinline__ void jac32(float* __restrict__ G, float* __restrict__ nrm,
                                      int lane) {
  const int kq  = lane >> 2, sub = lane & 3;
  const int k = (kq & 8) | ((kq & 1) << 2) | (kq & 2) | ((kq & 4) >> 2);
  const int o0 = 4 * sub, o1 = 4 * sub + 16;
  int pp = (k == 0) ? 31 : k;
  int qq = (k == 0) ? 0 : (31 - k);
  for (int sw = 0; sw < MAXSW32; ++sw) {
    bool anyact = false;
    for (int r = 0; r < 31; ++r) {
      CFENCE();
      const int p = pp, q = qq;
      if (k != 0) { pp += 16; if (pp >= 31) pp -= 31; }
      qq += 16; if (qq >= 31) qq -= 31;
      const int pb = p * 36, qb = q * 36;
      float dpp = nrm[p], dqq = nrm[q];
      float4 gp0 = *(const float4*)(G + pb + o0);
      float4 gp1 = *(const float4*)(G + pb + o1);
      float4 gq0 = *(const float4*)(G + qb + o0);
      float4 gq1 = *(const float4*)(G + qb + o1);
      float d = dot4(gp0, gq0) + dot4(gp1, gq1);
      d = dpp_add_xor1(d);
      d = dpp_add_xor2(d);
      bool active = (d * d > JTOL2 * dpp * dqq);
      if (__ballot(active) == 0ull) continue;
      anyact = true;
      if (active) {
        float c, s;
        rot_cs(d, dpp, dqq, c, s);
        float4 np0, np1, nq0, nq1;
        np0.x = c * gp0.x - s * gq0.x; nq0.x = s * gp0.x + c * gq0.x;
        np0.y = c * gp0.y - s * gq0.y; nq0.y = s * gp0.y + c * gq0.y;
        np0.z = c * gp0.z - s * gq0.z; nq0.z = s * gp0.z + c * gq0.z;
        np0.w = c * gp0.w - s * gq0.w; nq0.w = s * gp0.w + c * gq0.w;
        np1.x = c * gp1.x - s * gq1.x; nq1.x = s * gp1.x + c * gq1.x;
        np1.y = c * gp1.y - s * gq1.y; nq1.y = s * gp1.y + c * gq1.y;
        np1.z = c * gp1.z - s * gq1.z; nq1.z = s * gp1.z + c * gq1.z;
        np1.w = c * gp1.w - s * gq1.w; nq1.w = s * gp1.w + c * gq1.w;
        *(float4*)(G + pb + o0) = np0;
        *(float4*)(G + pb + o1) = np1;
        *(float4*)(G + qb + o0) = nq0;
        *(float4*)(G + qb + o1) = nq1;
        if (sub == 0) {
          float cs2 = 2.f * c * s * d, cc = c * c, ss = s * s;
          nrm[p] = cc * dpp - cs2 + ss * dqq;
          nrm[q] = ss * dpp + cs2 + cc * dqq;
        }
      }
    }
    if (!anyact) break;
  }
  CFENCE();
}

// One-sided Jacobi, n=16, column stride 20. 8 pairs x 8 lanes.
__device__ __forceinline__ void jac16(float* __restrict__ G, float* __restrict__ nrm,
                                      int lane) {
  const int kq = lane >> 3, sub = lane & 7;
  const int k = (kq >> 1) | ((kq & 1) << 2);
  const int o = 2 * sub;
  int pp = (k == 0) ? 15 : k;
  int qq = (k == 0) ? 0 : (15 - k);
  for (int sw = 0; sw < MAXSW16; ++sw) {
    bool anyact = false;
    for (int r = 0; r < 15; ++r) {
      CFENCE();
      const int p = pp, q = qq;
      if (k != 0) { pp += 8; if (pp >= 15) pp -= 15; }
      qq += 8; if (qq >= 15) qq -= 15;
      const int pb = p * 20 + o, qb = q * 20 + o;
      float dpp = nrm[p], dqq = nrm[q];
      float2 gp = *(const float2*)(G + pb);
      float2 gq = *(const float2*)(G + qb);
      float d = gp.x * gq.x + gp.y * gq.y;
      d = dpp_add_xor1(d);
      d = dpp_add_xor2(d);
      d = dpp_add_halfmirror(d);
      bool active = (d * d > JTOL2 * dpp * dqq);
      if (__ballot(active) == 0ull) continue;
      anyact = true;
      if (active) {
        float c, s;
        rot_cs(d, dpp, dqq, c, s);
        float2 np, nq;
        np.x = c * gp.x - s * gq.x; nq.x = s * gp.x + c * gq.x;
        np.y = c * gp.y - s * gq.y; nq.y = s * gp.y + c * gq.y;
        *(float2*)(G + pb) = np;
        *(float2*)(G + qb) = nq;
        if (sub == 0) {
          float cs2 = 2.f * c * s * d, cc = c * c, ss = s * s;
          nrm[p] = cc * dpp - cs2 + ss * dqq;
          nrm[q] = ss * dpp + cs2 + cc * dqq;
        }
      }
    }
    if (!anyact) break;
  }
  CFENCE();
}

__launch_bounds__(64, 4)
__global__ void spdnet_kernel(const float* __restrict__ x,
                              const float* __restrict__ w1,
                              const float* __restrict__ w2,
                              const float* __restrict__ w3,
                              const float* __restrict__ fcw,
                              float* __restrict__ out,
                              int B) {
  const int lane = threadIdx.x;
  const int b    = blockIdx.x;

  __shared__ __align__(16) float SH[SLICE];
  float* const A   = SH;             // x(s32) -> L(s32) -> X1/E/Z(s36) -> M2(s20,[0,320)) | Cd f64 @320 | Y@320 X3@384
  float* const PB  = SH + OFF_PB;    // 36: GJ pivot broadcast
  float* const NRM = SH + OFF_NRM;   // 32
  float* const W3S = SH + OFF_W3;    // 80: w3 col-major stride 20
  float* const VT  = SH + OFF_VT;    // 64: TQ then V
  float* const QS  = SH + OFF_Q;     // 128: Q rows (4 per row)
  float* const W2S = SH + OFF_W2;    // 512: w2 row-major

  const float* xb = x + (size_t)b * 1024;
  const int kc = lane >> 1, h = lane & 1, hb = h * 16;

  // ---- stage x -> A[0,1024) (stride 32) and w2 -> W2S ----
  #pragma unroll
  for (int t = 0; t < 4; ++t)
    ((float4*)A)[lane + 64 * t] = ((const float4*)xb)[lane + 64 * t];
  #pragma unroll
  for (int t = 0; t < 2; ++t)
    ((float4*)W2S)[lane + 64 * t] = ((const float4*)w2)[lane + 64 * t];
  CFENCE();

  // ---- L = x*w1 half-columns in regs (a[r] = L[hb+r][kc]); x from LDS ----
  float4 a0 = {0.f, 0.f, 0.f, 0.f}, a1 = a0, a2 = a0, a3 = a0;
  #pragma unroll 8
  for (int j = 0; j < 32; ++j) {
    float wv = w1[j * 32 + kc];              // 128B broadcast segment, L1
    const float4* xr = (const float4*)(A + j * 32 + hb);
    axpy4(a0, wv, xr[0]);
    axpy4(a1, wv, xr[1]);
    axpy4(a2, wv, xr[2]);
    axpy4(a3, wv, xr[3]);
  }
  CFENCE();                                  // all x reads done
  // ---- park L over dead x: A[j*32 + kc] = L[j][kc] ----
  A[(hb + 0)  * 32 + kc] = a0.x; A[(hb + 1)  * 32 + kc] = a0.y;
  A[(hb + 2)  * 32 + kc] = a0.z; A[(hb + 3)  * 32 + kc] = a0.w;
  A[(hb + 4)  * 32 + kc] = a1.x; A[(hb + 5)  * 32 + kc] = a1.y;
  A[(hb + 6)  * 32 + kc] = a1.z; A[(hb + 7)  * 32 + kc] = a1.w;
  A[(hb + 8)  * 32 + kc] = a2.x; A[(hb + 9)  * 32 + kc] = a2.y;
  A[(hb + 10) * 32 + kc] = a2.z; A[(hb + 11) * 32 + kc] = a2.w;
  A[(hb + 12) * 32 + kc] = a3.x; A[(hb + 13) * 32 + kc] = a3.y;
  A[(hb + 14) * 32 + kc] = a3.z; A[(hb + 15) * 32 + kc] = a3.w;
  CFENCE();

  // ---- X1 half-row (b regs); lv = L[kk][kc] from LDS ----
  {
    float4 b0 = {0.f, 0.f, 0.f, 0.f}, b1 = b0, b2 = b0, b3 = b0;
    #pragma unroll 4
    for (int kk = 0; kk < 32; ++kk) {
      float lv = A[kk * 32 + kc];            // pair-broadcast LDS read
      const float4* wr = (const float4*)(w1 + kk * 32 + hb);
      axpy4(b0, lv, wr[0]);
      axpy4(b1, lv, wr[1]);
      axpy4(b2, lv, wr[2]);
      axpy4(b3, lv, wr[3]);
    }
    float nv = dot4(b0, b0) + dot4(b1, b1) + dot4(b2, b2) + dot4(b3, b3);
    nv += shfl_xor_f(nv, 1);
    CFENCE();                                // all L reads done
    // dump X1 over L (stride 36)
    *(float4*)(A + kc * 36 + hb)      = b0;
    *(float4*)(A + kc * 36 + hb + 4)  = b1;
    *(float4*)(A + kc * 36 + hb + 8)  = b2;
    *(float4*)(A + kc * 36 + hb + 12) = b3;
    if (h == 0) NRM[kc] = nv;
  }
  CFENCE();

  // ---- maxd = max diag (uniform pair read) ----
  float maxd = wmax64(A[kc * 36 + kc]);

  // ---- inertia + shift-invert pass 1 ----
  float4 yv;
  {
    unsigned s = kc * 0x9E3779B9u + 0x7F4A7C15u;
    s = s * 1664525u + 1013904223u; yv.x = (float)(int)(s >> 16) - 32768.f;
    s = s * 1664525u + 1013904223u; yv.y = (float)(int)(s >> 16) - 32768.f;
    s = s * 1664525u + 1013904223u; yv.z = (float)(int)(s >> 16) - 32768.f;
    s = s * 1664525u + 1013904223u; yv.w = (float)(int)(s >> 16) - 32768.f;
  }
  int mneg; bool brk; float down;
  gj_reg(A, PB, kc, h, hb, maxd, yv, down, mneg, brk);
  const bool doeig  = brk || (mneg > 4);
  const bool docorr = !doeig && (mneg >= 1);

  if (docorr) {
    // ---- pass 2 (refine) + f64 GS + Rayleigh-Ritz ----
    float rd1 = __builtin_amdgcn_rcpf(down);
    float4 y1 = make_float4(yv.x * rd1, yv.y * rd1, yv.z * rd1, yv.w * rd1);
    int mn2; bool b2; float down2;
    gj_reg(A, PB, kc, h, hb, maxd, y1, down2, mn2, b2);
    (void)mn2; (void)b2;
    float rd2 = __builtin_amdgcn_rcpf(down2);
    double v0 = (double)(y1.x * rd2), v1 = (double)(y1.y * rd2);
    double v2 = (double)(y1.z * rd2), v3 = (double)(y1.w * rd2);
    double n, pr, q0, q1, q2, q3;
    n = 0.5 * dsum64(v0 * v0); q0 = v0 * (1.0 / sqrt(n + 1e-280));
    pr = 0.5 * dsum64(q0 * v1); v1 -= pr * q0;
    n = 0.5 * dsum64(v1 * v1); q1 = v1 * (1.0 / sqrt(n + 1e-280));
    pr = 0.5 * dsum64(q0 * v2); v2 -= pr * q0;
    pr = 0.5 * dsum64(q1 * v2); v2 -= pr * q1;
    n = 0.5 * dsum64(v2 * v2); q2 = v2 * (1.0 / sqrt(n + 1e-280));
    pr = 0.5 * dsum64(q0 * v3); v3 -= pr * q0;
    pr = 0.5 * dsum64(q1 * v3); v3 -= pr * q1;
    pr = 0.5 * dsum64(q2 * v3); v3 -= pr * q2;
    n = 0.5 * dsum64(v3 * v3); q3 = v3 * (1.0 / sqrt(n + 1e-280));
    if (h == 0)
      *(float4*)(QS + 4 * kc) =
          make_float4((float)q0, (float)q1, (float)q2, (float)q3);
    CFENCE();
    // T partials over own half: T[q] += X1[kc][hb+r] * Q[hb+r][q]
    double T0 = 0, T1 = 0, T2 = 0, T3 = 0;
    #pragma unroll
    for (int r = 0; r < 16; ++r) {
      float4 qv = *(const float4*)(QS + 4 * (hb + r));
      double xv = (double)A[kc * 36 + hb + r];
      T0 += xv * qv.x; T1 += xv * qv.y; T2 += xv * qv.z; T3 += xv * qv.w;
    }
    double S00 = dsum64(q0 * T0), S10 = dsum64(q1 * T0);
    double S20 = dsum64(q2 * T0), S30 = dsum64(q3 * T0);
    double S11 = dsum64(q1 * T1), S21 = dsum64(q2 * T1), S31 = dsum64(q3 * T1);
    double S22 = dsum64(q2 * T2), S32 = dsum64(q3 * T2);
    double S33 = dsum64(q3 * T3);
    if (lane == 0) {
      double Ad[4][4] = {{S00, S10, S20, S30}, {S10, S11, S21, S31},
                         {S20, S21, S22, S32}, {S30, S31, S32, S33}};
      float Wd[4][4] = {{1.f, 0.f, 0.f, 0.f}, {0.f, 1.f, 0.f, 0.f},
                        {0.f, 0.f, 1.f, 0.f}, {0.f, 0.f, 0.f, 1.f}};
      for (int sw = 0; sw < 5; ++sw) {
        #pragma unroll
        for (int p = 0; p < 3; ++p) {
          #pragma unroll
          for (int q = p + 1; q < 4; ++q) {
            double apq = Ad[p][q];
            if (fabs(apq) > 1e-14 * (fabs(Ad[p][p]) + fabs(Ad[q][q])) + 1e-300) {
              double tau = 0.5 * (Ad[q][q] - Ad[p][p]);
              double rr = sqrt(tau * tau + apq * apq);
              double t = ((tau >= 0.0) ? apq : -apq) / (fabs(tau) + rr);
              double c = 1.0 / sqrt(t * t + 1.0), sv = t * c;
              #pragma unroll
              for (int jj = 0; jj < 4; ++jj) {
                double ap = Ad[p][jj], aq = Ad[q][jj];
                Ad[p][jj] = c * ap - sv * aq;
                Ad[q][jj] = sv * ap + c * aq;
              }
              #pragma unroll
              for (int ii = 0; ii < 4; ++ii) {
                double ap = Ad[ii][p], aq = Ad[ii][q];
                Ad[ii][p] = c * ap - sv * aq;
                Ad[ii][q] = sv * ap + c * aq;
                float wp = Wd[ii][p], wq = Wd[ii][q];
                Wd[ii][p] = (float)(c * wp - sv * wq);
                Wd[ii][q] = (float)(sv * wp + c * wq);
              }
            }
          }
        }
      }
      #pragma unroll
      for (int qi = 0; qi < 4; ++qi) {
        NRM[16 + qi] = (float)Ad[qi][qi];
        #pragma unroll
        for (int ai = 0; ai < 4; ++ai) NRM[ai * 4 + qi] = Wd[ai][qi];
      }
    }
    CFENCE();
  }

  if (doeig) {
    // ---- fallback: full one-sided Jacobi on X1 (already in LDS) ----
    jac32(A, NRM, lane);
  }

  // ---- E (fast: scz=1) / Z (slow: scz=sqrt(mu)/lam) in place over A cols ----
  {
    float g[16];
    #pragma unroll
    for (int c = 0; c < 4; ++c) {
      float4 v = *(const float4*)(A + kc * 36 + hb + 4 * c);
      g[4 * c] = v.x; g[4 * c + 1] = v.y; g[4 * c + 2] = v.z; g[4 * c + 3] = v.w;
    }
    float scz = 1.f;
    if (doeig) {
      float dpp = 0.f;
      #pragma unroll
      for (int i = 0; i < 16; ++i) dpp += g[i] * g[i];
      dpp += shfl_xor_f(dpp, 1);
      float lam = __builtin_amdgcn_sqrtf(dpp);
      float mu  = fmaxf(lam, 1e-4f);
      scz = __builtin_amdgcn_sqrtf(mu) * __builtin_amdgcn_rcpf(fmaxf(lam, 1e-30f));
    }
    float part[16];
    #pragma unroll
    for (int a = 0; a < 16; ++a) part[a] = 0.f;
    #pragma unroll
    for (int r = 0; r < 16; ++r) {
      const float4* w2r = (const float4*)(W2S + (hb + r) * 16);
      ACC16(part, g[r], w2r);
    }
    #pragma unroll
    for (int a = 0; a < 16; ++a) part[a] = dpp_add_xor1(part[a]) * scz;
    CFENCE();
    if (h == 0) {
      *(float4*)(A + kc * 36 + 0)  = make_float4(part[0],  part[1],  part[2],  part[3]);
      *(float4*)(A + kc * 36 + 4)  = make_float4(part[4],  part[5],  part[6],  part[7]);
      *(float4*)(A + kc * 36 + 8)  = make_float4(part[8],  part[9],  part[10], part[11]);
      *(float4*)(A + kc * 36 + 12) = make_float4(part[12], part[13], part[14], part[15]);
    }
    CFENCE();
  }

  if (docorr) {
    // ---- TQ = w2^T Q (w2 from LDS) ----
    const int aq = lane >> 4, a16 = lane & 15;
    float tq = 0.f;
    #pragma unroll 4
    for (int j = 0; j < 32; ++j)
      tq += W2S[j * 16 + a16] * QS[4 * j + aq];
    VT[aq * 16 + a16] = tq;
    CFENCE();
    if (lane < 16) {
      float t0 = VT[lane], t1 = VT[16 + lane];
      float t2 = VT[32 + lane], t3 = VT[48 + lane];
      float4 vv;
      {
        float cs = __builtin_amdgcn_sqrtf(fmaxf(EPS_REC - NRM[16], 0.f));
        vv.x = cs * (t0 * NRM[0] + t1 * NRM[4] + t2 * NRM[8] + t3 * NRM[12]);
      }
      {
        float cs = __builtin_amdgcn_sqrtf(fmaxf(EPS_REC - NRM[17], 0.f));
        vv.y = cs * (t0 * NRM[1] + t1 * NRM[5] + t2 * NRM[9] + t3 * NRM[13]);
      }
      {
        float cs = __builtin_amdgcn_sqrtf(fmaxf(EPS_REC - NRM[18], 0.f));
        vv.z = cs * (t0 * NRM[2] + t1 * NRM[6] + t2 * NRM[10] + t3 * NRM[14]);
      }
      {
        float cs = __builtin_amdgcn_sqrtf(fmaxf(EPS_REC - NRM[19], 0.f));
        vv.w = cs * (t0 * NRM[3] + t1 * NRM[7] + t2 * NRM[11] + t3 * NRM[15]);
      }
      CFENCE();
      *(float4*)(VT + lane * 4) = vv;
    }
    CFENCE();
  }

  // ---- M2 (16x16) in place over A[0,320) stride 20 (+rank-4 corr) ----
  {
    const int a = lane & 15, b0i = (lane >> 4) * 4;
    float m0 = 0.f, m1 = 0.f, m2 = 0.f, m3 = 0.f;
    if (!doeig) {
      #pragma unroll
      for (int kk = 0; kk < 32; ++kk) {
        float za = A[kk * 36 + a];                           // E[a][kk]
        float4 zb = *(const float4*)(W2S + kk * 16 + b0i);   // w2[kk][b..]
        m0 += za * zb.x; m1 += za * zb.y; m2 += za * zb.z; m3 += za * zb.w;
      }
    } else {
      #pragma unroll
      for (int kk = 0; kk < 32; ++kk) {
        float za = A[kk * 36 + a];                           // Z[a][kk]
        float4 zb = *(const float4*)(A + kk * 36 + b0i);     // Z[b..][kk]
        m0 += za * zb.x; m1 += za * zb.y; m2 += za * zb.z; m3 += za * zb.w;
      }
    }
    if (docorr) {
      float4 va = *(const float4*)(VT + a * 4);
      float4 v0 = *(const float4*)(VT + (b0i + 0) * 4);
      float4 v1 = *(const float4*)(VT + (b0i + 1) * 4);
      float4 v2 = *(const float4*)(VT + (b0i + 2) * 4);
      float4 v3 = *(const float4*)(VT + (b0i + 3) * 4);
      m0 += dot4(va, v0); m1 += dot4(va, v1);
      m2 += dot4(va, v2); m3 += dot4(va, v3);
    }
    CFENCE();                      // all E/Z reads issued before M2 stores
    A[(b0i + 0) * 20 + a] = m0;
    A[(b0i + 1) * 20 + a] = m1;
    A[(b0i + 2) * 20 + a] = m2;
    A[(b0i + 3) * 20 + a] = m3;
    W3S[(lane & 3) * 20 + (lane >> 2)] = w3[lane];   // w3 col-major
  }
  CFENCE();

  // ---- norms of M2 columns ----
  if (lane < 32) {
    int cc = lane >> 1;
    float4 v0 = *(const float4*)(A + cc * 20 + 8 * h);
    float4 v1 = *(const float4*)(A + cc * 20 + 8 * h + 4);
    float n2 = dot4(v0, v0) + dot4(v1, v1);
    n2 += shfl_xor_f(n2, 1);
    if (h == 0) NRM[cc] = n2;
  }
  CFENCE();

  // ---- chol16 PD certificate on M2, f64 (Cd @ A+320, disjoint from M2) ----
  bool fast2 = true;
  {
    double* Cd = (double*)(A + 320);
    const int c16 = lane >> 2, s4 = (lane & 3) * 4;
    #pragma unroll
    for (int r = 0; r < 4; ++r)
      Cd[c16 * 20 + s4 + r] = (double)A[c16 * 20 + s4 + r];
    CFENCE();
    if (lane < 16) Cd[lane * 20 + lane] -= DELTA2;
    for (int k = 0; k < 16; ++k) {
      CFENCE();
      double d = Cd[k * 20 + k];
      if (!(d > 0.0)) { fast2 = false; break; }
      double rd = 1.0 / d;
      if (c16 > k) {
        double f = Cd[c16 * 20 + k] * rd;
        #pragma unroll
        for (int r = 0; r < 4; ++r)
          Cd[c16 * 20 + s4 + r] -= f * Cd[k * 20 + s4 + r];
      }
    }
  }
  CFENCE();

  if (fast2) {
    // ---- FAST stage 2: rec2 = M2. Y @ A+320 (Cd dead), X3 @ A+384 ----
    const int k3 = (lane >> 2) & 15, a3 = lane & 3;
    float dotv = 0.f;
    #pragma unroll
    for (int c = 0; c < 4; ++c) {
      float4 gv = *(const float4*)(A + k3 * 20 + 4 * c);
      float4 wv = *(const float4*)(W3S + a3 * 20 + 4 * c);
      dotv += dot4(gv, wv);
    }
    CFENCE();
    A[320 + k3 * 4 + a3] = dotv;           // Y
    CFENCE();
    if (lane < 16) {
      int a = lane >> 2, b2 = lane & 3;
      float s = 0.f;
      #pragma unroll
      for (int kk = 0; kk < 16; ++kk)
        s += A[320 + kk * 4 + a] * W3S[b2 * 20 + kk];
      A[384 + lane] = s;                   // X3
    }
    CFENCE();
  } else {
    // ---- SLOW stage 2: eig #2 + Y + X3 ----
    jac16(A, NRM, lane);
    {
      const int k3 = (lane >> 2) & 15, a3 = lane & 3;
      float dpp2 = 0.f, dotv = 0.f;
      #pragma unroll
      for (int c = 0; c < 4; ++c) {
        float4 gv = *(const float4*)(A + k3 * 20 + 4 * c);
        float4 wv = *(const float4*)(W3S + a3 * 20 + 4 * c);
        dpp2 += dot4(gv, gv);
        dotv += dot4(gv, wv);
      }
      float lam2 = __builtin_amdgcn_sqrtf(dpp2);
      float mu2  = fmaxf(lam2, 1e-4f);
      float sc2  = __builtin_amdgcn_sqrtf(mu2) * __builtin_amdgcn_rcpf(fmaxf(lam2, 1e-30f));
      CFENCE();
      A[320 + k3 * 4 + a3] = dotv * sc2;   // Y
    }
    CFENCE();
    if (lane < 16) {
      int a = lane >> 2, b2 = lane & 3;
      float s = 0.f;
      #pragma unroll
      for (int kk = 0; kk < 16; ++kk)
        s += A[320 + kk * 4 + a] * A[320 + kk * 4 + b2];
      A[384 + lane] = s;                   // X3
    }
    CFENCE();
  }

  // ---- stage 3: serial 4x4 two-sided Jacobi + LogEig + fc + log_softmax ----
  if (lane == 0) {
    float Am[4][4], V[4][4];
    float maxdg = 0.f;
    #pragma unroll
    for (int i = 0; i < 4; ++i) {
      #pragma unroll
      for (int j = 0; j < 4; ++j) {
        Am[i][j] = A[384 + i * 4 + j];
        V[i][j] = (i == j) ? 1.f : 0.f;
      }
      maxdg = fmaxf(maxdg, fabsf(Am[i][i]));
    }
    float tol3 = 1e-7f * maxdg;
    for (int sw = 0; sw < MAXSW4; ++sw) {
      bool any = false;
      #pragma unroll
      for (int p = 0; p < 3; ++p) {
        #pragma unroll
        for (int q = p + 1; q < 4; ++q) {
          float apq = Am[p][q];
          if (fabsf(apq) > tol3) {
            any = true;
            float c, sv;
            rot_cs(apq, Am[p][p], Am[q][q], c, sv);
            #pragma unroll
            for (int j = 0; j < 4; ++j) {
              float ap = Am[p][j], aq = Am[q][j];
              Am[p][j] = c * ap - sv * aq;
              Am[q][j] = sv * ap + c * aq;
            }
            #pragma unroll
            for (int i = 0; i < 4; ++i) {
              float ap = Am[i][p], aq = Am[i][q];
              Am[i][p] = c * ap - sv * aq;
              Am[i][q] = sv * ap + c * aq;
              float up = V[i][p], uq = V[i][q];
              V[i][p] = c * up - sv * uq;
              V[i][q] = sv * up + c * uq;
            }
          }
        }
      }
      if (!any) break;
    }
    float lm[4];
    #pragma unroll
    for (int i = 0; i < 4; ++i) lm[i] = logf(fmaxf(Am[i][i], 1e-10f));
    float feat[16];
    #pragma unroll
    for (int i = 0; i < 4; ++i)
      #pragma unroll
      for (int j = 0; j < 4; ++j) {
        float acc2 = 0.f;
        #pragma unroll
        for (int kk = 0; kk < 4; ++kk) acc2 += V[i][kk] * lm[kk] * V[j][kk];
        feat[i * 4 + j] = acc2;
      }
    float z0 = 0.f, z1 = 0.f;
    #pragma unroll
    for (int f = 0; f < 16; ++f) {
      z0 += feat[f] * fcw[f * 2 + 0];
      z1 += feat[f] * fcw[f * 2 + 1];
    }
    float mx = fmaxf(z0, z1);
    float lse = mx + logf(expf(z0 - mx) + expf(z1 - mx));
    out[b * 2 + 0] = z0 - lse;
    out[b * 2 + 1] = z1 - lse;
    float* fo = out + (size_t)2 * B + (size_t)b * 16;
    #pragma unroll
    for (int f = 0; f < 16; ++f) fo[f] = feat[f];
  }
}

extern "C" void kernel_launch(void* const* d_in, const int* in_sizes, int n_in,
                              void* d_out, int out_size, void* d_ws, size_t ws_size,
                              hipStream_t stream) {
  (void)n_in; (void)d_ws; (void)ws_size; (void)out_size;
  const float* x   = (const float*)d_in[0];
  const float* w1  = (const float*)d_in[1];
  const float* w2  = (const float*)d_in[2];
  const float* w3  = (const float*)d_in[3];
  const float* fcw = (const float*)d_in[4];
  float* out = (float*)d_out;
  int B = in_sizes[0] / 1024;
  spdnet_kernel<<<B, 64, 0, stream>>>(x, w1, w2, w3, fcw, out, B);
}

// Round 11
// 688.491 us; speedup vs baseline: 4.1351x; 1.1600x over previous
//
#include <hip/hip_runtime.h>
#include <math.h>

// SPDNet forward. Round 18: mneg==1 rank-2 Rayleigh-Ritz specialization.
// r15-r17 established: occupancy packaging is exhausted (705-740us across
// three structurally different packagings). Remaining time is per-matrix
// work. The docorr path (taken by nearly every block: one eigenvalue below
// the 4e-4 shift) paid for rank-4 machinery: 4-vector f64 GS (~23 dsum64),
// 4-col T-loop, and a SERIAL lane-0 4x4 f64 Jacobi RR (~1500 instr, 63 lanes
// idle). mneg==1 is the dominant case -> rank-2 RR: GS on 2 pass-2 columns
// (3 dsum64), 2-col T, closed-form 2x2 symmetric eig on ALL lanes (zero
// serial), V rows zero-padded so the shared M2 correction code is unchanged.
// Rank-2 (not rank-1) keeps the near-shift pair case accurate. mneg in [2,4]
// keeps the verified rank-4 path bit-for-bit.
//
// Structure (r16/r17): x staged in A (s32); L-loop x-from-LDS + w1 scalar
// global; L parked over dead x; X1-loop lv-from-LDS + w1 rows global; X1/E/Z
// s36 over A; M2 in place over dead E at A[0,320); Cd f64 @A+320; Y@320
// X3@384; w2 in W2S; slice 2004 fl = 8016B. __launch_bounds__(64,4): VGPR
// cap 64 (calibrated law), no spill at this demand (r17: WRITE 3MB).
// Pipeline: partial-spectrum ReEig (register GJ inertia + 2-pass shift-invert
// + rank-2/rank-4 RR + correction in M2 space; jac32 fallback); f64 chol16
// certificate + jac16 fallback; serial 4x4 Jacobi + LogEig + fc + softmax.

#define MAXSW32 8
#define MAXSW16 8
#define MAXSW4  8
#define JTOL2   1e-12f
#define EPS_REC 1e-4f
#define SHIFT1  4e-4f
#define BRKTOL  1e-7f
#define DELTA2  2e-4

#define SLICE   2004
#define OFF_PB  1152
#define OFF_NRM 1188
#define OFF_W3  1220
#define OFF_VT  1300
#define OFF_Q   1364
#define OFF_W2  1492

// Compiler-only memory fence (wave-private LDS: HW-ordered per wave).
#define CFENCE() asm volatile("" ::: "memory")

#define ACC16(part, av, w2r) do { \
  float4 _w0 = (w2r)[0], _w1 = (w2r)[1], _w2 = (w2r)[2], _w3 = (w2r)[3]; \
  float _a = (av); \
  part[0]+=_a*_w0.x; part[1]+=_a*_w0.y; part[2]+=_a*_w0.z; part[3]+=_a*_w0.w; \
  part[4]+=_a*_w1.x; part[5]+=_a*_w1.y; part[6]+=_a*_w1.z; part[7]+=_a*_w1.w; \
  part[8]+=_a*_w2.x; part[9]+=_a*_w2.y; part[10]+=_a*_w2.z; part[11]+=_a*_w2.w; \
  part[12]+=_a*_w3.x; part[13]+=_a*_w3.y; part[14]+=_a*_w3.z; part[15]+=_a*_w3.w; \
} while (0)

__device__ __forceinline__ float shfl_xor_f(float v, int m) { return __shfl_xor(v, m, 64); }
__device__ __forceinline__ float dot4(float4 a, float4 b) {
  return a.x * b.x + a.y * b.y + a.z * b.z + a.w * b.w;
}
__device__ __forceinline__ void axpy4(float4& a, float xv, float4 w) {
  a.x += xv * w.x; a.y += xv * w.y; a.z += xv * w.z; a.w += xv * w.w;
}

__device__ __forceinline__ float dpp_add_xor1(float d) {
  return d + __int_as_float(__builtin_amdgcn_mov_dpp(__float_as_int(d), 0xB1, 0xF, 0xF, true));
}
__device__ __forceinline__ float dpp_add_xor2(float d) {
  return d + __int_as_float(__builtin_amdgcn_mov_dpp(__float_as_int(d), 0x4E, 0xF, 0xF, true));
}
__device__ __forceinline__ float dpp_add_halfmirror(float d) {
  return d + __int_as_float(__builtin_amdgcn_mov_dpp(__float_as_int(d), 0x141, 0xF, 0xF, true));
}

__device__ __forceinline__ double dsum64(double v) {
  #pragma unroll
  for (int m = 1; m <= 32; m <<= 1) v += __shfl_xor(v, m, 64);
  return v;
}
__device__ __forceinline__ float wmax64(float v) {
  #pragma unroll
  for (int m = 1; m <= 32; m <<= 1) v = fmaxf(v, __shfl_xor(v, m, 64));
  return v;
}

__device__ __forceinline__ void rot_cs(float d, float dpp, float dqq,
                                       float& c, float& s) {
  float tau = 0.5f * (dqq - dpp);
  float r   = __builtin_amdgcn_sqrtf(fmaf(tau, tau, d * d));
  float den = fabsf(tau) + r;
  float tnum = __uint_as_float(__float_as_uint(d) ^
                               (__float_as_uint(tau) & 0x80000000u));
  float t = tnum * __builtin_amdgcn_rcpf(den);
  c = __builtin_amdgcn_rsqf(fmaf(t, t, 1.f));
  s = t * c;
}

// Register-resident Gauss-Jordan of A = X1 - SHIFT1*I, 4 RHS in regs.
// Rows loaded from X1 in LDS (stride 36) at entry.
__device__ __forceinline__ void gj_reg(const float* __restrict__ X1,
                                       float* __restrict__ PB,
                                       int kc, int h, int hb, float maxd,
                                       float4& y, float& down,
                                       int& mneg, bool& brk) {
  float4 r0 = *(const float4*)(X1 + kc * 36 + hb);
  float4 r1 = *(const float4*)(X1 + kc * 36 + hb + 4);
  float4 r2 = *(const float4*)(X1 + kc * 36 + hb + 8);
  float4 r3 = *(const float4*)(X1 + kc * 36 + hb + 12);
  const int dc = kc - hb;
  r0.x -= (dc == 0)  ? SHIFT1 : 0.f;
  r0.y -= (dc == 1)  ? SHIFT1 : 0.f;
  r0.z -= (dc == 2)  ? SHIFT1 : 0.f;
  r0.w -= (dc == 3)  ? SHIFT1 : 0.f;
  r1.x -= (dc == 4)  ? SHIFT1 : 0.f;
  r1.y -= (dc == 5)  ? SHIFT1 : 0.f;
  r1.z -= (dc == 6)  ? SHIFT1 : 0.f;
  r1.w -= (dc == 7)  ? SHIFT1 : 0.f;
  r2.x -= (dc == 8)  ? SHIFT1 : 0.f;
  r2.y -= (dc == 9)  ? SHIFT1 : 0.f;
  r2.z -= (dc == 10) ? SHIFT1 : 0.f;
  r2.w -= (dc == 11) ? SHIFT1 : 0.f;
  r3.x -= (dc == 12) ? SHIFT1 : 0.f;
  r3.y -= (dc == 13) ? SHIFT1 : 0.f;
  r3.z -= (dc == 14) ? SHIFT1 : 0.f;
  r3.w -= (dc == 15) ? SHIFT1 : 0.f;

  mneg = 0; brk = false; down = 1.f;
  #pragma unroll
  for (int k = 0; k < 32; ++k) {
    if (kc == k) {
      *(float4*)(PB + hb)      = r0;
      *(float4*)(PB + hb + 4)  = r1;
      *(float4*)(PB + hb + 8)  = r2;
      *(float4*)(PB + hb + 12) = r3;
      if (h == 0) *(float4*)(PB + 32) = y;
    }
    CFENCE();
    const float  d  = PB[k];
    const float4 p0 = *(const float4*)(PB + hb);
    const float4 p1 = *(const float4*)(PB + hb + 4);
    const float4 p2 = *(const float4*)(PB + hb + 8);
    const float4 p3 = *(const float4*)(PB + hb + 12);
    const float4 py = *(const float4*)(PB + 32);
    CFENCE();
    mneg += (d <= 0.f) ? 1 : 0;
    brk = brk || !(fabsf(d) >= BRKTOL * maxd);
    float elt;
    {
      const int q = (k >> 2) & 3;
      const float4 rq = (q == 0) ? r0 : (q == 1) ? r1 : (q == 2) ? r2 : r3;
      const int m = k & 3;
      elt = (m == 0) ? rq.x : (m == 1) ? rq.y : (m == 2) ? rq.z : rq.w;
    }
    const bool ownhalf = (k >= 16) ? (h == 1) : (h == 0);
    float tm = ownhalf ? elt : 0.f;
    float f  = dpp_add_xor1(tm);
    float fr = f * __builtin_amdgcn_rcpf(d);
    fr   = (brk || (kc == k)) ? 0.f : fr;
    down = (kc == k) ? d : down;
    axpy4(r0, -fr, p0);
    axpy4(r1, -fr, p1);
    axpy4(r2, -fr, p2);
    axpy4(r3, -fr, p3);
    axpy4(y,  -fr, py);
  }
}

// One-sided Jacobi, n=32, column stride 36. 16 pairs x 4 lanes.
__device__ __forceinline__ void jac32(float* __restrict__ G, float* __restrict__ nrm,
                                      int lane) {
  const int kq  = lane >> 2, sub = lane & 3;
  const int k = (kq & 8) | ((kq & 1) << 2) | (kq & 2) | ((kq & 4) >> 2);
  const int o0 = 4 * sub, o1 = 4 * sub + 16;
  int pp = (k == 0) ? 31 : k;
  int qq = (k == 0) ? 0 : (31 - k);
  for (int sw = 0; sw < MAXSW32; ++sw) {
    bool anyact = false;
    for (int r = 0; r < 31; ++r) {
      CFENCE();
      const int p = pp, q = qq;
      if (k != 0) { pp += 16; if (pp >= 31) pp -= 31; }
      qq += 16; if (qq >= 31) qq -= 31;
      const int pb = p * 36, qb = q * 36;
      float dpp = nrm[p], dqq = nrm[q];
      float4 gp0 = *(const float4*)(G + pb + o0);
      float4 gp1 = *(const float4*)(G + pb + o1);
      float4 gq0 = *(const float4*)(G + qb + o0);
      float4 gq1 = *(const float4*)(G + qb + o1);
      float d = dot4(gp0, gq0) + dot4(gp1, gq1);
      d = dpp_add_xor1(d);
      d = dpp_add_xor2(d);
      bool active = (d * d > JTOL2 * dpp * dqq);
      if (__ballot(active) == 0ull) continue;
      anyact = true;
      if (active) {
        float c, s;
        rot_cs(d, dpp, dqq, c, s);
        float4 np0, np1, nq0, nq1;
        np0.x = c * gp0.x - s * gq0.x; nq0.x = s * gp0.x + c * gq0.x;
        np0.y = c * gp0.y - s * gq0.y; nq0.y = s * gp0.y + c * gq0.y;
        np0.z = c * gp0.z - s * gq0.z; nq0.z = s * gp0.z + c * gq0.z;
        np0.w = c * gp0.w - s * gq0.w; nq0.w = s * gp0.w + c * gq0.w;
        np1.x = c * gp1.x - s * gq1.x; nq1.x = s * gp1.x + c * gq1.x;
        np1.y = c * gp1.y - s * gq1.y; nq1.y = s * gp1.y + c * gq1.y;
        np1.z = c * gp1.z - s * gq1.z; nq1.z = s * gp1.z + c * gq1.z;
        np1.w = c * gp1.w - s * gq1.w; nq1.w = s * gp1.w + c * gq1.w;
        *(float4*)(G + pb + o0) = np0;
        *(float4*)(G + pb + o1) = np1;
        *(float4*)(G + qb + o0) = nq0;
        *(float4*)(G + qb + o1) = nq1;
        if (sub == 0) {
          float cs2 = 2.f * c * s * d, cc = c * c, ss = s * s;
          nrm[p] = cc * dpp - cs2 + ss * dqq;
          nrm[q] = ss * dpp + cs2 + cc * dqq;
        }
      }
    }
    if (!anyact) break;
  }
  CFENCE();
}

// One-sided Jacobi, n=16, column stride 20. 8 pairs x 8 lanes.
__device__ __forceinline__ void jac16(float* __restrict__ G, float* __restrict__ nrm,
                                      int lane) {
  const int kq = lane >> 3, sub = lane & 7;
  const int k = (kq >> 1) | ((kq & 1) << 2);
  const int o = 2 * sub;
  int pp = (k == 0) ? 15 : k;
  int qq = (k == 0) ? 0 : (15 - k);
  for (int sw = 0; sw < MAXSW16; ++sw) {
    bool anyact = false;
    for (int r = 0; r < 15; ++r) {
      CFENCE();
      const int p = pp, q = qq;
      if (k != 0) { pp += 8; if (pp >= 15) pp -= 15; }
      qq += 8; if (qq >= 15) qq -= 15;
      const int pb = p * 20 + o, qb = q * 20 + o;
      float dpp = nrm[p], dqq = nrm[q];
      float2 gp = *(const float2*)(G + pb);
      float2 gq = *(const float2*)(G + qb);
      float d = gp.x * gq.x + gp.y * gq.y;
      d = dpp_add_xor1(d);
      d = dpp_add_xor2(d);
      d = dpp_add_halfmirror(d);
      bool active = (d * d > JTOL2 * dpp * dqq);
      if (__ballot(active) == 0ull) continue;
      anyact = true;
      if (active) {
        float c, s;
        rot_cs(d, dpp, dqq, c, s);
        float2 np, nq;
        np.x = c * gp.x - s * gq.x; nq.x = s * gp.x + c * gq.x;
        np.y = c * gp.y - s * gq.y; nq.y = s * gp.y + c * gq.y;
        *(float2*)(G + pb) = np;
        *(float2*)(G + qb) = nq;
        if (sub == 0) {
          float cs2 = 2.f * c * s * d, cc = c * c, ss = s * s;
          nrm[p] = cc * dpp - cs2 + ss * dqq;
          nrm[q] = ss * dpp + cs2 + cc * dqq;
        }
      }
    }
    if (!anyact) break;
  }
  CFENCE();
}

__launch_bounds__(64, 4)
__global__ void spdnet_kernel(const float* __restrict__ x,
                              const float* __restrict__ w1,
                              const float* __restrict__ w2,
                              const float* __restrict__ w3,
                              const float* __restrict__ fcw,
                              float* __restrict__ out,
                              int B) {
  const int lane = threadIdx.x;
  const int b    = blockIdx.x;

  __shared__ __align__(16) float SH[SLICE];
  float* const A   = SH;             // x(s32) -> L(s32) -> X1/E/Z(s36) -> M2(s20,[0,320)) | Cd f64 @320 | Y@320 X3@384
  float* const PB  = SH + OFF_PB;    // 36: GJ pivot broadcast
  float* const NRM = SH + OFF_NRM;   // 32
  float* const W3S = SH + OFF_W3;    // 80: w3 col-major stride 20
  float* const VT  = SH + OFF_VT;    // 64: TQ then V
  float* const QS  = SH + OFF_Q;     // 128: Q rows
  float* const W2S = SH + OFF_W2;    // 512: w2 row-major

  const float* xb = x + (size_t)b * 1024;
  const int kc = lane >> 1, h = lane & 1, hb = h * 16;

  // ---- stage x -> A[0,1024) (stride 32) and w2 -> W2S ----
  #pragma unroll
  for (int t = 0; t < 4; ++t)
    ((float4*)A)[lane + 64 * t] = ((const float4*)xb)[lane + 64 * t];
  #pragma unroll
  for (int t = 0; t < 2; ++t)
    ((float4*)W2S)[lane + 64 * t] = ((const float4*)w2)[lane + 64 * t];
  CFENCE();

  // ---- L = x*w1 half-columns in regs (a[r] = L[hb+r][kc]); x from LDS ----
  float4 a0 = {0.f, 0.f, 0.f, 0.f}, a1 = a0, a2 = a0, a3 = a0;
  #pragma unroll 8
  for (int j = 0; j < 32; ++j) {
    float wv = w1[j * 32 + kc];              // 128B broadcast segment, L1
    const float4* xr = (const float4*)(A + j * 32 + hb);
    axpy4(a0, wv, xr[0]);
    axpy4(a1, wv, xr[1]);
    axpy4(a2, wv, xr[2]);
    axpy4(a3, wv, xr[3]);
  }
  CFENCE();                                  // all x reads done
  // ---- park L over dead x: A[j*32 + kc] = L[j][kc] ----
  A[(hb + 0)  * 32 + kc] = a0.x; A[(hb + 1)  * 32 + kc] = a0.y;
  A[(hb + 2)  * 32 + kc] = a0.z; A[(hb + 3)  * 32 + kc] = a0.w;
  A[(hb + 4)  * 32 + kc] = a1.x; A[(hb + 5)  * 32 + kc] = a1.y;
  A[(hb + 6)  * 32 + kc] = a1.z; A[(hb + 7)  * 32 + kc] = a1.w;
  A[(hb + 8)  * 32 + kc] = a2.x; A[(hb + 9)  * 32 + kc] = a2.y;
  A[(hb + 10) * 32 + kc] = a2.z; A[(hb + 11) * 32 + kc] = a2.w;
  A[(hb + 12) * 32 + kc] = a3.x; A[(hb + 13) * 32 + kc] = a3.y;
  A[(hb + 14) * 32 + kc] = a3.z; A[(hb + 15) * 32 + kc] = a3.w;
  CFENCE();

  // ---- X1 half-row (b regs); lv = L[kk][kc] from LDS ----
  {
    float4 b0 = {0.f, 0.f, 0.f, 0.f}, b1 = b0, b2 = b0, b3 = b0;
    #pragma unroll 4
    for (int kk = 0; kk < 32; ++kk) {
      float lv = A[kk * 32 + kc];            // pair-broadcast LDS read
      const float4* wr = (const float4*)(w1 + kk * 32 + hb);
      axpy4(b0, lv, wr[0]);
      axpy4(b1, lv, wr[1]);
      axpy4(b2, lv, wr[2]);
      axpy4(b3, lv, wr[3]);
    }
    float nv = dot4(b0, b0) + dot4(b1, b1) + dot4(b2, b2) + dot4(b3, b3);
    nv += shfl_xor_f(nv, 1);
    CFENCE();                                // all L reads done
    // dump X1 over L (stride 36)
    *(float4*)(A + kc * 36 + hb)      = b0;
    *(float4*)(A + kc * 36 + hb + 4)  = b1;
    *(float4*)(A + kc * 36 + hb + 8)  = b2;
    *(float4*)(A + kc * 36 + hb + 12) = b3;
    if (h == 0) NRM[kc] = nv;
  }
  CFENCE();

  // ---- maxd = max diag (uniform pair read) ----
  float maxd = wmax64(A[kc * 36 + kc]);

  // ---- inertia + shift-invert pass 1 ----
  float4 yv;
  {
    unsigned s = kc * 0x9E3779B9u + 0x7F4A7C15u;
    s = s * 1664525u + 1013904223u; yv.x = (float)(int)(s >> 16) - 32768.f;
    s = s * 1664525u + 1013904223u; yv.y = (float)(int)(s >> 16) - 32768.f;
    s = s * 1664525u + 1013904223u; yv.z = (float)(int)(s >> 16) - 32768.f;
    s = s * 1664525u + 1013904223u; yv.w = (float)(int)(s >> 16) - 32768.f;
  }
  int mneg; bool brk; float down;
  gj_reg(A, PB, kc, h, hb, maxd, yv, down, mneg, brk);
  const bool doeig  = brk || (mneg > 4);
  const bool docorr = !doeig && (mneg >= 1);

  if (docorr) {
    // ---- pass 2 (refine) ----
    float rd1 = __builtin_amdgcn_rcpf(down);
    float4 y1 = make_float4(yv.x * rd1, yv.y * rd1, yv.z * rd1, yv.w * rd1);
    int mn2; bool b2; float down2;
    gj_reg(A, PB, kc, h, hb, maxd, y1, down2, mn2, b2);
    (void)mn2; (void)b2;
    float rd2 = __builtin_amdgcn_rcpf(down2);

    if (mneg == 1) {
      // ---- rank-2 RR: GS(2) + 2-col T + closed-form 2x2, zero serial ----
      double v0 = (double)(y1.x * rd2), v1 = (double)(y1.y * rd2);
      double n, pr, q0, q1;
      n = 0.5 * dsum64(v0 * v0); q0 = v0 * (1.0 / sqrt(n + 1e-280));
      pr = 0.5 * dsum64(q0 * v1); v1 -= pr * q0;
      n = 0.5 * dsum64(v1 * v1); q1 = v1 * (1.0 / sqrt(n + 1e-280));
      if (h == 0) *(float2*)(QS + 2 * kc) = make_float2((float)q0, (float)q1);
      CFENCE();
      double T0 = 0, T1 = 0;
      #pragma unroll
      for (int r = 0; r < 16; ++r) {
        float2 qv = *(const float2*)(QS + 2 * (hb + r));
        double xv = (double)A[kc * 36 + hb + r];
        T0 += xv * qv.x; T1 += xv * qv.y;
      }
      double T0p = T0 + __shfl_xor(T0, 1, 64);
      double T1p = T1 + __shfl_xor(T1, 1, 64);
      double S00 = 0.5 * dsum64(q0 * T0p);
      double S01 = 0.5 * dsum64(q0 * T1p);
      double S11 = 0.5 * dsum64(q1 * T1p);
      double th0, th1, w00, w10, w01, w11;
      if (fabs(S01) > 1e-14 * (fabs(S00) + fabs(S11)) + 1e-300) {
        double tr = S00 + S11, df = S00 - S11;
        double disc = sqrt(df * df + 4.0 * S01 * S01);
        th0 = 0.5 * (tr - disc); th1 = 0.5 * (tr + disc);
        double bb = th0 - S00, nn = 1.0 / sqrt(S01 * S01 + bb * bb);
        w00 = S01 * nn; w10 = bb * nn;
        bb = th1 - S00; nn = 1.0 / sqrt(S01 * S01 + bb * bb);
        w01 = S01 * nn; w11 = bb * nn;
      } else {
        th0 = S00; th1 = S11;
        w00 = 1.0; w10 = 0.0; w01 = 0.0; w11 = 1.0;
      }
      float cs0 = __builtin_amdgcn_sqrtf(fmaxf(EPS_REC - (float)th0, 0.f));
      float cs1 = __builtin_amdgcn_sqrtf(fmaxf(EPS_REC - (float)th1, 0.f));
      // TQ rank-2 (all lanes compute; lanes<16 write V rows, zero-padded)
      const int a16 = lane & 15;
      float t0 = 0.f, t1 = 0.f;
      #pragma unroll 4
      for (int j = 0; j < 32; ++j) {
        float2 qv = *(const float2*)(QS + 2 * j);
        float wv = W2S[j * 16 + a16];
        t0 += wv * qv.x; t1 += wv * qv.y;
      }
      if (lane < 16) {
        float va0 = cs0 * (float)((double)t0 * w00 + (double)t1 * w10);
        float va1 = cs1 * (float)((double)t0 * w01 + (double)t1 * w11);
        *(float4*)(VT + lane * 4) = make_float4(va0, va1, 0.f, 0.f);
      }
      CFENCE();
    } else {
      // ---- rank-4: f64 GS + Rayleigh-Ritz (verified path, unchanged) ----
      double v0 = (double)(y1.x * rd2), v1 = (double)(y1.y * rd2);
      double v2 = (double)(y1.z * rd2), v3 = (double)(y1.w * rd2);
      double n, pr, q0, q1, q2, q3;
      n = 0.5 * dsum64(v0 * v0); q0 = v0 * (1.0 / sqrt(n + 1e-280));
      pr = 0.5 * dsum64(q0 * v1); v1 -= pr * q0;
      n = 0.5 * dsum64(v1 * v1); q1 = v1 * (1.0 / sqrt(n + 1e-280));
      pr = 0.5 * dsum64(q0 * v2); v2 -= pr * q0;
      pr = 0.5 * dsum64(q1 * v2); v2 -= pr * q1;
      n = 0.5 * dsum64(v2 * v2); q2 = v2 * (1.0 / sqrt(n + 1e-280));
      pr = 0.5 * dsum64(q0 * v3); v3 -= pr * q0;
      pr = 0.5 * dsum64(q1 * v3); v3 -= pr * q1;
      pr = 0.5 * dsum64(q2 * v3); v3 -= pr * q2;
      n = 0.5 * dsum64(v3 * v3); q3 = v3 * (1.0 / sqrt(n + 1e-280));
      if (h == 0)
        *(float4*)(QS + 4 * kc) =
            make_float4((float)q0, (float)q1, (float)q2, (float)q3);
      CFENCE();
      double T0 = 0, T1 = 0, T2 = 0, T3 = 0;
      #pragma unroll
      for (int r = 0; r < 16; ++r) {
        float4 qv = *(const float4*)(QS + 4 * (hb + r));
        double xv = (double)A[kc * 36 + hb + r];
        T0 += xv * qv.x; T1 += xv * qv.y; T2 += xv * qv.z; T3 += xv * qv.w;
      }
      double S00 = dsum64(q0 * T0), S10 = dsum64(q1 * T0);
      double S20 = dsum64(q2 * T0), S30 = dsum64(q3 * T0);
      double S11 = dsum64(q1 * T1), S21 = dsum64(q2 * T1), S31 = dsum64(q3 * T1);
      double S22 = dsum64(q2 * T2), S32 = dsum64(q3 * T2);
      double S33 = dsum64(q3 * T3);
      if (lane == 0) {
        double Ad[4][4] = {{S00, S10, S20, S30}, {S10, S11, S21, S31},
                           {S20, S21, S22, S32}, {S30, S31, S32, S33}};
        float Wd[4][4] = {{1.f, 0.f, 0.f, 0.f}, {0.f, 1.f, 0.f, 0.f},
                          {0.f, 0.f, 1.f, 0.f}, {0.f, 0.f, 0.f, 1.f}};
        for (int sw = 0; sw < 5; ++sw) {
          #pragma unroll
          for (int p = 0; p < 3; ++p) {
            #pragma unroll
            for (int q = p + 1; q < 4; ++q) {
              double apq = Ad[p][q];
              if (fabs(apq) > 1e-14 * (fabs(Ad[p][p]) + fabs(Ad[q][q])) + 1e-300) {
                double tau = 0.5 * (Ad[q][q] - Ad[p][p]);
                double rr = sqrt(tau * tau + apq * apq);
                double t = ((tau >= 0.0) ? apq : -apq) / (fabs(tau) + rr);
                double c = 1.0 / sqrt(t * t + 1.0), sv = t * c;
                #pragma unroll
                for (int jj = 0; jj < 4; ++jj) {
                  double ap = Ad[p][jj], aq = Ad[q][jj];
                  Ad[p][jj] = c * ap - sv * aq;
                  Ad[q][jj] = sv * ap + c * aq;
                }
                #pragma unroll
                for (int ii = 0; ii < 4; ++ii) {
                  double ap = Ad[ii][p], aq = Ad[ii][q];
                  Ad[ii][p] = c * ap - sv * aq;
                  Ad[ii][q] = sv * ap + c * aq;
                  float wp = Wd[ii][p], wq = Wd[ii][q];
                  Wd[ii][p] = (float)(c * wp - sv * wq);
                  Wd[ii][q] = (float)(sv * wp + c * wq);
                }
              }
            }
          }
        }
        #pragma unroll
        for (int qi = 0; qi < 4; ++qi) {
          NRM[16 + qi] = (float)Ad[qi][qi];
          #pragma unroll
          for (int ai = 0; ai < 4; ++ai) NRM[ai * 4 + qi] = Wd[ai][qi];
        }
      }
      CFENCE();
    }
  }

  if (doeig) {
    // ---- fallback: full one-sided Jacobi on X1 (already in LDS) ----
    jac32(A, NRM, lane);
  }

  // ---- E (fast: scz=1) / Z (slow: scz=sqrt(mu)/lam) in place over A cols ----
  {
    float g[16];
    #pragma unroll
    for (int c = 0; c < 4; ++c) {
      float4 v = *(const float4*)(A + kc * 36 + hb + 4 * c);
      g[4 * c] = v.x; g[4 * c + 1] = v.y; g[4 * c + 2] = v.z; g[4 * c + 3] = v.w;
    }
    float scz = 1.f;
    if (doeig) {
      float dpp = 0.f;
      #pragma unroll
      for (int i = 0; i < 16; ++i) dpp += g[i] * g[i];
      dpp += shfl_xor_f(dpp, 1);
      float lam = __builtin_amdgcn_sqrtf(dpp);
      float mu  = fmaxf(lam, 1e-4f);
      scz = __builtin_amdgcn_sqrtf(mu) * __builtin_amdgcn_rcpf(fmaxf(lam, 1e-30f));
    }
    float part[16];
    #pragma unroll
    for (int a = 0; a < 16; ++a) part[a] = 0.f;
    #pragma unroll
    for (int r = 0; r < 16; ++r) {
      const float4* w2r = (const float4*)(W2S + (hb + r) * 16);
      ACC16(part, g[r], w2r);
    }
    #pragma unroll
    for (int a = 0; a < 16; ++a) part[a] = dpp_add_xor1(part[a]) * scz;
    CFENCE();
    if (h == 0) {
      *(float4*)(A + kc * 36 + 0)  = make_float4(part[0],  part[1],  part[2],  part[3]);
      *(float4*)(A + kc * 36 + 4)  = make_float4(part[4],  part[5],  part[6],  part[7]);
      *(float4*)(A + kc * 36 + 8)  = make_float4(part[8],  part[9],  part[10], part[11]);
      *(float4*)(A + kc * 36 + 12) = make_float4(part[12], part[13], part[14], part[15]);
    }
    CFENCE();
  }

  if (docorr && mneg >= 2) {
    // ---- rank-4 TQ = w2^T Q (w2 from LDS) + V (unchanged) ----
    const int aq = lane >> 4, a16 = lane & 15;
    float tq = 0.f;
    #pragma unroll 4
    for (int j = 0; j < 32; ++j)
      tq += W2S[j * 16 + a16] * QS[4 * j + aq];
    VT[aq * 16 + a16] = tq;
    CFENCE();
    if (lane < 16) {
      float t0 = VT[lane], t1 = VT[16 + lane];
      float t2 = VT[32 + lane], t3 = VT[48 + lane];
      float4 vv;
      {
        float cs = __builtin_amdgcn_sqrtf(fmaxf(EPS_REC - NRM[16], 0.f));
        vv.x = cs * (t0 * NRM[0] + t1 * NRM[4] + t2 * NRM[8] + t3 * NRM[12]);
      }
      {
        float cs = __builtin_amdgcn_sqrtf(fmaxf(EPS_REC - NRM[17], 0.f));
        vv.y = cs * (t0 * NRM[1] + t1 * NRM[5] + t2 * NRM[9] + t3 * NRM[13]);
      }
      {
        float cs = __builtin_amdgcn_sqrtf(fmaxf(EPS_REC - NRM[18], 0.f));
        vv.z = cs * (t0 * NRM[2] + t1 * NRM[6] + t2 * NRM[10] + t3 * NRM[14]);
      }
      {
        float cs = __builtin_amdgcn_sqrtf(fmaxf(EPS_REC - NRM[19], 0.f));
        vv.w = cs * (t0 * NRM[3] + t1 * NRM[7] + t2 * NRM[11] + t3 * NRM[15]);
      }
      CFENCE();
      *(float4*)(VT + lane * 4) = vv;
    }
    CFENCE();
  }

  // ---- M2 (16x16) in place over A[0,320) stride 20 (+rank-k corr) ----
  {
    const int a = lane & 15, b0i = (lane >> 4) * 4;
    float m0 = 0.f, m1 = 0.f, m2 = 0.f, m3 = 0.f;
    if (!doeig) {
      #pragma unroll
      for (int kk = 0; kk < 32; ++kk) {
        float za = A[kk * 36 + a];                           // E[a][kk]
        float4 zb = *(const float4*)(W2S + kk * 16 + b0i);   // w2[kk][b..]
        m0 += za * zb.x; m1 += za * zb.y; m2 += za * zb.z; m3 += za * zb.w;
      }
    } else {
      #pragma unroll
      for (int kk = 0; kk < 32; ++kk) {
        float za = A[kk * 36 + a];                           // Z[a][kk]
        float4 zb = *(const float4*)(A + kk * 36 + b0i);     // Z[b..][kk]
        m0 += za * zb.x; m1 += za * zb.y; m2 += za * zb.z; m3 += za * zb.w;
      }
    }
    if (docorr) {
      float4 va = *(const float4*)(VT + a * 4);
      float4 v0 = *(const float4*)(VT + (b0i + 0) * 4);
      float4 v1 = *(const float4*)(VT + (b0i + 1) * 4);
      float4 v2 = *(const float4*)(VT + (b0i + 2) * 4);
      float4 v3 = *(const float4*)(VT + (b0i + 3) * 4);
      m0 += dot4(va, v0); m1 += dot4(va, v1);
      m2 += dot4(va, v2); m3 += dot4(va, v3);
    }
    CFENCE();                      // all E/Z reads issued before M2 stores
    A[(b0i + 0) * 20 + a] = m0;
    A[(b0i + 1) * 20 + a] = m1;
    A[(b0i + 2) * 20 + a] = m2;
    A[(b0i + 3) * 20 + a] = m3;
    W3S[(lane & 3) * 20 + (lane >> 2)] = w3[lane];   // w3 col-major
  }
  CFENCE();

  // ---- norms of M2 columns ----
  if (lane < 32) {
    int cc = lane >> 1;
    float4 v0 = *(const float4*)(A + cc * 20 + 8 * h);
    float4 v1 = *(const float4*)(A + cc * 20 + 8 * h + 4);
    float n2 = dot4(v0, v0) + dot4(v1, v1);
    n2 += shfl_xor_f(n2, 1);
    if (h == 0) NRM[cc] = n2;
  }
  CFENCE();

  // ---- chol16 PD certificate on M2, f64 (Cd @ A+320, disjoint from M2) ----
  bool fast2 = true;
  {
    double* Cd = (double*)(A + 320);
    const int c16 = lane >> 2, s4 = (lane & 3) * 4;
    #pragma unroll
    for (int r = 0; r < 4; ++r)
      Cd[c16 * 20 + s4 + r] = (double)A[c16 * 20 + s4 + r];
    CFENCE();
    if (lane < 16) Cd[lane * 20 + lane] -= DELTA2;
    for (int k = 0; k < 16; ++k) {
      CFENCE();
      double d = Cd[k * 20 + k];
      if (!(d > 0.0)) { fast2 = false; break; }
      double rd = 1.0 / d;
      if (c16 > k) {
        double f = Cd[c16 * 20 + k] * rd;
        #pragma unroll
        for (int r = 0; r < 4; ++r)
          Cd[c16 * 20 + s4 + r] -= f * Cd[k * 20 + s4 + r];
      }
    }
  }
  CFENCE();

  if (fast2) {
    // ---- FAST stage 2: rec2 = M2. Y @ A+320 (Cd dead), X3 @ A+384 ----
    const int k3 = (lane >> 2) & 15, a3 = lane & 3;
    float dotv = 0.f;
    #pragma unroll
    for (int c = 0; c < 4; ++c) {
      float4 gv = *(const float4*)(A + k3 * 20 + 4 * c);
      float4 wv = *(const float4*)(W3S + a3 * 20 + 4 * c);
      dotv += dot4(gv, wv);
    }
    CFENCE();
    A[320 + k3 * 4 + a3] = dotv;           // Y
    CFENCE();
    if (lane < 16) {
      int a = lane >> 2, b2 = lane & 3;
      float s = 0.f;
      #pragma unroll
      for (int kk = 0; kk < 16; ++kk)
        s += A[320 + kk * 4 + a] * W3S[b2 * 20 + kk];
      A[384 + lane] = s;                   // X3
    }
    CFENCE();
  } else {
    // ---- SLOW stage 2: eig #2 + Y + X3 ----
    jac16(A, NRM, lane);
    {
      const int k3 = (lane >> 2) & 15, a3 = lane & 3;
      float dpp2 = 0.f, dotv = 0.f;
      #pragma unroll
      for (int c = 0; c < 4; ++c) {
        float4 gv = *(const float4*)(A + k3 * 20 + 4 * c);
        float4 wv = *(const float4*)(W3S + a3 * 20 + 4 * c);
        dpp2 += dot4(gv, gv);
        dotv += dot4(gv, wv);
      }
      float lam2 = __builtin_amdgcn_sqrtf(dpp2);
      float mu2  = fmaxf(lam2, 1e-4f);
      float sc2  = __builtin_amdgcn_sqrtf(mu2) * __builtin_amdgcn_rcpf(fmaxf(lam2, 1e-30f));
      CFENCE();
      A[320 + k3 * 4 + a3] = dotv * sc2;   // Y
    }
    CFENCE();
    if (lane < 16) {
      int a = lane >> 2, b2 = lane & 3;
      float s = 0.f;
      #pragma unroll
      for (int kk = 0; kk < 16; ++kk)
        s += A[320 + kk * 4 + a] * A[320 + kk * 4 + b2];
      A[384 + lane] = s;                   // X3
    }
    CFENCE();
  }

  // ---- stage 3: serial 4x4 two-sided Jacobi + LogEig + fc + log_softmax ----
  if (lane == 0) {
    float Am[4][4], V[4][4];
    float maxdg = 0.f;
    #pragma unroll
    for (int i = 0; i < 4; ++i) {
      #pragma unroll
      for (int j = 0; j < 4; ++j) {
        Am[i][j] = A[384 + i * 4 + j];
        V[i][j] = (i == j) ? 1.f : 0.f;
      }
      maxdg = fmaxf(maxdg, fabsf(Am[i][i]));
    }
    float tol3 = 1e-7f * maxdg;
    for (int sw = 0; sw < MAXSW4; ++sw) {
      bool any = false;
      #pragma unroll
      for (int p = 0; p < 3; ++p) {
        #pragma unroll
        for (int q = p + 1; q < 4; ++q) {
          float apq = Am[p][q];
          if (fabsf(apq) > tol3) {
            any = true;
            float c, sv;
            rot_cs(apq, Am[p][p], Am[q][q], c, sv);
            #pragma unroll
            for (int j = 0; j < 4; ++j) {
              float ap = Am[p][j], aq = Am[q][j];
              Am[p][j] = c * ap - sv * aq;
              Am[q][j] = sv * ap + c * aq;
            }
            #pragma unroll
            for (int i = 0; i < 4; ++i) {
              float ap = Am[i][p], aq = Am[i][q];
              Am[i][p] = c * ap - sv * aq;
              Am[i][q] = sv * ap + c * aq;
              float up = V[i][p], uq = V[i][q];
              V[i][p] = c * up - sv * uq;
              V[i][q] = sv * up + c * uq;
            }
          }
        }
      }
      if (!any) break;
    }
    float lm[4];
    #pragma unroll
    for (int i = 0; i < 4; ++i) lm[i] = logf(fmaxf(Am[i][i], 1e-10f));
    float feat[16];
    #pragma unroll
    for (int i = 0; i < 4; ++i)
      #pragma unroll
      for (int j = 0; j < 4; ++j) {
        float acc2 = 0.f;
        #pragma unroll
        for (int kk = 0; kk < 4; ++kk) acc2 += V[i][kk] * lm[kk] * V[j][kk];
        feat[i * 4 + j] = acc2;
      }
    float z0 = 0.f, z1 = 0.f;
    #pragma unroll
    for (int f = 0; f < 16; ++f) {
      z0 += feat[f] * fcw[f * 2 + 0];
      z1 += feat[f] * fcw[f * 2 + 1];
    }
    float mx = fmaxf(z0, z1);
    float lse = mx + logf(expf(z0 - mx) + expf(z1 - mx));
    out[b * 2 + 0] = z0 - lse;
    out[b * 2 + 1] = z1 - lse;
    float* fo = out + (size_t)2 * B + (size_t)b * 16;
    #pragma unroll
    for (int f = 0; f < 16; ++f) fo[f] = feat[f];
  }
}

extern "C" void kernel_launch(void* const* d_in, const int* in_sizes, int n_in,
                              void* d_out, int out_size, void* d_ws, size_t ws_size,
                              hipStream_t stream) {
  (void)n_in; (void)d_ws; (void)ws_size; (void)out_size;
  const float* x   = (const float*)d_in[0];
  const float* w1  = (const float*)d_in[1];
  const float* w2  = (const float*)d_in[2];
  const float* w3  = (const float*)d_in[3];
  const float* fcw = (const float*)d_in[4];
  float* out = (float*)d_out;
  int B = in_sizes[0] / 1024;
  spdnet_kernel<<<B, 64, 0, stream>>>(x, w1, w2, w3, fcw, out, B);
}

// Round 12
// 547.927 us; speedup vs baseline: 5.1959x; 1.2565x over previous
//
#include <hip/hip_runtime.h>
#include <math.h>

// SPDNet forward. Round 19: single-pass shift-invert for mneg==1.
// r18 (rank-2 RR) confirmed mneg==1 dominates and serial work is the cost
// (dispatch 722->600, VALUBusy 60->48: latency-chain-bound). Remaining spine:
// GJ pass1 -> GJ pass2 -> RR -> E -> M2 -> f64 chol16 -> lane-0 stage3.
// This round deletes GJ pass 2 for mneg==1: only theta0<eps gets a nonzero
// correction (theta1 > shift=4eps always has (eps-theta)+ = 0, pure shield);
// the rank-2 RR already deflates the nearest contaminant exactly, so the
// single-pass subspace error is second-order in theta0. Correction magnitude
// ~3e-3 in M2; few-% RR error perturbs outputs ~1e-4 << absmax 0.0625.
// mneg in [2,4] keeps the verified 2-pass rank-4 path bit-for-bit; the
// classification (pass-1 pivots) is untouched.
//
// Structure (r16-r18): x staged in A (s32); L-loop x-from-LDS + w1 scalar
// global; L parked over dead x; X1-loop lv-from-LDS + w1 rows global; X1/E/Z
// s36 over A; M2 in place over dead E at A[0,320); Cd f64 @A+320; Y@320
// X3@384; w2 in W2S; slice 2004 fl = 8016B. __launch_bounds__(64,4): VGPR
// cap 64, no spill (r17/r18: WRITE 3MB).

#define MAXSW32 8
#define MAXSW16 8
#define MAXSW4  8
#define JTOL2   1e-12f
#define EPS_REC 1e-4f
#define SHIFT1  4e-4f
#define BRKTOL  1e-7f
#define DELTA2  2e-4

#define SLICE   2004
#define OFF_PB  1152
#define OFF_NRM 1188
#define OFF_W3  1220
#define OFF_VT  1300
#define OFF_Q   1364
#define OFF_W2  1492

// Compiler-only memory fence (wave-private LDS: HW-ordered per wave).
#define CFENCE() asm volatile("" ::: "memory")

#define ACC16(part, av, w2r) do { \
  float4 _w0 = (w2r)[0], _w1 = (w2r)[1], _w2 = (w2r)[2], _w3 = (w2r)[3]; \
  float _a = (av); \
  part[0]+=_a*_w0.x; part[1]+=_a*_w0.y; part[2]+=_a*_w0.z; part[3]+=_a*_w0.w; \
  part[4]+=_a*_w1.x; part[5]+=_a*_w1.y; part[6]+=_a*_w1.z; part[7]+=_a*_w1.w; \
  part[8]+=_a*_w2.x; part[9]+=_a*_w2.y; part[10]+=_a*_w2.z; part[11]+=_a*_w2.w; \
  part[12]+=_a*_w3.x; part[13]+=_a*_w3.y; part[14]+=_a*_w3.z; part[15]+=_a*_w3.w; \
} while (0)

__device__ __forceinline__ float shfl_xor_f(float v, int m) { return __shfl_xor(v, m, 64); }
__device__ __forceinline__ float dot4(float4 a, float4 b) {
  return a.x * b.x + a.y * b.y + a.z * b.z + a.w * b.w;
}
__device__ __forceinline__ void axpy4(float4& a, float xv, float4 w) {
  a.x += xv * w.x; a.y += xv * w.y; a.z += xv * w.z; a.w += xv * w.w;
}

__device__ __forceinline__ float dpp_add_xor1(float d) {
  return d + __int_as_float(__builtin_amdgcn_mov_dpp(__float_as_int(d), 0xB1, 0xF, 0xF, true));
}
__device__ __forceinline__ float dpp_add_xor2(float d) {
  return d + __int_as_float(__builtin_amdgcn_mov_dpp(__float_as_int(d), 0x4E, 0xF, 0xF, true));
}
__device__ __forceinline__ float dpp_add_halfmirror(float d) {
  return d + __int_as_float(__builtin_amdgcn_mov_dpp(__float_as_int(d), 0x141, 0xF, 0xF, true));
}

__device__ __forceinline__ double dsum64(double v) {
  #pragma unroll
  for (int m = 1; m <= 32; m <<= 1) v += __shfl_xor(v, m, 64);
  return v;
}
__device__ __forceinline__ float wmax64(float v) {
  #pragma unroll
  for (int m = 1; m <= 32; m <<= 1) v = fmaxf(v, __shfl_xor(v, m, 64));
  return v;
}

__device__ __forceinline__ void rot_cs(float d, float dpp, float dqq,
                                       float& c, float& s) {
  float tau = 0.5f * (dqq - dpp);
  float r   = __builtin_amdgcn_sqrtf(fmaf(tau, tau, d * d));
  float den = fabsf(tau) + r;
  float tnum = __uint_as_float(__float_as_uint(d) ^
                               (__float_as_uint(tau) & 0x80000000u));
  float t = tnum * __builtin_amdgcn_rcpf(den);
  c = __builtin_amdgcn_rsqf(fmaf(t, t, 1.f));
  s = t * c;
}

// Register-resident Gauss-Jordan of A = X1 - SHIFT1*I, 4 RHS in regs.
// Rows loaded from X1 in LDS (stride 36) at entry.
__device__ __forceinline__ void gj_reg(const float* __restrict__ X1,
                                       float* __restrict__ PB,
                                       int kc, int h, int hb, float maxd,
                                       float4& y, float& down,
                                       int& mneg, bool& brk) {
  float4 r0 = *(const float4*)(X1 + kc * 36 + hb);
  float4 r1 = *(const float4*)(X1 + kc * 36 + hb + 4);
  float4 r2 = *(const float4*)(X1 + kc * 36 + hb + 8);
  float4 r3 = *(const float4*)(X1 + kc * 36 + hb + 12);
  const int dc = kc - hb;
  r0.x -= (dc == 0)  ? SHIFT1 : 0.f;
  r0.y -= (dc == 1)  ? SHIFT1 : 0.f;
  r0.z -= (dc == 2)  ? SHIFT1 : 0.f;
  r0.w -= (dc == 3)  ? SHIFT1 : 0.f;
  r1.x -= (dc == 4)  ? SHIFT1 : 0.f;
  r1.y -= (dc == 5)  ? SHIFT1 : 0.f;
  r1.z -= (dc == 6)  ? SHIFT1 : 0.f;
  r1.w -= (dc == 7)  ? SHIFT1 : 0.f;
  r2.x -= (dc == 8)  ? SHIFT1 : 0.f;
  r2.y -= (dc == 9)  ? SHIFT1 : 0.f;
  r2.z -= (dc == 10) ? SHIFT1 : 0.f;
  r2.w -= (dc == 11) ? SHIFT1 : 0.f;
  r3.x -= (dc == 12) ? SHIFT1 : 0.f;
  r3.y -= (dc == 13) ? SHIFT1 : 0.f;
  r3.z -= (dc == 14) ? SHIFT1 : 0.f;
  r3.w -= (dc == 15) ? SHIFT1 : 0.f;

  mneg = 0; brk = false; down = 1.f;
  #pragma unroll
  for (int k = 0; k < 32; ++k) {
    if (kc == k) {
      *(float4*)(PB + hb)      = r0;
      *(float4*)(PB + hb + 4)  = r1;
      *(float4*)(PB + hb + 8)  = r2;
      *(float4*)(PB + hb + 12) = r3;
      if (h == 0) *(float4*)(PB + 32) = y;
    }
    CFENCE();
    const float  d  = PB[k];
    const float4 p0 = *(const float4*)(PB + hb);
    const float4 p1 = *(const float4*)(PB + hb + 4);
    const float4 p2 = *(const float4*)(PB + hb + 8);
    const float4 p3 = *(const float4*)(PB + hb + 12);
    const float4 py = *(const float4*)(PB + 32);
    CFENCE();
    mneg += (d <= 0.f) ? 1 : 0;
    brk = brk || !(fabsf(d) >= BRKTOL * maxd);
    float elt;
    {
      const int q = (k >> 2) & 3;
      const float4 rq = (q == 0) ? r0 : (q == 1) ? r1 : (q == 2) ? r2 : r3;
      const int m = k & 3;
      elt = (m == 0) ? rq.x : (m == 1) ? rq.y : (m == 2) ? rq.z : rq.w;
    }
    const bool ownhalf = (k >= 16) ? (h == 1) : (h == 0);
    float tm = ownhalf ? elt : 0.f;
    float f  = dpp_add_xor1(tm);
    float fr = f * __builtin_amdgcn_rcpf(d);
    fr   = (brk || (kc == k)) ? 0.f : fr;
    down = (kc == k) ? d : down;
    axpy4(r0, -fr, p0);
    axpy4(r1, -fr, p1);
    axpy4(r2, -fr, p2);
    axpy4(r3, -fr, p3);
    axpy4(y,  -fr, py);
  }
}

// One-sided Jacobi, n=32, column stride 36. 16 pairs x 4 lanes.
__device__ __forceinline__ void jac32(float* __restrict__ G, float* __restrict__ nrm,
                                      int lane) {
  const int kq  = lane >> 2, sub = lane & 3;
  const int k = (kq & 8) | ((kq & 1) << 2) | (kq & 2) | ((kq & 4) >> 2);
  const int o0 = 4 * sub, o1 = 4 * sub + 16;
  int pp = (k == 0) ? 31 : k;
  int qq = (k == 0) ? 0 : (31 - k);
  for (int sw = 0; sw < MAXSW32; ++sw) {
    bool anyact = false;
    for (int r = 0; r < 31; ++r) {
      CFENCE();
      const int p = pp, q = qq;
      if (k != 0) { pp += 16; if (pp >= 31) pp -= 31; }
      qq += 16; if (qq >= 31) qq -= 31;
      const int pb = p * 36, qb = q * 36;
      float dpp = nrm[p], dqq = nrm[q];
      float4 gp0 = *(const float4*)(G + pb + o0);
      float4 gp1 = *(const float4*)(G + pb + o1);
      float4 gq0 = *(const float4*)(G + qb + o0);
      float4 gq1 = *(const float4*)(G + qb + o1);
      float d = dot4(gp0, gq0) + dot4(gp1, gq1);
      d = dpp_add_xor1(d);
      d = dpp_add_xor2(d);
      bool active = (d * d > JTOL2 * dpp * dqq);
      if (__ballot(active) == 0ull) continue;
      anyact = true;
      if (active) {
        float c, s;
        rot_cs(d, dpp, dqq, c, s);
        float4 np0, np1, nq0, nq1;
        np0.x = c * gp0.x - s * gq0.x; nq0.x = s * gp0.x + c * gq0.x;
        np0.y = c * gp0.y - s * gq0.y; nq0.y = s * gp0.y + c * gq0.y;
        np0.z = c * gp0.z - s * gq0.z; nq0.z = s * gp0.z + c * gq0.z;
        np0.w = c * gp0.w - s * gq0.w; nq0.w = s * gp0.w + c * gq0.w;
        np1.x = c * gp1.x - s * gq1.x; nq1.x = s * gp1.x + c * gq1.x;
        np1.y = c * gp1.y - s * gq1.y; nq1.y = s * gp1.y + c * gq1.y;
        np1.z = c * gp1.z - s * gq1.z; nq1.z = s * gp1.z + c * gq1.z;
        np1.w = c * gp1.w - s * gq1.w; nq1.w = s * gp1.w + c * gq1.w;
        *(float4*)(G + pb + o0) = np0;
        *(float4*)(G + pb + o1) = np1;
        *(float4*)(G + qb + o0) = nq0;
        *(float4*)(G + qb + o1) = nq1;
        if (sub == 0) {
          float cs2 = 2.f * c * s * d, cc = c * c, ss = s * s;
          nrm[p] = cc * dpp - cs2 + ss * dqq;
          nrm[q] = ss * dpp + cs2 + cc * dqq;
        }
      }
    }
    if (!anyact) break;
  }
  CFENCE();
}

// One-sided Jacobi, n=16, column stride 20. 8 pairs x 8 lanes.
__device__ __forceinline__ void jac16(float* __restrict__ G, float* __restrict__ nrm,
                                      int lane) {
  const int kq = lane >> 3, sub = lane & 7;
  const int k = (kq >> 1) | ((kq & 1) << 2);
  const int o = 2 * sub;
  int pp = (k == 0) ? 15 : k;
  int qq = (k == 0) ? 0 : (15 - k);
  for (int sw = 0; sw < MAXSW16; ++sw) {
    bool anyact = false;
    for (int r = 0; r < 15; ++r) {
      CFENCE();
      const int p = pp, q = qq;
      if (k != 0) { pp += 8; if (pp >= 15) pp -= 15; }
      qq += 8; if (qq >= 15) qq -= 15;
      const int pb = p * 20 + o, qb = q * 20 + o;
      float dpp = nrm[p], dqq = nrm[q];
      float2 gp = *(const float2*)(G + pb);
      float2 gq = *(const float2*)(G + qb);
      float d = gp.x * gq.x + gp.y * gq.y;
      d = dpp_add_xor1(d);
      d = dpp_add_xor2(d);
      d = dpp_add_halfmirror(d);
      bool active = (d * d > JTOL2 * dpp * dqq);
      if (__ballot(active) == 0ull) continue;
      anyact = true;
      if (active) {
        float c, s;
        rot_cs(d, dpp, dqq, c, s);
        float2 np, nq;
        np.x = c * gp.x - s * gq.x; nq.x = s * gp.x + c * gq.x;
        np.y = c * gp.y - s * gq.y; nq.y = s * gp.y + c * gq.y;
        *(float2*)(G + pb) = np;
        *(float2*)(G + qb) = nq;
        if (sub == 0) {
          float cs2 = 2.f * c * s * d, cc = c * c, ss = s * s;
          nrm[p] = cc * dpp - cs2 + ss * dqq;
          nrm[q] = ss * dpp + cs2 + cc * dqq;
        }
      }
    }
    if (!anyact) break;
  }
  CFENCE();
}

__launch_bounds__(64, 4)
__global__ void spdnet_kernel(const float* __restrict__ x,
                              const float* __restrict__ w1,
                              const float* __restrict__ w2,
                              const float* __restrict__ w3,
                              const float* __restrict__ fcw,
                              float* __restrict__ out,
                              int B) {
  const int lane = threadIdx.x;
  const int b    = blockIdx.x;

  __shared__ __align__(16) float SH[SLICE];
  float* const A   = SH;             // x(s32) -> L(s32) -> X1/E/Z(s36) -> M2(s20,[0,320)) | Cd f64 @320 | Y@320 X3@384
  float* const PB  = SH + OFF_PB;    // 36: GJ pivot broadcast
  float* const NRM = SH + OFF_NRM;   // 32
  float* const W3S = SH + OFF_W3;    // 80: w3 col-major stride 20
  float* const VT  = SH + OFF_VT;    // 64: TQ then V
  float* const QS  = SH + OFF_Q;     // 128: Q rows
  float* const W2S = SH + OFF_W2;    // 512: w2 row-major

  const float* xb = x + (size_t)b * 1024;
  const int kc = lane >> 1, h = lane & 1, hb = h * 16;

  // ---- stage x -> A[0,1024) (stride 32) and w2 -> W2S ----
  #pragma unroll
  for (int t = 0; t < 4; ++t)
    ((float4*)A)[lane + 64 * t] = ((const float4*)xb)[lane + 64 * t];
  #pragma unroll
  for (int t = 0; t < 2; ++t)
    ((float4*)W2S)[lane + 64 * t] = ((const float4*)w2)[lane + 64 * t];
  CFENCE();

  // ---- L = x*w1 half-columns in regs (a[r] = L[hb+r][kc]); x from LDS ----
  float4 a0 = {0.f, 0.f, 0.f, 0.f}, a1 = a0, a2 = a0, a3 = a0;
  #pragma unroll 8
  for (int j = 0; j < 32; ++j) {
    float wv = w1[j * 32 + kc];              // 128B broadcast segment, L1
    const float4* xr = (const float4*)(A + j * 32 + hb);
    axpy4(a0, wv, xr[0]);
    axpy4(a1, wv, xr[1]);
    axpy4(a2, wv, xr[2]);
    axpy4(a3, wv, xr[3]);
  }
  CFENCE();                                  // all x reads done
  // ---- park L over dead x: A[j*32 + kc] = L[j][kc] ----
  A[(hb + 0)  * 32 + kc] = a0.x; A[(hb + 1)  * 32 + kc] = a0.y;
  A[(hb + 2)  * 32 + kc] = a0.z; A[(hb + 3)  * 32 + kc] = a0.w;
  A[(hb + 4)  * 32 + kc] = a1.x; A[(hb + 5)  * 32 + kc] = a1.y;
  A[(hb + 6)  * 32 + kc] = a1.z; A[(hb + 7)  * 32 + kc] = a1.w;
  A[(hb + 8)  * 32 + kc] = a2.x; A[(hb + 9)  * 32 + kc] = a2.y;
  A[(hb + 10) * 32 + kc] = a2.z; A[(hb + 11) * 32 + kc] = a2.w;
  A[(hb + 12) * 32 + kc] = a3.x; A[(hb + 13) * 32 + kc] = a3.y;
  A[(hb + 14) * 32 + kc] = a3.z; A[(hb + 15) * 32 + kc] = a3.w;
  CFENCE();

  // ---- X1 half-row (b regs); lv = L[kk][kc] from LDS ----
  {
    float4 b0 = {0.f, 0.f, 0.f, 0.f}, b1 = b0, b2 = b0, b3 = b0;
    #pragma unroll 4
    for (int kk = 0; kk < 32; ++kk) {
      float lv = A[kk * 32 + kc];            // pair-broadcast LDS read
      const float4* wr = (const float4*)(w1 + kk * 32 + hb);
      axpy4(b0, lv, wr[0]);
      axpy4(b1, lv, wr[1]);
      axpy4(b2, lv, wr[2]);
      axpy4(b3, lv, wr[3]);
    }
    float nv = dot4(b0, b0) + dot4(b1, b1) + dot4(b2, b2) + dot4(b3, b3);
    nv += shfl_xor_f(nv, 1);
    CFENCE();                                // all L reads done
    // dump X1 over L (stride 36)
    *(float4*)(A + kc * 36 + hb)      = b0;
    *(float4*)(A + kc * 36 + hb + 4)  = b1;
    *(float4*)(A + kc * 36 + hb + 8)  = b2;
    *(float4*)(A + kc * 36 + hb + 12) = b3;
    if (h == 0) NRM[kc] = nv;
  }
  CFENCE();

  // ---- maxd = max diag (uniform pair read) ----
  float maxd = wmax64(A[kc * 36 + kc]);

  // ---- inertia + shift-invert pass 1 ----
  float4 yv;
  {
    unsigned s = kc * 0x9E3779B9u + 0x7F4A7C15u;
    s = s * 1664525u + 1013904223u; yv.x = (float)(int)(s >> 16) - 32768.f;
    s = s * 1664525u + 1013904223u; yv.y = (float)(int)(s >> 16) - 32768.f;
    s = s * 1664525u + 1013904223u; yv.z = (float)(int)(s >> 16) - 32768.f;
    s = s * 1664525u + 1013904223u; yv.w = (float)(int)(s >> 16) - 32768.f;
  }
  int mneg; bool brk; float down;
  gj_reg(A, PB, kc, h, hb, maxd, yv, down, mneg, brk);
  const bool doeig  = brk || (mneg > 4);
  const bool docorr = !doeig && (mneg >= 1);

  if (docorr) {
    float rd1 = __builtin_amdgcn_rcpf(down);
    float4 y1 = make_float4(yv.x * rd1, yv.y * rd1, yv.z * rd1, yv.w * rd1);

    if (mneg == 1) {
      // ---- SINGLE-PASS rank-2 RR: GS(2) + 2-col T + closed-form 2x2 ----
      // (rank-2 RR deflates the nearest contaminant; theta1 > shift always
      //  has zero correction, so only theta0 accuracy matters -> one
      //  inverse-iteration pass suffices at this tolerance.)
      double v0 = (double)y1.x, v1 = (double)y1.y;
      double n, pr, q0, q1;
      n = 0.5 * dsum64(v0 * v0); q0 = v0 * (1.0 / sqrt(n + 1e-280));
      pr = 0.5 * dsum64(q0 * v1); v1 -= pr * q0;
      n = 0.5 * dsum64(v1 * v1); q1 = v1 * (1.0 / sqrt(n + 1e-280));
      if (h == 0) *(float2*)(QS + 2 * kc) = make_float2((float)q0, (float)q1);
      CFENCE();
      double T0 = 0, T1 = 0;
      #pragma unroll
      for (int r = 0; r < 16; ++r) {
        float2 qv = *(const float2*)(QS + 2 * (hb + r));
        double xv = (double)A[kc * 36 + hb + r];
        T0 += xv * qv.x; T1 += xv * qv.y;
      }
      double T0p = T0 + __shfl_xor(T0, 1, 64);
      double T1p = T1 + __shfl_xor(T1, 1, 64);
      double S00 = 0.5 * dsum64(q0 * T0p);
      double S01 = 0.5 * dsum64(q0 * T1p);
      double S11 = 0.5 * dsum64(q1 * T1p);
      double th0, th1, w00, w10, w01, w11;
      if (fabs(S01) > 1e-14 * (fabs(S00) + fabs(S11)) + 1e-300) {
        double tr = S00 + S11, df = S00 - S11;
        double disc = sqrt(df * df + 4.0 * S01 * S01);
        th0 = 0.5 * (tr - disc); th1 = 0.5 * (tr + disc);
        double bb = th0 - S00, nn = 1.0 / sqrt(S01 * S01 + bb * bb);
        w00 = S01 * nn; w10 = bb * nn;
        bb = th1 - S00; nn = 1.0 / sqrt(S01 * S01 + bb * bb);
        w01 = S01 * nn; w11 = bb * nn;
      } else {
        th0 = S00; th1 = S11;
        w00 = 1.0; w10 = 0.0; w01 = 0.0; w11 = 1.0;
      }
      float cs0 = __builtin_amdgcn_sqrtf(fmaxf(EPS_REC - (float)th0, 0.f));
      float cs1 = __builtin_amdgcn_sqrtf(fmaxf(EPS_REC - (float)th1, 0.f));
      const int a16 = lane & 15;
      float t0 = 0.f, t1 = 0.f;
      #pragma unroll 4
      for (int j = 0; j < 32; ++j) {
        float2 qv = *(const float2*)(QS + 2 * j);
        float wv = W2S[j * 16 + a16];
        t0 += wv * qv.x; t1 += wv * qv.y;
      }
      if (lane < 16) {
        float va0 = cs0 * (float)((double)t0 * w00 + (double)t1 * w10);
        float va1 = cs1 * (float)((double)t0 * w01 + (double)t1 * w11);
        *(float4*)(VT + lane * 4) = make_float4(va0, va1, 0.f, 0.f);
      }
      CFENCE();
    } else {
      // ---- pass 2 (refine) + rank-4 f64 GS + RR (verified, unchanged) ----
      int mn2; bool b2; float down2;
      gj_reg(A, PB, kc, h, hb, maxd, y1, down2, mn2, b2);
      (void)mn2; (void)b2;
      float rd2 = __builtin_amdgcn_rcpf(down2);
      double v0 = (double)(y1.x * rd2), v1 = (double)(y1.y * rd2);
      double v2 = (double)(y1.z * rd2), v3 = (double)(y1.w * rd2);
      double n, pr, q0, q1, q2, q3;
      n = 0.5 * dsum64(v0 * v0); q0 = v0 * (1.0 / sqrt(n + 1e-280));
      pr = 0.5 * dsum64(q0 * v1); v1 -= pr * q0;
      n = 0.5 * dsum64(v1 * v1); q1 = v1 * (1.0 / sqrt(n + 1e-280));
      pr = 0.5 * dsum64(q0 * v2); v2 -= pr * q0;
      pr = 0.5 * dsum64(q1 * v2); v2 -= pr * q1;
      n = 0.5 * dsum64(v2 * v2); q2 = v2 * (1.0 / sqrt(n + 1e-280));
      pr = 0.5 * dsum64(q0 * v3); v3 -= pr * q0;
      pr = 0.5 * dsum64(q1 * v3); v3 -= pr * q1;
      pr = 0.5 * dsum64(q2 * v3); v3 -= pr * q2;
      n = 0.5 * dsum64(v3 * v3); q3 = v3 * (1.0 / sqrt(n + 1e-280));
      if (h == 0)
        *(float4*)(QS + 4 * kc) =
            make_float4((float)q0, (float)q1, (float)q2, (float)q3);
      CFENCE();
      double T0 = 0, T1 = 0, T2 = 0, T3 = 0;
      #pragma unroll
      for (int r = 0; r < 16; ++r) {
        float4 qv = *(const float4*)(QS + 4 * (hb + r));
        double xv = (double)A[kc * 36 + hb + r];
        T0 += xv * qv.x; T1 += xv * qv.y; T2 += xv * qv.z; T3 += xv * qv.w;
      }
      double S00 = dsum64(q0 * T0), S10 = dsum64(q1 * T0);
      double S20 = dsum64(q2 * T0), S30 = dsum64(q3 * T0);
      double S11 = dsum64(q1 * T1), S21 = dsum64(q2 * T1), S31 = dsum64(q3 * T1);
      double S22 = dsum64(q2 * T2), S32 = dsum64(q3 * T2);
      double S33 = dsum64(q3 * T3);
      if (lane == 0) {
        double Ad[4][4] = {{S00, S10, S20, S30}, {S10, S11, S21, S31},
                           {S20, S21, S22, S32}, {S30, S31, S32, S33}};
        float Wd[4][4] = {{1.f, 0.f, 0.f, 0.f}, {0.f, 1.f, 0.f, 0.f},
                          {0.f, 0.f, 1.f, 0.f}, {0.f, 0.f, 0.f, 1.f}};
        for (int sw = 0; sw < 5; ++sw) {
          #pragma unroll
          for (int p = 0; p < 3; ++p) {
            #pragma unroll
            for (int q = p + 1; q < 4; ++q) {
              double apq = Ad[p][q];
              if (fabs(apq) > 1e-14 * (fabs(Ad[p][p]) + fabs(Ad[q][q])) + 1e-300) {
                double tau = 0.5 * (Ad[q][q] - Ad[p][p]);
                double rr = sqrt(tau * tau + apq * apq);
                double t = ((tau >= 0.0) ? apq : -apq) / (fabs(tau) + rr);
                double c = 1.0 / sqrt(t * t + 1.0), sv = t * c;
                #pragma unroll
                for (int jj = 0; jj < 4; ++jj) {
                  double ap = Ad[p][jj], aq = Ad[q][jj];
                  Ad[p][jj] = c * ap - sv * aq;
                  Ad[q][jj] = sv * ap + c * aq;
                }
                #pragma unroll
                for (int ii = 0; ii < 4; ++ii) {
                  double ap = Ad[ii][p], aq = Ad[ii][q];
                  Ad[ii][p] = c * ap - sv * aq;
                  Ad[ii][q] = sv * ap + c * aq;
                  float wp = Wd[ii][p], wq = Wd[ii][q];
                  Wd[ii][p] = (float)(c * wp - sv * wq);
                  Wd[ii][q] = (float)(sv * wp + c * wq);
                }
              }
            }
          }
        }
        #pragma unroll
        for (int qi = 0; qi < 4; ++qi) {
          NRM[16 + qi] = (float)Ad[qi][qi];
          #pragma unroll
          for (int ai = 0; ai < 4; ++ai) NRM[ai * 4 + qi] = Wd[ai][qi];
        }
      }
      CFENCE();
    }
  }

  if (doeig) {
    // ---- fallback: full one-sided Jacobi on X1 (already in LDS) ----
    jac32(A, NRM, lane);
  }

  // ---- E (fast: scz=1) / Z (slow: scz=sqrt(mu)/lam) in place over A cols ----
  {
    float g[16];
    #pragma unroll
    for (int c = 0; c < 4; ++c) {
      float4 v = *(const float4*)(A + kc * 36 + hb + 4 * c);
      g[4 * c] = v.x; g[4 * c + 1] = v.y; g[4 * c + 2] = v.z; g[4 * c + 3] = v.w;
    }
    float scz = 1.f;
    if (doeig) {
      float dpp = 0.f;
      #pragma unroll
      for (int i = 0; i < 16; ++i) dpp += g[i] * g[i];
      dpp += shfl_xor_f(dpp, 1);
      float lam = __builtin_amdgcn_sqrtf(dpp);
      float mu  = fmaxf(lam, 1e-4f);
      scz = __builtin_amdgcn_sqrtf(mu) * __builtin_amdgcn_rcpf(fmaxf(lam, 1e-30f));
    }
    float part[16];
    #pragma unroll
    for (int a = 0; a < 16; ++a) part[a] = 0.f;
    #pragma unroll
    for (int r = 0; r < 16; ++r) {
      const float4* w2r = (const float4*)(W2S + (hb + r) * 16);
      ACC16(part, g[r], w2r);
    }
    #pragma unroll
    for (int a = 0; a < 16; ++a) part[a] = dpp_add_xor1(part[a]) * scz;
    CFENCE();
    if (h == 0) {
      *(float4*)(A + kc * 36 + 0)  = make_float4(part[0],  part[1],  part[2],  part[3]);
      *(float4*)(A + kc * 36 + 4)  = make_float4(part[4],  part[5],  part[6],  part[7]);
      *(float4*)(A + kc * 36 + 8)  = make_float4(part[8],  part[9],  part[10], part[11]);
      *(float4*)(A + kc * 36 + 12) = make_float4(part[12], part[13], part[14], part[15]);
    }
    CFENCE();
  }

  if (docorr && mneg >= 2) {
    // ---- rank-4 TQ = w2^T Q (w2 from LDS) + V (unchanged) ----
    const int aq = lane >> 4, a16 = lane & 15;
    float tq = 0.f;
    #pragma unroll 4
    for (int j = 0; j < 32; ++j)
      tq += W2S[j * 16 + a16] * QS[4 * j + aq];
    VT[aq * 16 + a16] = tq;
    CFENCE();
    if (lane < 16) {
      float t0 = VT[lane], t1 = VT[16 + lane];
      float t2 = VT[32 + lane], t3 = VT[48 + lane];
      float4 vv;
      {
        float cs = __builtin_amdgcn_sqrtf(fmaxf(EPS_REC - NRM[16], 0.f));
        vv.x = cs * (t0 * NRM[0] + t1 * NRM[4] + t2 * NRM[8] + t3 * NRM[12]);
      }
      {
        float cs = __builtin_amdgcn_sqrtf(fmaxf(EPS_REC - NRM[17], 0.f));
        vv.y = cs * (t0 * NRM[1] + t1 * NRM[5] + t2 * NRM[9] + t3 * NRM[13]);
      }
      {
        float cs = __builtin_amdgcn_sqrtf(fmaxf(EPS_REC - NRM[18], 0.f));
        vv.z = cs * (t0 * NRM[2] + t1 * NRM[6] + t2 * NRM[10] + t3 * NRM[14]);
      }
      {
        float cs = __builtin_amdgcn_sqrtf(fmaxf(EPS_REC - NRM[19], 0.f));
        vv.w = cs * (t0 * NRM[3] + t1 * NRM[7] + t2 * NRM[11] + t3 * NRM[15]);
      }
      CFENCE();
      *(float4*)(VT + lane * 4) = vv;
    }
    CFENCE();
  }

  // ---- M2 (16x16) in place over A[0,320) stride 20 (+rank-k corr) ----
  {
    const int a = lane & 15, b0i = (lane >> 4) * 4;
    float m0 = 0.f, m1 = 0.f, m2 = 0.f, m3 = 0.f;
    if (!doeig) {
      #pragma unroll
      for (int kk = 0; kk < 32; ++kk) {
        float za = A[kk * 36 + a];                           // E[a][kk]
        float4 zb = *(const float4*)(W2S + kk * 16 + b0i);   // w2[kk][b..]
        m0 += za * zb.x; m1 += za * zb.y; m2 += za * zb.z; m3 += za * zb.w;
      }
    } else {
      #pragma unroll
      for (int kk = 0; kk < 32; ++kk) {
        float za = A[kk * 36 + a];                           // Z[a][kk]
        float4 zb = *(const float4*)(A + kk * 36 + b0i);     // Z[b..][kk]
        m0 += za * zb.x; m1 += za * zb.y; m2 += za * zb.z; m3 += za * zb.w;
      }
    }
    if (docorr) {
      float4 va = *(const float4*)(VT + a * 4);
      float4 v0 = *(const float4*)(VT + (b0i + 0) * 4);
      float4 v1 = *(const float4*)(VT + (b0i + 1) * 4);
      float4 v2 = *(const float4*)(VT + (b0i + 2) * 4);
      float4 v3 = *(const float4*)(VT + (b0i + 3) * 4);
      m0 += dot4(va, v0); m1 += dot4(va, v1);
      m2 += dot4(va, v2); m3 += dot4(va, v3);
    }
    CFENCE();                      // all E/Z reads issued before M2 stores
    A[(b0i + 0) * 20 + a] = m0;
    A[(b0i + 1) * 20 + a] = m1;
    A[(b0i + 2) * 20 + a] = m2;
    A[(b0i + 3) * 20 + a] = m3;
    W3S[(lane & 3) * 20 + (lane >> 2)] = w3[lane];   // w3 col-major
  }
  CFENCE();

  // ---- norms of M2 columns ----
  if (lane < 32) {
    int cc = lane >> 1;
    float4 v0 = *(const float4*)(A + cc * 20 + 8 * h);
    float4 v1 = *(const float4*)(A + cc * 20 + 8 * h + 4);
    float n2 = dot4(v0, v0) + dot4(v1, v1);
    n2 += shfl_xor_f(n2, 1);
    if (h == 0) NRM[cc] = n2;
  }
  CFENCE();

  // ---- chol16 PD certificate on M2, f64 (Cd @ A+320, disjoint from M2) ----
  bool fast2 = true;
  {
    double* Cd = (double*)(A + 320);
    const int c16 = lane >> 2, s4 = (lane & 3) * 4;
    #pragma unroll
    for (int r = 0; r < 4; ++r)
      Cd[c16 * 20 + s4 + r] = (double)A[c16 * 20 + s4 + r];
    CFENCE();
    if (lane < 16) Cd[lane * 20 + lane] -= DELTA2;
    for (int k = 0; k < 16; ++k) {
      CFENCE();
      double d = Cd[k * 20 + k];
      if (!(d > 0.0)) { fast2 = false; break; }
      double rd = 1.0 / d;
      if (c16 > k) {
        double f = Cd[c16 * 20 + k] * rd;
        #pragma unroll
        for (int r = 0; r < 4; ++r)
          Cd[c16 * 20 + s4 + r] -= f * Cd[k * 20 + s4 + r];
      }
    }
  }
  CFENCE();

  if (fast2) {
    // ---- FAST stage 2: rec2 = M2. Y @ A+320 (Cd dead), X3 @ A+384 ----
    const int k3 = (lane >> 2) & 15, a3 = lane & 3;
    float dotv = 0.f;
    #pragma unroll
    for (int c = 0; c < 4; ++c) {
      float4 gv = *(const float4*)(A + k3 * 20 + 4 * c);
      float4 wv = *(const float4*)(W3S + a3 * 20 + 4 * c);
      dotv += dot4(gv, wv);
    }
    CFENCE();
    A[320 + k3 * 4 + a3] = dotv;           // Y
    CFENCE();
    if (lane < 16) {
      int a = lane >> 2, b2 = lane & 3;
      float s = 0.f;
      #pragma unroll
      for (int kk = 0; kk < 16; ++kk)
        s += A[320 + kk * 4 + a] * W3S[b2 * 20 + kk];
      A[384 + lane] = s;                   // X3
    }
    CFENCE();
  } else {
    // ---- SLOW stage 2: eig #2 + Y + X3 ----
    jac16(A, NRM, lane);
    {
      const int k3 = (lane >> 2) & 15, a3 = lane & 3;
      float dpp2 = 0.f, dotv = 0.f;
      #pragma unroll
      for (int c = 0; c < 4; ++c) {
        float4 gv = *(const float4*)(A + k3 * 20 + 4 * c);
        float4 wv = *(const float4*)(W3S + a3 * 20 + 4 * c);
        dpp2 += dot4(gv, gv);
        dotv += dot4(gv, wv);
      }
      float lam2 = __builtin_amdgcn_sqrtf(dpp2);
      float mu2  = fmaxf(lam2, 1e-4f);
      float sc2  = __builtin_amdgcn_sqrtf(mu2) * __builtin_amdgcn_rcpf(fmaxf(lam2, 1e-30f));
      CFENCE();
      A[320 + k3 * 4 + a3] = dotv * sc2;   // Y
    }
    CFENCE();
    if (lane < 16) {
      int a = lane >> 2, b2 = lane & 3;
      float s = 0.f;
      #pragma unroll
      for (int kk = 0; kk < 16; ++kk)
        s += A[320 + kk * 4 + a] * A[320 + kk * 4 + b2];
      A[384 + lane] = s;                   // X3
    }
    CFENCE();
  }

  // ---- stage 3: serial 4x4 two-sided Jacobi + LogEig + fc + log_softmax ----
  if (lane == 0) {
    float Am[4][4], V[4][4];
    float maxdg = 0.f;
    #pragma unroll
    for (int i = 0; i < 4; ++i) {
      #pragma unroll
      for (int j = 0; j < 4; ++j) {
        Am[i][j] = A[384 + i * 4 + j];
        V[i][j] = (i == j) ? 1.f : 0.f;
      }
      maxdg = fmaxf(maxdg, fabsf(Am[i][i]));
    }
    float tol3 = 1e-7f * maxdg;
    for (int sw = 0; sw < MAXSW4; ++sw) {
      bool any = false;
      #pragma unroll
      for (int p = 0; p < 3; ++p) {
        #pragma unroll
        for (int q = p + 1; q < 4; ++q) {
          float apq = Am[p][q];
          if (fabsf(apq) > tol3) {
            any = true;
            float c, sv;
            rot_cs(apq, Am[p][p], Am[q][q], c, sv);
            #pragma unroll
            for (int j = 0; j < 4; ++j) {
              float ap = Am[p][j], aq = Am[q][j];
              Am[p][j] = c * ap - sv * aq;
              Am[q][j] = sv * ap + c * aq;
            }
            #pragma unroll
            for (int i = 0; i < 4; ++i) {
              float ap = Am[i][p], aq = Am[i][q];
              Am[i][p] = c * ap - sv * aq;
              Am[i][q] = sv * ap + c * aq;
              float up = V[i][p], uq = V[i][q];
              V[i][p] = c * up - sv * uq;
              V[i][q] = sv * up + c * uq;
            }
          }
        }
      }
      if (!any) break;
    }
    float lm[4];
    #pragma unroll
    for (int i = 0; i < 4; ++i) lm[i] = logf(fmaxf(Am[i][i], 1e-10f));
    float feat[16];
    #pragma unroll
    for (int i = 0; i < 4; ++i)
      #pragma unroll
      for (int j = 0; j < 4; ++j) {
        float acc2 = 0.f;
        #pragma unroll
        for (int kk = 0; kk < 4; ++kk) acc2 += V[i][kk] * lm[kk] * V[j][kk];
        feat[i * 4 + j] = acc2;
      }
    float z0 = 0.f, z1 = 0.f;
    #pragma unroll
    for (int f = 0; f < 16; ++f) {
      z0 += feat[f] * fcw[f * 2 + 0];
      z1 += feat[f] * fcw[f * 2 + 1];
    }
    float mx = fmaxf(z0, z1);
    float lse = mx + logf(expf(z0 - mx) + expf(z1 - mx));
    out[b * 2 + 0] = z0 - lse;
    out[b * 2 + 1] = z1 - lse;
    float* fo = out + (size_t)2 * B + (size_t)b * 16;
    #pragma unroll
    for (int f = 0; f < 16; ++f) fo[f] = feat[f];
  }
}

extern "C" void kernel_launch(void* const* d_in, const int* in_sizes, int n_in,
                              void* d_out, int out_size, void* d_ws, size_t ws_size,
                              hipStream_t stream) {
  (void)n_in; (void)d_ws; (void)ws_size; (void)out_size;
  const float* x   = (const float*)d_in[0];
  const float* w1  = (const float*)d_in[1];
  const float* w2  = (const float*)d_in[2];
  const float* w3  = (const float*)d_in[3];
  const float* fcw = (const float*)d_in[4];
  float* out = (float*)d_out;
  int B = in_sizes[0] / 1024;
  spdnet_kernel<<<B, 64, 0, stream>>>(x, w1, w2, w3, fcw, out, B);
}